// Round 1
// baseline (3135.884 us; speedup 1.0000x reference)
//
#include <hip/hip_runtime.h>
#include <hip/hip_bf16.h>

#define N_NODES 50000
#define N_EDGES 600000
#define IN_CH 128
#define HID 256
#define OUT_FEAT 256
#define OUT_CH 128
#define TM 16

typedef unsigned short u16;
typedef unsigned char u8;

__device__ __forceinline__ float bf2f(u16 v) {
    unsigned u = ((unsigned)v) << 16;
    return __uint_as_float(u);
}
__device__ __forceinline__ u16 f2bf(float f) {
    unsigned u = __float_as_uint(f);
    u += 0x7FFF + ((u >> 16) & 1);   // round-to-nearest-even
    return (u16)(u >> 16);
}

// ---------------- format detection ----------------
// flags[0]: 1 if float tensors are bf16, 0 if f32
// flags[1]: mask format: 0=u8, 1=i32, 2=f32, 3=bf16
__global__ void detect_kernel(const u16* __restrict__ xu, const u8* __restrict__ mb,
                              int* __restrict__ flags) {
    if (threadIdx.x == 0 && blockIdx.x == 0) {
        // x ~ N(0,1): if storage is bf16, every u16's exponent field is "sane".
        // If storage is f32, half the u16s are mantissa garbage (uniform exponent field).
        int inr = 0;
        for (int i = 0; i < 256; i++) {
            int e = (xu[i] >> 7) & 0xFF;
            if (e >= 100 && e <= 133) inr++;
        }
        flags[0] = (inr >= 200) ? 1 : 0;

        // mask bytes: u8 {0,1}; i32 -> [v,0,0,0]; f32 1.0 -> [0,0,0x80,0x3F]; bf16 1.0 -> [0x80,0x3F]
        int c1 = 0, c23 = 0, h3f_1 = 0, h3f_3 = 0;
        for (int i = 0; i < 4096; i++) {
            int b = mb[i];
            int p = i & 3;
            if (p == 1) { if (b) c1++; if (b == 0x3F) h3f_1 = 1; }
            else if (p == 2) { if (b) c23++; }
            else if (p == 3) { if (b) c23++; if (b == 0x3F) h3f_3 = 1; }
        }
        int fmt;
        if (h3f_1) fmt = 3;              // bf16
        else if (h3f_3) fmt = 2;         // f32
        else if (c1 + c23 > 0) fmt = 0;  // u8 bool
        else fmt = 1;                    // int32
        flags[1] = fmt;
    }
}

// ---------------- conversions ----------------
__global__ void convert_kernel(const void* __restrict__ src, float* __restrict__ dst,
                               int n, const int* __restrict__ flags) {
    int i = blockIdx.x * blockDim.x + threadIdx.x;
    if (i >= n) return;
    if (flags[0]) dst[i] = bf2f(((const u16*)src)[i]);
    else          dst[i] = ((const float*)src)[i];
}

// src is [R, C]; dst is [C, R] (K-major weight layout)
__global__ void convt_kernel(const void* __restrict__ src, float* __restrict__ dst,
                             int R, int C, const int* __restrict__ flags) {
    int i = blockIdx.x * blockDim.x + threadIdx.x;
    if (i >= R * C) return;
    int r = i / C, c = i % C;
    float v = flags[0] ? bf2f(((const u16*)src)[i]) : ((const float*)src)[i];
    dst[c * R + r] = v;
}

__global__ void mask_kernel(const void* __restrict__ src, float* __restrict__ dst,
                            int n, const int* __restrict__ flags) {
    int i = blockIdx.x * blockDim.x + threadIdx.x;
    if (i >= n) return;
    int fmt = flags[1];
    float m;
    if (fmt == 0)      m = ((const u8*)src)[i] ? 1.f : 0.f;
    else if (fmt == 1) m = ((const int*)src)[i] ? 1.f : 0.f;
    else if (fmt == 2) m = (((const float*)src)[i] != 0.f) ? 1.f : 0.f;
    else               m = (((const u16*)src)[i] != 0) ? 1.f : 0.f;
    dst[i] = m;
}

// ---------------- edge scatter (atomics baseline) ----------------
// one wave per edge, 128 channels, 2 floats/lane
__global__ __launch_bounds__(256) void scatter1_kernel(const int* __restrict__ ei,
                                                       const float* __restrict__ xf,
                                                       float* __restrict__ agg,
                                                       float* __restrict__ cnt) {
    int wid = (blockIdx.x * blockDim.x + threadIdx.x) >> 6;
    int lane = threadIdx.x & 63;
    if (wid >= N_EDGES) return;
    int s = ei[wid];
    int d = ei[N_EDGES + wid];
    const float2 v = *(const float2*)(xf + (size_t)s * IN_CH + lane * 2);
    atomicAdd(&agg[(size_t)d * IN_CH + lane * 2 + 0], v.x);
    atomicAdd(&agg[(size_t)d * IN_CH + lane * 2 + 1], v.y);
    if (lane == 0) atomicAdd(&cnt[d], 1.0f);
}

// one wave per edge, 256 channels, 4 floats/lane, masked
__global__ __launch_bounds__(256) void scatter2_kernel(const int* __restrict__ ei,
                                                       const float* __restrict__ h1,
                                                       const float* __restrict__ maskf,
                                                       float* __restrict__ agg,
                                                       float* __restrict__ cnt) {
    int wid = (blockIdx.x * blockDim.x + threadIdx.x) >> 6;
    int lane = threadIdx.x & 63;
    if (wid >= N_EDGES) return;
    float m = maskf[wid];
    if (m == 0.f) return;                 // wave-uniform skip (30% of edges)
    int s = ei[wid];
    int d = ei[N_EDGES + wid];
    const float4 v = *(const float4*)(h1 + (size_t)s * HID + lane * 4);
    atomicAdd(&agg[(size_t)d * HID + lane * 4 + 0], v.x * m);
    atomicAdd(&agg[(size_t)d * HID + lane * 4 + 1], v.y * m);
    atomicAdd(&agg[(size_t)d * HID + lane * 4 + 2], v.z * m);
    atomicAdd(&agg[(size_t)d * HID + lane * 4 + 3], v.w * m);
    if (lane == 0) atomicAdd(&cnt[d], m);
}

// ---------------- layer 1 fused GEMM ----------------
// out1 = mean_agg @ W1l^T + b1 + x @ W1r^T ; h = out1/||out1|| + x @ Ws^T + bs ; h1 = tanh(h)
__global__ __launch_bounds__(256) void sage1_kernel(const float* __restrict__ xf,
                                                    const float* __restrict__ agg,
                                                    const float* __restrict__ cnt,
                                                    const float* __restrict__ Wt1,   // [256][256] K-major, rows 0..127 = W1l cols, 128..255 = W1r cols
                                                    const float* __restrict__ Wts,   // [128][256]
                                                    const float* __restrict__ b1,
                                                    const float* __restrict__ bs,
                                                    float* __restrict__ h1out) {
    __shared__ float a_sh[TM][256];   // [m][0..127]=mean agg, [128..255]=x row
    __shared__ float red[TM][256];
    __shared__ float inv[TM];
    int tid = threadIdx.x;
    int base = blockIdx.x * TM;

    if (tid < TM) {
        int node = base + tid;
        float c = (node < N_NODES) ? cnt[node] : 1.f;
        inv[tid] = 1.f / fmaxf(c, 1.f);
    }
    __syncthreads();
    for (int idx = tid; idx < TM * 128; idx += 256) {
        int m = idx >> 7, k = idx & 127;
        int node = base + m;
        float av = (node < N_NODES) ? agg[(size_t)node * IN_CH + k] * inv[m] : 0.f;
        float xv = (node < N_NODES) ? xf[(size_t)node * IN_CH + k] : 0.f;
        a_sh[m][k] = av;
        a_sh[m][128 + k] = xv;
    }
    __syncthreads();

    int j = tid;
    float acc1[TM], accs[TM];
#pragma unroll
    for (int m = 0; m < TM; m++) { acc1[m] = 0.f; accs[m] = 0.f; }

    for (int k = 0; k < 128; k += 2) {
        float w_a0 = Wt1[(k + 0) * 256 + j];
        float w_a1 = Wt1[(k + 1) * 256 + j];
        float w_b0 = Wt1[(128 + k + 0) * 256 + j];
        float w_b1 = Wt1[(128 + k + 1) * 256 + j];
        float w_s0 = Wts[(k + 0) * 256 + j];
        float w_s1 = Wts[(k + 1) * 256 + j];
#pragma unroll
        for (int m = 0; m < TM; m++) {
            float2 a = *(const float2*)&a_sh[m][k];
            float2 b = *(const float2*)&a_sh[m][128 + k];
            acc1[m] = fmaf(a.x, w_a0, acc1[m]);
            acc1[m] = fmaf(a.y, w_a1, acc1[m]);
            acc1[m] = fmaf(b.x, w_b0, acc1[m]);
            acc1[m] = fmaf(b.y, w_b1, acc1[m]);
            accs[m] = fmaf(b.x, w_s0, accs[m]);
            accs[m] = fmaf(b.y, w_s1, accs[m]);
        }
    }
    float bj = b1[j], bsj = bs[j];
#pragma unroll
    for (int m = 0; m < TM; m++) { acc1[m] += bj; red[m][j] = acc1[m] * acc1[m]; }
    __syncthreads();
    for (int sl = 7; sl >= 0; sl--) {
        int s = 1 << sl;
        for (int idx = tid; idx < TM * s; idx += 256) {
            int m = idx >> sl, t = idx & (s - 1);
            red[m][t] += red[m][t + s];
        }
        __syncthreads();
    }
#pragma unroll
    for (int m = 0; m < TM; m++) {
        int node = base + m;
        if (node >= N_NODES) continue;
        float nrm = fmaxf(sqrtf(red[m][0]), 1e-12f);
        float h = acc1[m] / nrm + accs[m] + bsj;
        h1out[(size_t)node * HID + j] = tanhf(h);
    }
}

// ---------------- layer 2 fused GEMM ----------------
// out2 = mean_agg2 @ W2l^T + b2 + h1 @ W2r^T ; h2 = tanh(out2/||out2||) ; written in-place into agg
__global__ __launch_bounds__(256) void sage2_kernel(const float* __restrict__ h1,
                                                    float* __restrict__ agg,
                                                    const float* __restrict__ cnt,
                                                    const float* __restrict__ Wt2,  // [512][256] K-major
                                                    const float* __restrict__ b2) {
    __shared__ float a_sh[TM][512];
    __shared__ float red[TM][256];
    __shared__ float inv[TM];
    int tid = threadIdx.x;
    int base = blockIdx.x * TM;

    if (tid < TM) {
        int node = base + tid;
        float c = (node < N_NODES) ? cnt[node] : 1.f;
        inv[tid] = 1.f / fmaxf(c, 1.f);
    }
    __syncthreads();
    for (int idx = tid; idx < TM * 256; idx += 256) {
        int m = idx >> 8, k = idx & 255;
        int node = base + m;
        float av = (node < N_NODES) ? agg[(size_t)node * HID + k] * inv[m] : 0.f;
        float hv = (node < N_NODES) ? h1[(size_t)node * HID + k] : 0.f;
        a_sh[m][k] = av;
        a_sh[m][256 + k] = hv;
    }
    __syncthreads();

    int j = tid;
    float acc[TM];
#pragma unroll
    for (int m = 0; m < TM; m++) acc[m] = 0.f;

    for (int k = 0; k < 256; k += 2) {
        float w_a0 = Wt2[(k + 0) * 256 + j];
        float w_a1 = Wt2[(k + 1) * 256 + j];
        float w_b0 = Wt2[(256 + k + 0) * 256 + j];
        float w_b1 = Wt2[(256 + k + 1) * 256 + j];
#pragma unroll
        for (int m = 0; m < TM; m++) {
            float2 a = *(const float2*)&a_sh[m][k];
            float2 b = *(const float2*)&a_sh[m][256 + k];
            acc[m] = fmaf(a.x, w_a0, acc[m]);
            acc[m] = fmaf(a.y, w_a1, acc[m]);
            acc[m] = fmaf(b.x, w_b0, acc[m]);
            acc[m] = fmaf(b.y, w_b1, acc[m]);
        }
    }
    float bj = b2[j];
#pragma unroll
    for (int m = 0; m < TM; m++) { acc[m] += bj; red[m][j] = acc[m] * acc[m]; }
    __syncthreads();
    for (int sl = 7; sl >= 0; sl--) {
        int s = 1 << sl;
        for (int idx = tid; idx < TM * s; idx += 256) {
            int m = idx >> sl, t = idx & (s - 1);
            red[m][t] += red[m][t + s];
        }
        __syncthreads();
    }
#pragma unroll
    for (int m = 0; m < TM; m++) {
        int node = base + m;
        if (node >= N_NODES) continue;
        float nrm = fmaxf(sqrtf(red[m][0]), 1e-12f);
        agg[(size_t)node * HID + j] = tanhf(acc[m] / nrm);
    }
}

// ---------------- final projection ----------------
__global__ __launch_bounds__(128) void final_kernel(const float* __restrict__ h2,
                                                    const float* __restrict__ Wto,  // [256][128] K-major
                                                    const float* __restrict__ bo,
                                                    void* __restrict__ out,
                                                    const int* __restrict__ flags) {
    __shared__ float a_sh[TM][256];
    int tid = threadIdx.x;
    int base = blockIdx.x * TM;
    for (int idx = tid; idx < TM * 256; idx += 128) {
        int m = idx >> 8, k = idx & 255;
        int node = base + m;
        a_sh[m][k] = (node < N_NODES) ? h2[(size_t)node * HID + k] : 0.f;
    }
    __syncthreads();

    int j = tid;
    float acc[TM];
#pragma unroll
    for (int m = 0; m < TM; m++) acc[m] = 0.f;
    for (int k = 0; k < 256; k += 2) {
        float w0 = Wto[(k + 0) * 128 + j];
        float w1 = Wto[(k + 1) * 128 + j];
#pragma unroll
        for (int m = 0; m < TM; m++) {
            float2 a = *(const float2*)&a_sh[m][k];
            acc[m] = fmaf(a.x, w0, acc[m]);
            acc[m] = fmaf(a.y, w1, acc[m]);
        }
    }
    float bj = bo[j];
    int isbf = flags[0];
#pragma unroll
    for (int m = 0; m < TM; m++) {
        int node = base + m;
        if (node >= N_NODES) continue;
        float v = acc[m] + bj;
        if (isbf) ((u16*)out)[(size_t)node * OUT_CH + j] = f2bf(v);
        else      ((float*)out)[(size_t)node * OUT_CH + j] = v;
    }
}

extern "C" void kernel_launch(void* const* d_in, const int* in_sizes, int n_in,
                              void* d_out, int out_size, void* d_ws, size_t ws_size,
                              hipStream_t stream) {
    const void* x    = d_in[0];
    const int*  ei   = (const int*)d_in[1];
    const void* em   = d_in[2];
    const void* W1l  = d_in[3];
    const void* b1   = d_in[4];
    const void* W1r  = d_in[5];
    const void* Ws   = d_in[6];
    const void* bs   = d_in[7];
    const void* W2l  = d_in[8];
    const void* b2   = d_in[9];
    const void* W2r  = d_in[10];
    const void* Wo   = d_in[11];
    const void* bo   = d_in[12];

    int* flags = (int*)d_ws;
    float* base = (float*)((char*)d_ws + 256);
    size_t off = 0;
    float* xf    = base + off; off += (size_t)N_NODES * IN_CH;      // 6.4M
    float* h1    = base + off; off += (size_t)N_NODES * HID;        // 12.8M
    float* agg   = base + off; off += (size_t)N_NODES * HID;        // 12.8M
    float* cnt   = base + off; off += 50048;
    float* maskf = base + off; off += N_EDGES;
    float* Wt1   = base + off; off += 256 * 256;
    float* Wts_  = base + off; off += 128 * 256;
    float* Wt2   = base + off; off += 512 * 256;
    float* Wto   = base + off; off += 256 * 128;
    float* b1f   = base + off; off += 256;
    float* bsf   = base + off; off += 256;
    float* b2f   = base + off; off += 256;
    float* bof   = base + off; off += 128;
    (void)ws_size; (void)in_sizes; (void)n_in; (void)out_size;

    detect_kernel<<<1, 64, 0, stream>>>((const u16*)x, (const u8*)em, flags);

    convert_kernel<<<(N_NODES * IN_CH + 255) / 256, 256, 0, stream>>>(x, xf, N_NODES * IN_CH, flags);
    convt_kernel<<<(256 * 128 + 255) / 256, 256, 0, stream>>>(W1l, Wt1, 256, 128, flags);
    convt_kernel<<<(256 * 128 + 255) / 256, 256, 0, stream>>>(W1r, Wt1 + 128 * 256, 256, 128, flags);
    convt_kernel<<<(256 * 128 + 255) / 256, 256, 0, stream>>>(Ws, Wts_, 256, 128, flags);
    convt_kernel<<<(256 * 256 + 255) / 256, 256, 0, stream>>>(W2l, Wt2, 256, 256, flags);
    convt_kernel<<<(256 * 256 + 255) / 256, 256, 0, stream>>>(W2r, Wt2 + 256 * 256, 256, 256, flags);
    convt_kernel<<<(128 * 256 + 255) / 256, 256, 0, stream>>>(Wo, Wto, 128, 256, flags);
    convert_kernel<<<1, 256, 0, stream>>>(b1, b1f, 256, flags);
    convert_kernel<<<1, 256, 0, stream>>>(bs, bsf, 256, flags);
    convert_kernel<<<1, 256, 0, stream>>>(b2, b2f, 256, flags);
    convert_kernel<<<1, 256, 0, stream>>>(bo, bof, 128, flags);
    mask_kernel<<<(N_EDGES + 255) / 256, 256, 0, stream>>>(em, maskf, N_EDGES, flags);

    // layer 1 aggregation
    hipMemsetAsync(agg, 0, (size_t)N_NODES * HID * sizeof(float), stream);
    hipMemsetAsync(cnt, 0, 50048 * sizeof(float), stream);
    scatter1_kernel<<<(N_EDGES * 64) / 256, 256, 0, stream>>>(ei, xf, agg, cnt);
    sage1_kernel<<<(N_NODES + TM - 1) / TM, 256, 0, stream>>>(xf, agg, cnt, Wt1, Wts_, b1f, bsf, h1);

    // layer 2 aggregation (masked)
    hipMemsetAsync(agg, 0, (size_t)N_NODES * HID * sizeof(float), stream);
    hipMemsetAsync(cnt, 0, 50048 * sizeof(float), stream);
    scatter2_kernel<<<(N_EDGES * 64) / 256, 256, 0, stream>>>(ei, h1, maskf, agg, cnt);
    sage2_kernel<<<(N_NODES + TM - 1) / TM, 256, 0, stream>>>(h1, agg, cnt, Wt2, b2f);

    final_kernel<<<(N_NODES + TM - 1) / TM, 128, 0, stream>>>(agg, Wto, bof, d_out, flags);
}

// Round 2
// 1291.377 us; speedup vs baseline: 2.4283x; 2.4283x over previous
//
#include <hip/hip_runtime.h>
#include <hip/hip_bf16.h>

#define N_NODES 50000
#define N_EDGES 600000
#define IN_CH 128
#define HID 256
#define OUT_FEAT 256
#define OUT_CH 128
#define TM 16

typedef unsigned short u16;
typedef unsigned char u8;

__device__ __forceinline__ float bf2f(u16 v) {
    unsigned u = ((unsigned)v) << 16;
    return __uint_as_float(u);
}
__device__ __forceinline__ u16 f2bf(float f) {
    unsigned u = __float_as_uint(f);
    u += 0x7FFF + ((u >> 16) & 1);   // round-to-nearest-even
    return (u16)(u >> 16);
}

// ---------------- format detection ----------------
// flags[0]: 1 if float tensors are bf16, 0 if f32
// flags[1]: mask format: 0=u8, 1=i32, 2=f32, 3=bf16
__global__ void detect_kernel(const u16* __restrict__ xu, const u8* __restrict__ mb,
                              int* __restrict__ flags) {
    if (threadIdx.x == 0 && blockIdx.x == 0) {
        int inr = 0;
        for (int i = 0; i < 256; i++) {
            int e = (xu[i] >> 7) & 0xFF;
            if (e >= 100 && e <= 133) inr++;
        }
        flags[0] = (inr >= 200) ? 1 : 0;

        int c1 = 0, c23 = 0, h3f_1 = 0, h3f_3 = 0;
        for (int i = 0; i < 4096; i++) {
            int b = mb[i];
            int p = i & 3;
            if (p == 1) { if (b) c1++; if (b == 0x3F) h3f_1 = 1; }
            else if (p == 2) { if (b) c23++; }
            else if (p == 3) { if (b) c23++; if (b == 0x3F) h3f_3 = 1; }
        }
        int fmt;
        if (h3f_1) fmt = 3;
        else if (h3f_3) fmt = 2;
        else if (c1 + c23 > 0) fmt = 0;
        else fmt = 1;
        flags[1] = fmt;
    }
}

// ---------------- conversions ----------------
__global__ void convert_kernel(const void* __restrict__ src, float* __restrict__ dst,
                               int n, const int* __restrict__ flags) {
    int i = blockIdx.x * blockDim.x + threadIdx.x;
    if (i >= n) return;
    if (flags[0]) dst[i] = bf2f(((const u16*)src)[i]);
    else          dst[i] = ((const float*)src)[i];
}

__global__ void convt_kernel(const void* __restrict__ src, float* __restrict__ dst,
                             int R, int C, const int* __restrict__ flags) {
    int i = blockIdx.x * blockDim.x + threadIdx.x;
    if (i >= R * C) return;
    int r = i / C, c = i % C;
    float v = flags[0] ? bf2f(((const u16*)src)[i]) : ((const float*)src)[i];
    dst[c * R + r] = v;
}

__global__ void mask_kernel(const void* __restrict__ src, float* __restrict__ dst,
                            int n, const int* __restrict__ flags) {
    int i = blockIdx.x * blockDim.x + threadIdx.x;
    if (i >= n) return;
    int fmt = flags[1];
    float m;
    if (fmt == 0)      m = ((const u8*)src)[i] ? 1.f : 0.f;
    else if (fmt == 1) m = ((const int*)src)[i] ? 1.f : 0.f;
    else if (fmt == 2) m = (((const float*)src)[i] != 0.f) ? 1.f : 0.f;
    else               m = (((const u16*)src)[i] != 0) ? 1.f : 0.f;
    dst[i] = m;
}

// ---------------- CSR build (counting sort by dst) ----------------
__global__ void hist_kernel(const int* __restrict__ ei, int* __restrict__ deg,
                            int* __restrict__ rank) {
    int i = blockIdx.x * blockDim.x + threadIdx.x;
    if (i >= N_EDGES) return;
    int d = ei[N_EDGES + i];
    rank[i] = atomicAdd(&deg[d], 1);
}

// per-256-chunk sums of deg
__global__ void partial_kernel(const int* __restrict__ deg, int* __restrict__ partial) {
    __shared__ int sh[256];
    int t = threadIdx.x;
    int i = blockIdx.x * 256 + t;
    sh[t] = (i < N_NODES) ? deg[i] : 0;
    __syncthreads();
    for (int s = 128; s > 0; s >>= 1) {
        if (t < s) sh[t] += sh[t + s];
        __syncthreads();
    }
    if (t == 0) partial[blockIdx.x] = sh[0];
}

// exclusive scan of partial[0..nb) -> pscan (one block, Hillis-Steele over 256)
__global__ void scanp_kernel(const int* __restrict__ partial, int* __restrict__ pscan, int nb) {
    __shared__ int sh[256];
    int t = threadIdx.x;
    int v = (t < nb) ? partial[t] : 0;
    sh[t] = v;
    __syncthreads();
    for (int o = 1; o < 256; o <<= 1) {
        int u = (t >= o) ? sh[t - o] : 0;
        __syncthreads();
        sh[t] += u;
        __syncthreads();
    }
    if (t < nb) pscan[t] = sh[t] - v;   // exclusive
}

// per-chunk exclusive scan + pscan offset -> row_ptr
__global__ void rowptr_kernel(const int* __restrict__ deg, const int* __restrict__ pscan,
                              int* __restrict__ row_ptr) {
    __shared__ int sh[256];
    int t = threadIdx.x;
    int i = blockIdx.x * 256 + t;
    int v = (i < N_NODES) ? deg[i] : 0;
    sh[t] = v;
    __syncthreads();
    for (int o = 1; o < 256; o <<= 1) {
        int u = (t >= o) ? sh[t - o] : 0;
        __syncthreads();
        sh[t] += u;
        __syncthreads();
    }
    if (i <= N_NODES) row_ptr[i] = pscan[blockIdx.x] + sh[t] - v;
}

__global__ void scatter_csr_kernel(const int* __restrict__ ei, const int* __restrict__ rank,
                                   const int* __restrict__ row_ptr,
                                   const float* __restrict__ maskf,
                                   int* __restrict__ srcs, float* __restrict__ maskp) {
    int i = blockIdx.x * blockDim.x + threadIdx.x;
    if (i >= N_EDGES) return;
    int d = ei[N_EDGES + i];
    int p = row_ptr[d] + rank[i];
    srcs[p] = ei[i];
    maskp[p] = maskf[i];
}

// ---------------- CSR gathers (one wave per node), write MEAN directly ----------------
__global__ __launch_bounds__(256) void gather1_kernel(const int* __restrict__ row_ptr,
                                                      const int* __restrict__ srcs,
                                                      const float* __restrict__ xf,
                                                      float* __restrict__ agg) {
    int wid = (blockIdx.x * blockDim.x + threadIdx.x) >> 6;
    int lane = threadIdx.x & 63;
    if (wid >= N_NODES) return;
    int start = row_ptr[wid], end = row_ptr[wid + 1];
    float2 a0 = {0.f, 0.f}, a1 = {0.f, 0.f};
    int e = start;
    for (; e + 2 <= end; e += 2) {
        int s0 = srcs[e], s1 = srcs[e + 1];
        float2 v0 = *(const float2*)(xf + (size_t)s0 * IN_CH + lane * 2);
        float2 v1 = *(const float2*)(xf + (size_t)s1 * IN_CH + lane * 2);
        a0.x += v0.x; a0.y += v0.y;
        a1.x += v1.x; a1.y += v1.y;
    }
    if (e < end) {
        int s0 = srcs[e];
        float2 v0 = *(const float2*)(xf + (size_t)s0 * IN_CH + lane * 2);
        a0.x += v0.x; a0.y += v0.y;
    }
    float inv = 1.f / fmaxf((float)(end - start), 1.f);
    float2 r;
    r.x = (a0.x + a1.x) * inv;
    r.y = (a0.y + a1.y) * inv;
    *(float2*)(agg + (size_t)wid * IN_CH + lane * 2) = r;
}

__global__ __launch_bounds__(256) void gather2_kernel(const int* __restrict__ row_ptr,
                                                      const int* __restrict__ srcs,
                                                      const float* __restrict__ maskp,
                                                      const float* __restrict__ h1,
                                                      float* __restrict__ agg) {
    int wid = (blockIdx.x * blockDim.x + threadIdx.x) >> 6;
    int lane = threadIdx.x & 63;
    if (wid >= N_NODES) return;
    int start = row_ptr[wid], end = row_ptr[wid + 1];
    float4 acc = {0.f, 0.f, 0.f, 0.f};
    float c = 0.f;
    for (int e = start; e < end; e++) {
        float m = maskp[e];
        if (m != 0.f) {
            int s = srcs[e];
            float4 v = *(const float4*)(h1 + (size_t)s * HID + lane * 4);
            acc.x += v.x * m; acc.y += v.y * m;
            acc.z += v.z * m; acc.w += v.w * m;
            c += m;
        }
    }
    float inv = 1.f / fmaxf(c, 1.f);
    acc.x *= inv; acc.y *= inv; acc.z *= inv; acc.w *= inv;
    *(float4*)(agg + (size_t)wid * HID + lane * 4) = acc;
}

// ---------------- layer 1 fused GEMM ----------------
// agg already holds MEAN. out1 = agg@W1l^T + b1 + x@W1r^T; h = out1/||out1|| + x@Ws^T + bs; h1=tanh(h)
__global__ __launch_bounds__(256) void sage1_kernel(const float* __restrict__ xf,
                                                    const float* __restrict__ agg,
                                                    const float* __restrict__ Wt1,
                                                    const float* __restrict__ Wts,
                                                    const float* __restrict__ b1,
                                                    const float* __restrict__ bs,
                                                    float* __restrict__ h1out) {
    __shared__ float a_sh[TM][256];
    __shared__ float red[TM][256];
    int tid = threadIdx.x;
    int base = blockIdx.x * TM;

    for (int idx = tid; idx < TM * 128; idx += 256) {
        int m = idx >> 7, k = idx & 127;
        int node = base + m;
        float av = (node < N_NODES) ? agg[(size_t)node * IN_CH + k] : 0.f;
        float xv = (node < N_NODES) ? xf[(size_t)node * IN_CH + k] : 0.f;
        a_sh[m][k] = av;
        a_sh[m][128 + k] = xv;
    }
    __syncthreads();

    int j = tid;
    float acc1[TM], accs[TM];
#pragma unroll
    for (int m = 0; m < TM; m++) { acc1[m] = 0.f; accs[m] = 0.f; }

    for (int k = 0; k < 128; k += 2) {
        float w_a0 = Wt1[(k + 0) * 256 + j];
        float w_a1 = Wt1[(k + 1) * 256 + j];
        float w_b0 = Wt1[(128 + k + 0) * 256 + j];
        float w_b1 = Wt1[(128 + k + 1) * 256 + j];
        float w_s0 = Wts[(k + 0) * 256 + j];
        float w_s1 = Wts[(k + 1) * 256 + j];
#pragma unroll
        for (int m = 0; m < TM; m++) {
            float2 a = *(const float2*)&a_sh[m][k];
            float2 b = *(const float2*)&a_sh[m][128 + k];
            acc1[m] = fmaf(a.x, w_a0, acc1[m]);
            acc1[m] = fmaf(a.y, w_a1, acc1[m]);
            acc1[m] = fmaf(b.x, w_b0, acc1[m]);
            acc1[m] = fmaf(b.y, w_b1, acc1[m]);
            accs[m] = fmaf(b.x, w_s0, accs[m]);
            accs[m] = fmaf(b.y, w_s1, accs[m]);
        }
    }
    float bj = b1[j], bsj = bs[j];
#pragma unroll
    for (int m = 0; m < TM; m++) { acc1[m] += bj; red[m][j] = acc1[m] * acc1[m]; }
    __syncthreads();
    for (int sl = 7; sl >= 0; sl--) {
        int s = 1 << sl;
        for (int idx = tid; idx < TM * s; idx += 256) {
            int m = idx >> sl, t = idx & (s - 1);
            red[m][t] += red[m][t + s];
        }
        __syncthreads();
    }
#pragma unroll
    for (int m = 0; m < TM; m++) {
        int node = base + m;
        if (node >= N_NODES) continue;
        float nrm = fmaxf(sqrtf(red[m][0]), 1e-12f);
        float h = acc1[m] / nrm + accs[m] + bsj;
        h1out[(size_t)node * HID + j] = tanhf(h);
    }
}

// ---------------- layer 2 fused GEMM ----------------
__global__ __launch_bounds__(256) void sage2_kernel(const float* __restrict__ h1,
                                                    float* __restrict__ agg,
                                                    const float* __restrict__ Wt2,
                                                    const float* __restrict__ b2) {
    __shared__ float a_sh[TM][512];
    __shared__ float red[TM][256];
    int tid = threadIdx.x;
    int base = blockIdx.x * TM;

    for (int idx = tid; idx < TM * 256; idx += 256) {
        int m = idx >> 8, k = idx & 255;
        int node = base + m;
        float av = (node < N_NODES) ? agg[(size_t)node * HID + k] : 0.f;
        float hv = (node < N_NODES) ? h1[(size_t)node * HID + k] : 0.f;
        a_sh[m][k] = av;
        a_sh[m][256 + k] = hv;
    }
    __syncthreads();

    int j = tid;
    float acc[TM];
#pragma unroll
    for (int m = 0; m < TM; m++) acc[m] = 0.f;

    for (int k = 0; k < 256; k += 2) {
        float w_a0 = Wt2[(k + 0) * 256 + j];
        float w_a1 = Wt2[(k + 1) * 256 + j];
        float w_b0 = Wt2[(256 + k + 0) * 256 + j];
        float w_b1 = Wt2[(256 + k + 1) * 256 + j];
#pragma unroll
        for (int m = 0; m < TM; m++) {
            float2 a = *(const float2*)&a_sh[m][k];
            float2 b = *(const float2*)&a_sh[m][256 + k];
            acc[m] = fmaf(a.x, w_a0, acc[m]);
            acc[m] = fmaf(a.y, w_a1, acc[m]);
            acc[m] = fmaf(b.x, w_b0, acc[m]);
            acc[m] = fmaf(b.y, w_b1, acc[m]);
        }
    }
    float bj = b2[j];
#pragma unroll
    for (int m = 0; m < TM; m++) { acc[m] += bj; red[m][j] = acc[m] * acc[m]; }
    __syncthreads();
    for (int sl = 7; sl >= 0; sl--) {
        int s = 1 << sl;
        for (int idx = tid; idx < TM * s; idx += 256) {
            int m = idx >> sl, t = idx & (s - 1);
            red[m][t] += red[m][t + s];
        }
        __syncthreads();
    }
#pragma unroll
    for (int m = 0; m < TM; m++) {
        int node = base + m;
        if (node >= N_NODES) continue;
        float nrm = fmaxf(sqrtf(red[m][0]), 1e-12f);
        agg[(size_t)node * HID + j] = tanhf(acc[m] / nrm);
    }
}

// ---------------- final projection ----------------
__global__ __launch_bounds__(128) void final_kernel(const float* __restrict__ h2,
                                                    const float* __restrict__ Wto,
                                                    const float* __restrict__ bo,
                                                    void* __restrict__ out,
                                                    const int* __restrict__ flags) {
    __shared__ float a_sh[TM][256];
    int tid = threadIdx.x;
    int base = blockIdx.x * TM;
    for (int idx = tid; idx < TM * 256; idx += 128) {
        int m = idx >> 8, k = idx & 255;
        int node = base + m;
        a_sh[m][k] = (node < N_NODES) ? h2[(size_t)node * HID + k] : 0.f;
    }
    __syncthreads();

    int j = tid;
    float acc[TM];
#pragma unroll
    for (int m = 0; m < TM; m++) acc[m] = 0.f;
    for (int k = 0; k < 256; k += 2) {
        float w0 = Wto[(k + 0) * 128 + j];
        float w1 = Wto[(k + 1) * 128 + j];
#pragma unroll
        for (int m = 0; m < TM; m++) {
            float2 a = *(const float2*)&a_sh[m][k];
            acc[m] = fmaf(a.x, w0, acc[m]);
            acc[m] = fmaf(a.y, w1, acc[m]);
        }
    }
    float bj = bo[j];
    int isbf = flags[0];
#pragma unroll
    for (int m = 0; m < TM; m++) {
        int node = base + m;
        if (node >= N_NODES) continue;
        float v = acc[m] + bj;
        if (isbf) ((u16*)out)[(size_t)node * OUT_CH + j] = f2bf(v);
        else      ((float*)out)[(size_t)node * OUT_CH + j] = v;
    }
}

extern "C" void kernel_launch(void* const* d_in, const int* in_sizes, int n_in,
                              void* d_out, int out_size, void* d_ws, size_t ws_size,
                              hipStream_t stream) {
    const void* x    = d_in[0];
    const int*  ei   = (const int*)d_in[1];
    const void* em   = d_in[2];
    const void* W1l  = d_in[3];
    const void* b1   = d_in[4];
    const void* W1r  = d_in[5];
    const void* Ws   = d_in[6];
    const void* bs   = d_in[7];
    const void* W2l  = d_in[8];
    const void* b2   = d_in[9];
    const void* W2r  = d_in[10];
    const void* Wo   = d_in[11];
    const void* bo   = d_in[12];

    int* flags = (int*)d_ws;
    float* base = (float*)((char*)d_ws + 256);
    size_t off = 0;
    float* xf    = base + off; off += (size_t)N_NODES * IN_CH;      // 6.4M
    float* h1    = base + off; off += (size_t)N_NODES * HID;        // 12.8M
    float* agg   = base + off; off += (size_t)N_NODES * HID;        // 12.8M
    float* Wt1   = base + off; off += 256 * 256;
    float* Wts_  = base + off; off += 128 * 256;
    float* Wt2   = base + off; off += 512 * 256;
    float* Wto   = base + off; off += 256 * 128;
    float* b1f   = base + off; off += 256;
    float* bsf   = base + off; off += 256;
    float* b2f   = base + off; off += 256;
    float* bof   = base + off; off += 128;
    // CSR arrays
    int*   deg     = (int*)(base + off); off += 50056;
    int*   row_ptr = (int*)(base + off); off += 50056;
    int*   partial = (int*)(base + off); off += 256;
    int*   pscan   = (int*)(base + off); off += 256;
    int*   srcs    = (int*)(base + off); off += N_EDGES;
    float* maskp   = base + off; off += N_EDGES;
    // aliases (lifetime-disjoint)
    int*   rank  = (int*)agg;      // consumed by scatter_csr before gather1 writes agg
    float* maskf = h1;             // consumed by scatter_csr before sage1 writes h1
    (void)ws_size; (void)in_sizes; (void)n_in; (void)out_size;

    detect_kernel<<<1, 64, 0, stream>>>((const u16*)x, (const u8*)em, flags);

    convert_kernel<<<(N_NODES * IN_CH + 255) / 256, 256, 0, stream>>>(x, xf, N_NODES * IN_CH, flags);
    convt_kernel<<<(256 * 128 + 255) / 256, 256, 0, stream>>>(W1l, Wt1, 256, 128, flags);
    convt_kernel<<<(256 * 128 + 255) / 256, 256, 0, stream>>>(W1r, Wt1 + 128 * 256, 256, 128, flags);
    convt_kernel<<<(256 * 128 + 255) / 256, 256, 0, stream>>>(Ws, Wts_, 256, 128, flags);
    convt_kernel<<<(256 * 256 + 255) / 256, 256, 0, stream>>>(W2l, Wt2, 256, 256, flags);
    convt_kernel<<<(256 * 256 + 255) / 256, 256, 0, stream>>>(W2r, Wt2 + 256 * 256, 256, 256, flags);
    convt_kernel<<<(128 * 256 + 255) / 256, 256, 0, stream>>>(Wo, Wto, 128, 256, flags);
    convert_kernel<<<1, 256, 0, stream>>>(b1, b1f, 256, flags);
    convert_kernel<<<1, 256, 0, stream>>>(bs, bsf, 256, flags);
    convert_kernel<<<1, 256, 0, stream>>>(b2, b2f, 256, flags);
    convert_kernel<<<1, 256, 0, stream>>>(bo, bof, 128, flags);
    mask_kernel<<<(N_EDGES + 255) / 256, 256, 0, stream>>>(em, maskf, N_EDGES, flags);

    // ---- CSR build (shared by both layers) ----
    hipMemsetAsync(deg, 0, 50056 * sizeof(int), stream);
    hist_kernel<<<(N_EDGES + 255) / 256, 256, 0, stream>>>(ei, deg, rank);
    const int NB = (N_NODES + 255) / 256;   // 196 chunks
    partial_kernel<<<NB, 256, 0, stream>>>(deg, partial);
    scanp_kernel<<<1, 256, 0, stream>>>(partial, pscan, NB);
    rowptr_kernel<<<NB, 256, 0, stream>>>(deg, pscan, row_ptr);
    scatter_csr_kernel<<<(N_EDGES + 255) / 256, 256, 0, stream>>>(ei, rank, row_ptr, maskf, srcs, maskp);

    // ---- layer 1 ----
    gather1_kernel<<<(N_NODES * 64 + 255) / 256, 256, 0, stream>>>(row_ptr, srcs, xf, agg);
    sage1_kernel<<<(N_NODES + TM - 1) / TM, 256, 0, stream>>>(xf, agg, Wt1, Wts_, b1f, bsf, h1);

    // ---- layer 2 ----
    gather2_kernel<<<(N_NODES * 64 + 255) / 256, 256, 0, stream>>>(row_ptr, srcs, maskp, h1, agg);
    sage2_kernel<<<(N_NODES + TM - 1) / TM, 256, 0, stream>>>(h1, agg, Wt2, b2f);

    final_kernel<<<(N_NODES + TM - 1) / TM, 128, 0, stream>>>(agg, Wto, bof, d_out, flags);
}

// Round 3
// 774.571 us; speedup vs baseline: 4.0485x; 1.6672x over previous
//
#include <hip/hip_runtime.h>
#include <hip/hip_bf16.h>

#define N_NODES 50000
#define N_PAD   50016
#define N_EDGES 600000
#define IN_CH 128
#define HID 256
#define OUT_CH 128

typedef unsigned short u16;
typedef unsigned char u8;
typedef unsigned int u32;

typedef __attribute__((ext_vector_type(8))) short short8;
typedef __attribute__((ext_vector_type(4))) float f32x4;

__device__ __forceinline__ float bf2f(u16 v) {
    unsigned u = ((unsigned)v) << 16;
    return __uint_as_float(u);
}
__device__ __forceinline__ u16 f2bf(float f) {
    unsigned u = __float_as_uint(f);
    u += 0x7FFF + ((u >> 16) & 1);   // round-to-nearest-even
    return (u16)(u >> 16);
}
__device__ __forceinline__ short8 ld8(const u16* p) {
    return *(const short8*)p;        // 16B vector load (aligned by construction)
}

// ---------------- format detection ----------------
// flags[0]: 1 if float tensors are bf16, 0 if f32
// flags[1]: mask format: 0=u8, 1=i32, 2=f32, 3=bf16
__global__ void detect_kernel(const u16* __restrict__ xu, const u8* __restrict__ mb,
                              int* __restrict__ flags) {
    if (threadIdx.x == 0 && blockIdx.x == 0) {
        int inr = 0;
        for (int i = 0; i < 256; i++) {
            int e = (xu[i] >> 7) & 0xFF;
            if (e >= 100 && e <= 133) inr++;
        }
        flags[0] = (inr >= 200) ? 1 : 0;

        int c1 = 0, c23 = 0, h3f_1 = 0, h3f_3 = 0;
        for (int i = 0; i < 4096; i++) {
            int b = mb[i];
            int p = i & 3;
            if (p == 1) { if (b) c1++; if (b == 0x3F) h3f_1 = 1; }
            else if (p == 2) { if (b) c23++; }
            else if (p == 3) { if (b) c23++; if (b == 0x3F) h3f_3 = 1; }
        }
        int fmt;
        if (h3f_1) fmt = 3;
        else if (h3f_3) fmt = 2;
        else if (c1 + c23 > 0) fmt = 0;
        else fmt = 1;
        flags[1] = fmt;
    }
}

// ---------------- conversions ----------------
__global__ void convert_kernel(const void* __restrict__ src, float* __restrict__ dst,
                               int n, const int* __restrict__ flags) {
    int i = blockIdx.x * blockDim.x + threadIdx.x;
    if (i >= n) return;
    if (flags[0]) dst[i] = bf2f(((const u16*)src)[i]);
    else          dst[i] = ((const float*)src)[i];
}

// concat-convert to bf16: dst[n][k] = k<K1 ? A[n][k] : B[n][k-K1]  (K2 may be 0)
__global__ void wcat_kernel(const void* __restrict__ A, const void* __restrict__ B,
                            u16* __restrict__ dst, int N, int K1, int K2,
                            const int* __restrict__ flags) {
    int i = blockIdx.x * blockDim.x + threadIdx.x;
    int K = K1 + K2;
    if (i >= N * K) return;
    int n = i / K, k = i % K;
    const void* src; int idx;
    if (k < K1) { src = A; idx = n * K1 + k; }
    else        { src = B; idx = n * K2 + (k - K1); }
    u16 v;
    if (flags[0]) v = ((const u16*)src)[idx];
    else          v = f2bf(((const float*)src)[idx]);
    dst[i] = v;
}

__global__ void mask_kernel(const void* __restrict__ src, float* __restrict__ dst,
                            int n, const int* __restrict__ flags) {
    int i = blockIdx.x * blockDim.x + threadIdx.x;
    if (i >= n) return;
    int fmt = flags[1];
    float m;
    if (fmt == 0)      m = ((const u8*)src)[i] ? 1.f : 0.f;
    else if (fmt == 1) m = ((const int*)src)[i] ? 1.f : 0.f;
    else if (fmt == 2) m = (((const float*)src)[i] != 0.f) ? 1.f : 0.f;
    else               m = (((const u16*)src)[i] != 0) ? 1.f : 0.f;
    dst[i] = m;
}

// ---------------- CSR build (counting sort by dst) ----------------
__global__ void hist_kernel(const int* __restrict__ ei, int* __restrict__ deg,
                            int* __restrict__ rank) {
    int i = blockIdx.x * blockDim.x + threadIdx.x;
    if (i >= N_EDGES) return;
    int d = ei[N_EDGES + i];
    rank[i] = atomicAdd(&deg[d], 1);
}

__global__ void partial_kernel(const int* __restrict__ deg, int* __restrict__ partial) {
    __shared__ int sh[256];
    int t = threadIdx.x;
    int i = blockIdx.x * 256 + t;
    sh[t] = (i < N_NODES) ? deg[i] : 0;
    __syncthreads();
    for (int s = 128; s > 0; s >>= 1) {
        if (t < s) sh[t] += sh[t + s];
        __syncthreads();
    }
    if (t == 0) partial[blockIdx.x] = sh[0];
}

__global__ void scanp_kernel(const int* __restrict__ partial, int* __restrict__ pscan, int nb) {
    __shared__ int sh[256];
    int t = threadIdx.x;
    int v = (t < nb) ? partial[t] : 0;
    sh[t] = v;
    __syncthreads();
    for (int o = 1; o < 256; o <<= 1) {
        int u = (t >= o) ? sh[t - o] : 0;
        __syncthreads();
        sh[t] += u;
        __syncthreads();
    }
    if (t < nb) pscan[t] = sh[t] - v;   // exclusive
}

__global__ void rowptr_kernel(const int* __restrict__ deg, const int* __restrict__ pscan,
                              int* __restrict__ row_ptr) {
    __shared__ int sh[256];
    int t = threadIdx.x;
    int i = blockIdx.x * 256 + t;
    int v = (i < N_NODES) ? deg[i] : 0;
    sh[t] = v;
    __syncthreads();
    for (int o = 1; o < 256; o <<= 1) {
        int u = (t >= o) ? sh[t - o] : 0;
        __syncthreads();
        sh[t] += u;
        __syncthreads();
    }
    if (i <= N_NODES) row_ptr[i] = pscan[blockIdx.x] + sh[t] - v;
}

__global__ void scatter_csr_kernel(const int* __restrict__ ei, const int* __restrict__ rank,
                                   const int* __restrict__ row_ptr,
                                   const float* __restrict__ maskf,
                                   int* __restrict__ srcs, float* __restrict__ maskp) {
    int i = blockIdx.x * blockDim.x + threadIdx.x;
    if (i >= N_EDGES) return;
    int d = ei[N_EDGES + i];
    int p = row_ptr[d] + rank[i];
    srcs[p] = ei[i];
    maskp[p] = maskf[i];
}

// ---------------- CSR gathers (one wave per node), write MEAN as bf16 ----------------
__global__ __launch_bounds__(256) void gather1_kernel(const int* __restrict__ row_ptr,
                                                      const int* __restrict__ srcs,
                                                      const u16* __restrict__ xb,
                                                      u16* __restrict__ aggb) {
    int wid = (blockIdx.x * blockDim.x + threadIdx.x) >> 6;
    int lane = threadIdx.x & 63;
    if (wid >= N_NODES) return;
    int start = row_ptr[wid], end = row_ptr[wid + 1];
    float ax = 0.f, ay = 0.f;
    for (int e = start; e < end; e++) {
        int s = srcs[e];
        u32 v = *(const u32*)(xb + (size_t)s * IN_CH + lane * 2);
        ax += bf2f((u16)v);
        ay += bf2f((u16)(v >> 16));
    }
    float inv = 1.f / fmaxf((float)(end - start), 1.f);
    u32 o = (u32)f2bf(ax * inv) | ((u32)f2bf(ay * inv) << 16);
    *(u32*)(aggb + (size_t)wid * IN_CH + lane * 2) = o;
}

__global__ __launch_bounds__(256) void gather2_kernel(const int* __restrict__ row_ptr,
                                                      const int* __restrict__ srcs,
                                                      const float* __restrict__ maskp,
                                                      const u16* __restrict__ h1b,
                                                      u16* __restrict__ aggb) {
    int wid = (blockIdx.x * blockDim.x + threadIdx.x) >> 6;
    int lane = threadIdx.x & 63;
    if (wid >= N_NODES) return;
    int start = row_ptr[wid], end = row_ptr[wid + 1];
    float a0 = 0.f, a1 = 0.f, a2 = 0.f, a3 = 0.f, c = 0.f;
    for (int e = start; e < end; e++) {
        float m = maskp[e];
        if (m != 0.f) {
            int s = srcs[e];
            const u16* p = h1b + (size_t)s * HID + lane * 4;
            u32 v0 = *(const u32*)p;
            u32 v1 = *(const u32*)(p + 2);
            a0 += bf2f((u16)v0) * m;
            a1 += bf2f((u16)(v0 >> 16)) * m;
            a2 += bf2f((u16)v1) * m;
            a3 += bf2f((u16)(v1 >> 16)) * m;
            c += m;
        }
    }
    float inv = 1.f / fmaxf(c, 1.f);
    u32 o0 = (u32)f2bf(a0 * inv) | ((u32)f2bf(a1 * inv) << 16);
    u32 o1 = (u32)f2bf(a2 * inv) | ((u32)f2bf(a3 * inv) << 16);
    u16* p = aggb + (size_t)wid * HID + lane * 4;
    *(u32*)p = o0;
    *(u32*)(p + 2) = o1;
}

// ---------------- layer 1 MFMA GEMM ----------------
// A = [agg1 (128) | x (128)], K=256; acc1 = A @ Wc1^T (+b1, norm); accs = x @ Ws^T
// h1 = tanh(norm(acc1+b1) + accs + bs), stored bf16.
__global__ __launch_bounds__(256) void sage1_kernel(const u16* __restrict__ xb,
                                                    const u16* __restrict__ aggb,
                                                    const u16* __restrict__ Wc1,
                                                    const u16* __restrict__ Wsb,
                                                    const float* __restrict__ b1f,
                                                    const float* __restrict__ bsf,
                                                    u16* __restrict__ h1b) {
    __shared__ float red[32][4];
    __shared__ float invn[32];
    int tid = threadIdx.x;
    int wave = tid >> 6, lane = tid & 63;
    int q = lane >> 4, c = lane & 15;
    int n0 = wave * 64;
    int m_base = blockIdx.x * 32;
    int koff = q * 8;

    f32x4 acc1[2][4], accs[2][4];
    const f32x4 z = {0.f, 0.f, 0.f, 0.f};
#pragma unroll
    for (int mt = 0; mt < 2; mt++)
#pragma unroll
        for (int nt = 0; nt < 4; nt++) { acc1[mt][nt] = z; accs[mt][nt] = z; }

#pragma unroll
    for (int kt = 0; kt < 8; kt++) {
        int k = kt * 32 + koff;
        short8 a0, a1;
        if (kt < 4) {
            a0 = ld8(aggb + (size_t)(m_base + c) * IN_CH + k);
            a1 = ld8(aggb + (size_t)(m_base + 16 + c) * IN_CH + k);
        } else {
            a0 = ld8(xb + (size_t)(m_base + c) * IN_CH + (k - 128));
            a1 = ld8(xb + (size_t)(m_base + 16 + c) * IN_CH + (k - 128));
        }
#pragma unroll
        for (int nt = 0; nt < 4; nt++) {
            int n = n0 + nt * 16 + c;
            short8 b = ld8(Wc1 + (size_t)n * 256 + k);
            acc1[0][nt] = __builtin_amdgcn_mfma_f32_16x16x32_bf16(a0, b, acc1[0][nt], 0, 0, 0);
            acc1[1][nt] = __builtin_amdgcn_mfma_f32_16x16x32_bf16(a1, b, acc1[1][nt], 0, 0, 0);
        }
        if (kt >= 4) {
#pragma unroll
            for (int nt = 0; nt < 4; nt++) {
                int n = n0 + nt * 16 + c;
                short8 b = ld8(Wsb + (size_t)n * 128 + (k - 128));
                accs[0][nt] = __builtin_amdgcn_mfma_f32_16x16x32_bf16(a0, b, accs[0][nt], 0, 0, 0);
                accs[1][nt] = __builtin_amdgcn_mfma_f32_16x16x32_bf16(a1, b, accs[1][nt], 0, 0, 0);
            }
        }
    }

    // epilogue: v = acc1 + b1[col]; norm over 256 cols; h = v/nrm + accs + bs[col]; tanh
    float bcol[4], bscol[4];
#pragma unroll
    for (int nt = 0; nt < 4; nt++) {
        bcol[nt] = b1f[n0 + nt * 16 + c];
        bscol[nt] = bsf[n0 + nt * 16 + c];
    }
    float s[2][4];
#pragma unroll
    for (int mt = 0; mt < 2; mt++)
#pragma unroll
        for (int r = 0; r < 4; r++) {
            float t = 0.f;
#pragma unroll
            for (int nt = 0; nt < 4; nt++) {
                float v = acc1[mt][nt][r] + bcol[nt];
                acc1[mt][nt][r] = v;
                t += v * v;
            }
            s[mt][r] = t;
        }
#pragma unroll
    for (int off = 1; off < 16; off <<= 1) {
#pragma unroll
        for (int mt = 0; mt < 2; mt++)
#pragma unroll
            for (int r = 0; r < 4; r++)
                s[mt][r] += __shfl_xor(s[mt][r], off, 64);
    }
    if (c == 0) {
#pragma unroll
        for (int mt = 0; mt < 2; mt++)
#pragma unroll
            for (int r = 0; r < 4; r++)
                red[mt * 16 + q * 4 + r][wave] = s[mt][r];
    }
    __syncthreads();
    if (tid < 32) {
        float t = red[tid][0] + red[tid][1] + red[tid][2] + red[tid][3];
        invn[tid] = 1.f / fmaxf(sqrtf(t), 1e-12f);
    }
    __syncthreads();
#pragma unroll
    for (int mt = 0; mt < 2; mt++)
#pragma unroll
        for (int r = 0; r < 4; r++) {
            int rl = mt * 16 + q * 4 + r;
            int row = m_base + rl;
            if (row < N_NODES) {
                float iv = invn[rl];
#pragma unroll
                for (int nt = 0; nt < 4; nt++) {
                    float h = acc1[mt][nt][r] * iv + accs[mt][nt][r] + bscol[nt];
                    h1b[(size_t)row * HID + n0 + nt * 16 + c] = f2bf(tanhf(h));
                }
            }
        }
}

// ---------------- layer 2 MFMA GEMM ----------------
// A = [agg2 (256) | h1 (256)], K=512; h2 = tanh(norm(A@Wc2^T + b2)), stored bf16.
__global__ __launch_bounds__(256) void sage2_kernel(const u16* __restrict__ h1b,
                                                    const u16* __restrict__ aggb,
                                                    const u16* __restrict__ Wc2,
                                                    const float* __restrict__ b2f,
                                                    u16* __restrict__ h2b) {
    __shared__ float red[32][4];
    __shared__ float invn[32];
    int tid = threadIdx.x;
    int wave = tid >> 6, lane = tid & 63;
    int q = lane >> 4, c = lane & 15;
    int n0 = wave * 64;
    int m_base = blockIdx.x * 32;
    int koff = q * 8;

    f32x4 acc[2][4];
    const f32x4 z = {0.f, 0.f, 0.f, 0.f};
#pragma unroll
    for (int mt = 0; mt < 2; mt++)
#pragma unroll
        for (int nt = 0; nt < 4; nt++) acc[mt][nt] = z;

#pragma unroll
    for (int kt = 0; kt < 16; kt++) {
        int k = kt * 32 + koff;
        short8 a0, a1;
        if (kt < 8) {
            a0 = ld8(aggb + (size_t)(m_base + c) * HID + k);
            a1 = ld8(aggb + (size_t)(m_base + 16 + c) * HID + k);
        } else {
            a0 = ld8(h1b + (size_t)(m_base + c) * HID + (k - 256));
            a1 = ld8(h1b + (size_t)(m_base + 16 + c) * HID + (k - 256));
        }
#pragma unroll
        for (int nt = 0; nt < 4; nt++) {
            int n = n0 + nt * 16 + c;
            short8 b = ld8(Wc2 + (size_t)n * 512 + k);
            acc[0][nt] = __builtin_amdgcn_mfma_f32_16x16x32_bf16(a0, b, acc[0][nt], 0, 0, 0);
            acc[1][nt] = __builtin_amdgcn_mfma_f32_16x16x32_bf16(a1, b, acc[1][nt], 0, 0, 0);
        }
    }

    float bcol[4];
#pragma unroll
    for (int nt = 0; nt < 4; nt++) bcol[nt] = b2f[n0 + nt * 16 + c];
    float s[2][4];
#pragma unroll
    for (int mt = 0; mt < 2; mt++)
#pragma unroll
        for (int r = 0; r < 4; r++) {
            float t = 0.f;
#pragma unroll
            for (int nt = 0; nt < 4; nt++) {
                float v = acc[mt][nt][r] + bcol[nt];
                acc[mt][nt][r] = v;
                t += v * v;
            }
            s[mt][r] = t;
        }
#pragma unroll
    for (int off = 1; off < 16; off <<= 1) {
#pragma unroll
        for (int mt = 0; mt < 2; mt++)
#pragma unroll
            for (int r = 0; r < 4; r++)
                s[mt][r] += __shfl_xor(s[mt][r], off, 64);
    }
    if (c == 0) {
#pragma unroll
        for (int mt = 0; mt < 2; mt++)
#pragma unroll
            for (int r = 0; r < 4; r++)
                red[mt * 16 + q * 4 + r][wave] = s[mt][r];
    }
    __syncthreads();
    if (tid < 32) {
        float t = red[tid][0] + red[tid][1] + red[tid][2] + red[tid][3];
        invn[tid] = 1.f / fmaxf(sqrtf(t), 1e-12f);
    }
    __syncthreads();
#pragma unroll
    for (int mt = 0; mt < 2; mt++)
#pragma unroll
        for (int r = 0; r < 4; r++) {
            int rl = mt * 16 + q * 4 + r;
            int row = m_base + rl;
            if (row < N_NODES) {
                float iv = invn[rl];
#pragma unroll
                for (int nt = 0; nt < 4; nt++)
                    h2b[(size_t)row * HID + n0 + nt * 16 + c] = f2bf(tanhf(acc[mt][nt][r] * iv));
            }
        }
}

// ---------------- final MFMA projection ----------------
// out = h2 @ Wo^T + bo, N=128, K=256
__global__ __launch_bounds__(256) void final_kernel(const u16* __restrict__ h2b,
                                                    const u16* __restrict__ Wob,
                                                    const float* __restrict__ bof,
                                                    void* __restrict__ out,
                                                    const int* __restrict__ flags) {
    int tid = threadIdx.x;
    int wave = tid >> 6, lane = tid & 63;
    int q = lane >> 4, c = lane & 15;
    int n0 = wave * 32;
    int m_base = blockIdx.x * 32;
    int koff = q * 8;

    f32x4 acc[2][2];
    const f32x4 z = {0.f, 0.f, 0.f, 0.f};
#pragma unroll
    for (int mt = 0; mt < 2; mt++)
#pragma unroll
        for (int nt = 0; nt < 2; nt++) acc[mt][nt] = z;

#pragma unroll
    for (int kt = 0; kt < 8; kt++) {
        int k = kt * 32 + koff;
        short8 a0 = ld8(h2b + (size_t)(m_base + c) * HID + k);
        short8 a1 = ld8(h2b + (size_t)(m_base + 16 + c) * HID + k);
#pragma unroll
        for (int nt = 0; nt < 2; nt++) {
            int n = n0 + nt * 16 + c;
            short8 b = ld8(Wob + (size_t)n * 256 + k);
            acc[0][nt] = __builtin_amdgcn_mfma_f32_16x16x32_bf16(a0, b, acc[0][nt], 0, 0, 0);
            acc[1][nt] = __builtin_amdgcn_mfma_f32_16x16x32_bf16(a1, b, acc[1][nt], 0, 0, 0);
        }
    }
    float bcol[2];
#pragma unroll
    for (int nt = 0; nt < 2; nt++) bcol[nt] = bof[n0 + nt * 16 + c];
    int isbf = flags[0];
#pragma unroll
    for (int mt = 0; mt < 2; mt++)
#pragma unroll
        for (int r = 0; r < 4; r++) {
            int row = m_base + mt * 16 + q * 4 + r;
            if (row < N_NODES) {
#pragma unroll
                for (int nt = 0; nt < 2; nt++) {
                    float v = acc[mt][nt][r] + bcol[nt];
                    int col = n0 + nt * 16 + c;
                    if (isbf) ((u16*)out)[(size_t)row * OUT_CH + col] = f2bf(v);
                    else      ((float*)out)[(size_t)row * OUT_CH + col] = v;
                }
            }
        }
}

extern "C" void kernel_launch(void* const* d_in, const int* in_sizes, int n_in,
                              void* d_out, int out_size, void* d_ws, size_t ws_size,
                              hipStream_t stream) {
    const void* x    = d_in[0];
    const int*  ei   = (const int*)d_in[1];
    const void* em   = d_in[2];
    const void* W1l  = d_in[3];
    const void* b1   = d_in[4];
    const void* W1r  = d_in[5];
    const void* Ws   = d_in[6];
    const void* bs   = d_in[7];
    const void* W2l  = d_in[8];
    const void* b2   = d_in[9];
    const void* W2r  = d_in[10];
    const void* Wo   = d_in[11];
    const void* bo   = d_in[12];

    char* p = (char*)d_ws;
    auto carve = [&](size_t bytes) { char* r = p; p += (bytes + 63) & ~(size_t)63; return r; };
    int*   flags  = (int*)carve(256);
    u16*   xb     = (u16*)carve((size_t)N_PAD * IN_CH * 2);
    u16*   h1b    = (u16*)carve((size_t)N_PAD * HID * 2);
    u16*   aggb   = (u16*)carve((size_t)N_PAD * HID * 2);   // layer1 view: [N_PAD][128]
    u16*   h2b    = (u16*)carve((size_t)N_PAD * HID * 2);
    u16*   Wc1    = (u16*)carve(256 * 256 * 2);
    u16*   Wsb    = (u16*)carve(256 * 128 * 2);
    u16*   Wc2    = (u16*)carve(256 * 512 * 2);
    u16*   Wob    = (u16*)carve(128 * 256 * 2);
    float* b1f    = (float*)carve(256 * 4);
    float* bsf    = (float*)carve(256 * 4);
    float* b2f    = (float*)carve(256 * 4);
    float* bof    = (float*)carve(128 * 4);
    int*   deg    = (int*)carve(50056 * 4);
    int*   row_ptr= (int*)carve(50056 * 4);
    int*   partial= (int*)carve(256 * 4);
    int*   pscan  = (int*)carve(256 * 4);
    int*   rank   = (int*)carve((size_t)N_EDGES * 4);
    int*   srcs   = (int*)carve((size_t)N_EDGES * 4);
    float* maskf  = (float*)carve((size_t)N_EDGES * 4);
    float* maskp  = (float*)carve((size_t)N_EDGES * 4);
    (void)ws_size; (void)in_sizes; (void)n_in; (void)out_size;

    detect_kernel<<<1, 64, 0, stream>>>((const u16*)x, (const u8*)em, flags);

    // bf16 conversions / weight concats
    wcat_kernel<<<(N_NODES * IN_CH + 255) / 256, 256, 0, stream>>>(x, x, xb, 1, N_NODES * IN_CH, 0, flags);
    wcat_kernel<<<(256 * 256 + 255) / 256, 256, 0, stream>>>(W1l, W1r, Wc1, 256, 128, 128, flags);
    wcat_kernel<<<(256 * 128 + 255) / 256, 256, 0, stream>>>(Ws, Ws, Wsb, 1, 256 * 128, 0, flags);
    wcat_kernel<<<(256 * 512 + 255) / 256, 256, 0, stream>>>(W2l, W2r, Wc2, 256, 256, 256, flags);
    wcat_kernel<<<(128 * 256 + 255) / 256, 256, 0, stream>>>(Wo, Wo, Wob, 1, 128 * 256, 0, flags);
    convert_kernel<<<1, 256, 0, stream>>>(b1, b1f, 256, flags);
    convert_kernel<<<1, 256, 0, stream>>>(bs, bsf, 256, flags);
    convert_kernel<<<1, 256, 0, stream>>>(b2, b2f, 256, flags);
    convert_kernel<<<1, 256, 0, stream>>>(bo, bof, 128, flags);
    mask_kernel<<<(N_EDGES + 255) / 256, 256, 0, stream>>>(em, maskf, N_EDGES, flags);

    // ---- CSR build (shared by both layers) ----
    hipMemsetAsync(deg, 0, 50056 * sizeof(int), stream);
    hist_kernel<<<(N_EDGES + 255) / 256, 256, 0, stream>>>(ei, deg, rank);
    const int NB = (N_NODES + 255) / 256;
    partial_kernel<<<NB, 256, 0, stream>>>(deg, partial);
    scanp_kernel<<<1, 256, 0, stream>>>(partial, pscan, NB);
    rowptr_kernel<<<NB, 256, 0, stream>>>(deg, pscan, row_ptr);
    scatter_csr_kernel<<<(N_EDGES + 255) / 256, 256, 0, stream>>>(ei, rank, row_ptr, maskf, srcs, maskp);

    const int GB = (N_NODES + 31) / 32;   // 1563 GEMM blocks

    // ---- layer 1 ----
    gather1_kernel<<<(N_NODES * 64) / 256, 256, 0, stream>>>(row_ptr, srcs, xb, aggb);
    sage1_kernel<<<GB, 256, 0, stream>>>(xb, aggb, Wc1, Wsb, b1f, bsf, h1b);

    // ---- layer 2 ----
    gather2_kernel<<<(N_NODES * 64) / 256, 256, 0, stream>>>(row_ptr, srcs, maskp, h1b, aggb);
    sage2_kernel<<<GB, 256, 0, stream>>>(h1b, aggb, Wc2, b2f, h2b);

    final_kernel<<<GB, 256, 0, stream>>>(h2b, Wob, bof, d_out, flags);
}

// Round 4
// 495.324 us; speedup vs baseline: 6.3310x; 1.5638x over previous
//
#include <hip/hip_runtime.h>
#include <hip/hip_bf16.h>

#define N_NODES 50000
#define N_PAD   50016
#define N_EDGES 600000
#define IN_CH 128
#define HID 256
#define OUT_CH 128

typedef unsigned short u16;
typedef unsigned char u8;
typedef unsigned int u32;

typedef __attribute__((ext_vector_type(8))) short short8;
typedef __attribute__((ext_vector_type(4))) float f32x4;

__device__ __forceinline__ float bf2f(u16 v) {
    unsigned u = ((unsigned)v) << 16;
    return __uint_as_float(u);
}
__device__ __forceinline__ u16 f2bf(float f) {
    unsigned u = __float_as_uint(f);
    u += 0x7FFF + ((u >> 16) & 1);   // round-to-nearest-even
    return (u16)(u >> 16);
}
__device__ __forceinline__ short8 ld8(const u16* p) {
    return *(const short8*)p;        // 16B vector load (aligned by construction)
}

// ---------------- format detection (one wave, lane-parallel) ----------------
// flags[0]: 1 if float tensors are bf16, 0 if f32
// flags[1]: mask format: 0=u8, 1=i32, 2=f32, 3=bf16
__global__ void detect_kernel(const u16* __restrict__ xu, const u8* __restrict__ mb,
                              int* __restrict__ flags) {
    int lane = threadIdx.x & 63;

    // x ~ N(0,1): bf16 storage -> every u16 has a sane exponent field.
    // 256 u16 = 128 u32; 2 u32 per lane, independent loads.
    int inr = 0;
    {
        u32 w0 = ((const u32*)xu)[lane * 2 + 0];
        u32 w1 = ((const u32*)xu)[lane * 2 + 1];
        u16 h[4] = {(u16)w0, (u16)(w0 >> 16), (u16)w1, (u16)(w1 >> 16)};
#pragma unroll
        for (int j = 0; j < 4; j++) {
            int e = (h[j] >> 7) & 0xFF;
            if (e >= 100 && e <= 133) inr++;
        }
    }

    // mask bytes: 4096 bytes = 1024 u32; 16 u32 per lane, independent loads.
    int c1 = 0, c23 = 0, h3f_1 = 0, h3f_3 = 0;
#pragma unroll
    for (int t = 0; t < 16; t++) {
        u32 w = ((const u32*)mb)[t * 64 + lane];
        u8 b1 = (u8)(w >> 8), b2 = (u8)(w >> 16), b3 = (u8)(w >> 24);
        if (b1) c1++;
        if (b1 == 0x3F) h3f_1 = 1;
        if (b2) c23++;
        if (b3) c23++;
        if (b3 == 0x3F) h3f_3 = 1;
    }

#pragma unroll
    for (int off = 32; off > 0; off >>= 1) {
        inr   += __shfl_xor(inr, off, 64);
        c1    += __shfl_xor(c1, off, 64);
        c23   += __shfl_xor(c23, off, 64);
        h3f_1 |= __shfl_xor(h3f_1, off, 64);
        h3f_3 |= __shfl_xor(h3f_3, off, 64);
    }

    if (lane == 0 && blockIdx.x == 0) {
        flags[0] = (inr >= 200) ? 1 : 0;
        int fmt;
        if (h3f_1) fmt = 3;              // bf16
        else if (h3f_3) fmt = 2;         // f32
        else if (c1 + c23 > 0) fmt = 0;  // u8 bool
        else fmt = 1;                    // int32
        flags[1] = fmt;
    }
}

// ---------------- conversions ----------------
// all four biases in one launch: dst layout [b1(256) | bs(256) | b2(256) | bo(128)]
__global__ void biases_kernel(const void* __restrict__ b1, const void* __restrict__ bs,
                              const void* __restrict__ b2, const void* __restrict__ bo,
                              float* __restrict__ dst, const int* __restrict__ flags) {
    int i = blockIdx.x * blockDim.x + threadIdx.x;
    if (i >= 896) return;
    const void* src; int idx;
    if (i < 256)      { src = b1; idx = i; }
    else if (i < 512) { src = bs; idx = i - 256; }
    else if (i < 768) { src = b2; idx = i - 512; }
    else              { src = bo; idx = i - 768; }
    float v;
    if (flags[0]) v = bf2f(((const u16*)src)[idx]);
    else          v = ((const float*)src)[idx];
    dst[i] = v;
}

// concat-convert to bf16: dst[n][k] = k<K1 ? A[n][k] : B[n][k-K1]  (K2 may be 0)
__global__ void wcat_kernel(const void* __restrict__ A, const void* __restrict__ B,
                            u16* __restrict__ dst, int N, int K1, int K2,
                            const int* __restrict__ flags) {
    int i = blockIdx.x * blockDim.x + threadIdx.x;
    int K = K1 + K2;
    if (i >= N * K) return;
    int n = i / K, k = i % K;
    const void* src; int idx;
    if (k < K1) { src = A; idx = n * K1 + k; }
    else        { src = B; idx = n * K2 + (k - K1); }
    u16 v;
    if (flags[0]) v = ((const u16*)src)[idx];
    else          v = f2bf(((const float*)src)[idx]);
    dst[i] = v;
}

__global__ void mask_kernel(const void* __restrict__ src, float* __restrict__ dst,
                            int n, const int* __restrict__ flags) {
    int i = blockIdx.x * blockDim.x + threadIdx.x;
    if (i >= n) return;
    int fmt = flags[1];
    float m;
    if (fmt == 0)      m = ((const u8*)src)[i] ? 1.f : 0.f;
    else if (fmt == 1) m = ((const int*)src)[i] ? 1.f : 0.f;
    else if (fmt == 2) m = (((const float*)src)[i] != 0.f) ? 1.f : 0.f;
    else               m = (((const u16*)src)[i] != 0) ? 1.f : 0.f;
    dst[i] = m;
}

// ---------------- CSR build (counting sort by dst) ----------------
__global__ void hist_kernel(const int* __restrict__ ei, int* __restrict__ deg,
                            int* __restrict__ rank) {
    int i = blockIdx.x * blockDim.x + threadIdx.x;
    if (i >= N_EDGES) return;
    int d = ei[N_EDGES + i];
    rank[i] = atomicAdd(&deg[d], 1);
}

__global__ void partial_kernel(const int* __restrict__ deg, int* __restrict__ partial) {
    __shared__ int sh[256];
    int t = threadIdx.x;
    int i = blockIdx.x * 256 + t;
    sh[t] = (i < N_NODES) ? deg[i] : 0;
    __syncthreads();
    for (int s = 128; s > 0; s >>= 1) {
        if (t < s) sh[t] += sh[t + s];
        __syncthreads();
    }
    if (t == 0) partial[blockIdx.x] = sh[0];
}

__global__ void scanp_kernel(const int* __restrict__ partial, int* __restrict__ pscan, int nb) {
    __shared__ int sh[256];
    int t = threadIdx.x;
    int v = (t < nb) ? partial[t] : 0;
    sh[t] = v;
    __syncthreads();
    for (int o = 1; o < 256; o <<= 1) {
        int u = (t >= o) ? sh[t - o] : 0;
        __syncthreads();
        sh[t] += u;
        __syncthreads();
    }
    if (t < nb) pscan[t] = sh[t] - v;   // exclusive
}

__global__ void rowptr_kernel(const int* __restrict__ deg, const int* __restrict__ pscan,
                              int* __restrict__ row_ptr) {
    __shared__ int sh[256];
    int t = threadIdx.x;
    int i = blockIdx.x * 256 + t;
    int v = (i < N_NODES) ? deg[i] : 0;
    sh[t] = v;
    __syncthreads();
    for (int o = 1; o < 256; o <<= 1) {
        int u = (t >= o) ? sh[t - o] : 0;
        __syncthreads();
        sh[t] += u;
        __syncthreads();
    }
    if (i <= N_NODES) row_ptr[i] = pscan[blockIdx.x] + sh[t] - v;
}

__global__ void scatter_csr_kernel(const int* __restrict__ ei, const int* __restrict__ rank,
                                   const int* __restrict__ row_ptr,
                                   const float* __restrict__ maskf,
                                   int* __restrict__ srcs, float* __restrict__ maskp) {
    int i = blockIdx.x * blockDim.x + threadIdx.x;
    if (i >= N_EDGES) return;
    int d = ei[N_EDGES + i];
    int p = row_ptr[d] + rank[i];
    srcs[p] = ei[i];
    maskp[p] = maskf[i];
}

// ---------------- CSR gathers (one wave per node), write MEAN as bf16 ----------------
__global__ __launch_bounds__(256) void gather1_kernel(const int* __restrict__ row_ptr,
                                                      const int* __restrict__ srcs,
                                                      const u16* __restrict__ xb,
                                                      u16* __restrict__ aggb) {
    int wid = (blockIdx.x * blockDim.x + threadIdx.x) >> 6;
    int lane = threadIdx.x & 63;
    if (wid >= N_NODES) return;
    int start = row_ptr[wid], end = row_ptr[wid + 1];
    float ax = 0.f, ay = 0.f;
    for (int e = start; e < end; e++) {
        int s = srcs[e];
        u32 v = *(const u32*)(xb + (size_t)s * IN_CH + lane * 2);
        ax += bf2f((u16)v);
        ay += bf2f((u16)(v >> 16));
    }
    float inv = 1.f / fmaxf((float)(end - start), 1.f);
    u32 o = (u32)f2bf(ax * inv) | ((u32)f2bf(ay * inv) << 16);
    *(u32*)(aggb + (size_t)wid * IN_CH + lane * 2) = o;
}

__global__ __launch_bounds__(256) void gather2_kernel(const int* __restrict__ row_ptr,
                                                      const int* __restrict__ srcs,
                                                      const float* __restrict__ maskp,
                                                      const u16* __restrict__ h1b,
                                                      u16* __restrict__ aggb) {
    int wid = (blockIdx.x * blockDim.x + threadIdx.x) >> 6;
    int lane = threadIdx.x & 63;
    if (wid >= N_NODES) return;
    int start = row_ptr[wid], end = row_ptr[wid + 1];
    float a0 = 0.f, a1 = 0.f, a2 = 0.f, a3 = 0.f, c = 0.f;
    for (int e = start; e < end; e++) {
        float m = maskp[e];
        if (m != 0.f) {
            int s = srcs[e];
            const u16* p = h1b + (size_t)s * HID + lane * 4;
            u32 v0 = *(const u32*)p;
            u32 v1 = *(const u32*)(p + 2);
            a0 += bf2f((u16)v0) * m;
            a1 += bf2f((u16)(v0 >> 16)) * m;
            a2 += bf2f((u16)v1) * m;
            a3 += bf2f((u16)(v1 >> 16)) * m;
            c += m;
        }
    }
    float inv = 1.f / fmaxf(c, 1.f);
    u32 o0 = (u32)f2bf(a0 * inv) | ((u32)f2bf(a1 * inv) << 16);
    u32 o1 = (u32)f2bf(a2 * inv) | ((u32)f2bf(a3 * inv) << 16);
    u16* p = aggb + (size_t)wid * HID + lane * 4;
    *(u32*)p = o0;
    *(u32*)(p + 2) = o1;
}

// ---------------- layer 1 MFMA GEMM ----------------
// A = [agg1 (128) | x (128)], K=256; acc1 = A @ Wc1^T (+b1, norm); accs = x @ Ws^T
// h1 = tanh(norm(acc1+b1) + accs + bs), stored bf16.
__global__ __launch_bounds__(256) void sage1_kernel(const u16* __restrict__ xb,
                                                    const u16* __restrict__ aggb,
                                                    const u16* __restrict__ Wc1,
                                                    const u16* __restrict__ Wsb,
                                                    const float* __restrict__ b1f,
                                                    const float* __restrict__ bsf,
                                                    u16* __restrict__ h1b) {
    __shared__ float red[32][4];
    __shared__ float invn[32];
    int tid = threadIdx.x;
    int wave = tid >> 6, lane = tid & 63;
    int q = lane >> 4, c = lane & 15;
    int n0 = wave * 64;
    int m_base = blockIdx.x * 32;
    int koff = q * 8;

    f32x4 acc1[2][4], accs[2][4];
    const f32x4 z = {0.f, 0.f, 0.f, 0.f};
#pragma unroll
    for (int mt = 0; mt < 2; mt++)
#pragma unroll
        for (int nt = 0; nt < 4; nt++) { acc1[mt][nt] = z; accs[mt][nt] = z; }

#pragma unroll
    for (int kt = 0; kt < 8; kt++) {
        int k = kt * 32 + koff;
        short8 a0, a1;
        if (kt < 4) {
            a0 = ld8(aggb + (size_t)(m_base + c) * IN_CH + k);
            a1 = ld8(aggb + (size_t)(m_base + 16 + c) * IN_CH + k);
        } else {
            a0 = ld8(xb + (size_t)(m_base + c) * IN_CH + (k - 128));
            a1 = ld8(xb + (size_t)(m_base + 16 + c) * IN_CH + (k - 128));
        }
#pragma unroll
        for (int nt = 0; nt < 4; nt++) {
            int n = n0 + nt * 16 + c;
            short8 b = ld8(Wc1 + (size_t)n * 256 + k);
            acc1[0][nt] = __builtin_amdgcn_mfma_f32_16x16x32_bf16(a0, b, acc1[0][nt], 0, 0, 0);
            acc1[1][nt] = __builtin_amdgcn_mfma_f32_16x16x32_bf16(a1, b, acc1[1][nt], 0, 0, 0);
        }
        if (kt >= 4) {
#pragma unroll
            for (int nt = 0; nt < 4; nt++) {
                int n = n0 + nt * 16 + c;
                short8 b = ld8(Wsb + (size_t)n * 128 + (k - 128));
                accs[0][nt] = __builtin_amdgcn_mfma_f32_16x16x32_bf16(a0, b, accs[0][nt], 0, 0, 0);
                accs[1][nt] = __builtin_amdgcn_mfma_f32_16x16x32_bf16(a1, b, accs[1][nt], 0, 0, 0);
            }
        }
    }

    // epilogue: v = acc1 + b1[col]; norm over 256 cols; h = v/nrm + accs + bs[col]; tanh
    float bcol[4], bscol[4];
#pragma unroll
    for (int nt = 0; nt < 4; nt++) {
        bcol[nt] = b1f[n0 + nt * 16 + c];
        bscol[nt] = bsf[n0 + nt * 16 + c];
    }
    float s[2][4];
#pragma unroll
    for (int mt = 0; mt < 2; mt++)
#pragma unroll
        for (int r = 0; r < 4; r++) {
            float t = 0.f;
#pragma unroll
            for (int nt = 0; nt < 4; nt++) {
                float v = acc1[mt][nt][r] + bcol[nt];
                acc1[mt][nt][r] = v;
                t += v * v;
            }
            s[mt][r] = t;
        }
#pragma unroll
    for (int off = 1; off < 16; off <<= 1) {
#pragma unroll
        for (int mt = 0; mt < 2; mt++)
#pragma unroll
            for (int r = 0; r < 4; r++)
                s[mt][r] += __shfl_xor(s[mt][r], off, 64);
    }
    if (c == 0) {
#pragma unroll
        for (int mt = 0; mt < 2; mt++)
#pragma unroll
            for (int r = 0; r < 4; r++)
                red[mt * 16 + q * 4 + r][wave] = s[mt][r];
    }
    __syncthreads();
    if (tid < 32) {
        float t = red[tid][0] + red[tid][1] + red[tid][2] + red[tid][3];
        invn[tid] = 1.f / fmaxf(sqrtf(t), 1e-12f);
    }
    __syncthreads();
#pragma unroll
    for (int mt = 0; mt < 2; mt++)
#pragma unroll
        for (int r = 0; r < 4; r++) {
            int rl = mt * 16 + q * 4 + r;
            int row = m_base + rl;
            if (row < N_NODES) {
                float iv = invn[rl];
#pragma unroll
                for (int nt = 0; nt < 4; nt++) {
                    float h = acc1[mt][nt][r] * iv + accs[mt][nt][r] + bscol[nt];
                    h1b[(size_t)row * HID + n0 + nt * 16 + c] = f2bf(tanhf(h));
                }
            }
        }
}

// ---------------- layer 2 MFMA GEMM ----------------
// A = [agg2 (256) | h1 (256)], K=512; h2 = tanh(norm(A@Wc2^T + b2)), stored bf16.
__global__ __launch_bounds__(256) void sage2_kernel(const u16* __restrict__ h1b,
                                                    const u16* __restrict__ aggb,
                                                    const u16* __restrict__ Wc2,
                                                    const float* __restrict__ b2f,
                                                    u16* __restrict__ h2b) {
    __shared__ float red[32][4];
    __shared__ float invn[32];
    int tid = threadIdx.x;
    int wave = tid >> 6, lane = tid & 63;
    int q = lane >> 4, c = lane & 15;
    int n0 = wave * 64;
    int m_base = blockIdx.x * 32;
    int koff = q * 8;

    f32x4 acc[2][4];
    const f32x4 z = {0.f, 0.f, 0.f, 0.f};
#pragma unroll
    for (int mt = 0; mt < 2; mt++)
#pragma unroll
        for (int nt = 0; nt < 4; nt++) acc[mt][nt] = z;

#pragma unroll
    for (int kt = 0; kt < 16; kt++) {
        int k = kt * 32 + koff;
        short8 a0, a1;
        if (kt < 8) {
            a0 = ld8(aggb + (size_t)(m_base + c) * HID + k);
            a1 = ld8(aggb + (size_t)(m_base + 16 + c) * HID + k);
        } else {
            a0 = ld8(h1b + (size_t)(m_base + c) * HID + (k - 256));
            a1 = ld8(h1b + (size_t)(m_base + 16 + c) * HID + (k - 256));
        }
#pragma unroll
        for (int nt = 0; nt < 4; nt++) {
            int n = n0 + nt * 16 + c;
            short8 b = ld8(Wc2 + (size_t)n * 512 + k);
            acc[0][nt] = __builtin_amdgcn_mfma_f32_16x16x32_bf16(a0, b, acc[0][nt], 0, 0, 0);
            acc[1][nt] = __builtin_amdgcn_mfma_f32_16x16x32_bf16(a1, b, acc[1][nt], 0, 0, 0);
        }
    }

    float bcol[4];
#pragma unroll
    for (int nt = 0; nt < 4; nt++) bcol[nt] = b2f[n0 + nt * 16 + c];
    float s[2][4];
#pragma unroll
    for (int mt = 0; mt < 2; mt++)
#pragma unroll
        for (int r = 0; r < 4; r++) {
            float t = 0.f;
#pragma unroll
            for (int nt = 0; nt < 4; nt++) {
                float v = acc[mt][nt][r] + bcol[nt];
                acc[mt][nt][r] = v;
                t += v * v;
            }
            s[mt][r] = t;
        }
#pragma unroll
    for (int off = 1; off < 16; off <<= 1) {
#pragma unroll
        for (int mt = 0; mt < 2; mt++)
#pragma unroll
            for (int r = 0; r < 4; r++)
                s[mt][r] += __shfl_xor(s[mt][r], off, 64);
    }
    if (c == 0) {
#pragma unroll
        for (int mt = 0; mt < 2; mt++)
#pragma unroll
            for (int r = 0; r < 4; r++)
                red[mt * 16 + q * 4 + r][wave] = s[mt][r];
    }
    __syncthreads();
    if (tid < 32) {
        float t = red[tid][0] + red[tid][1] + red[tid][2] + red[tid][3];
        invn[tid] = 1.f / fmaxf(sqrtf(t), 1e-12f);
    }
    __syncthreads();
#pragma unroll
    for (int mt = 0; mt < 2; mt++)
#pragma unroll
        for (int r = 0; r < 4; r++) {
            int rl = mt * 16 + q * 4 + r;
            int row = m_base + rl;
            if (row < N_NODES) {
                float iv = invn[rl];
#pragma unroll
                for (int nt = 0; nt < 4; nt++)
                    h2b[(size_t)row * HID + n0 + nt * 16 + c] = f2bf(tanhf(acc[mt][nt][r] * iv));
            }
        }
}

// ---------------- final MFMA projection ----------------
// out = h2 @ Wo^T + bo, N=128, K=256
__global__ __launch_bounds__(256) void final_kernel(const u16* __restrict__ h2b,
                                                    const u16* __restrict__ Wob,
                                                    const float* __restrict__ bof,
                                                    void* __restrict__ out,
                                                    const int* __restrict__ flags) {
    int tid = threadIdx.x;
    int wave = tid >> 6, lane = tid & 63;
    int q = lane >> 4, c = lane & 15;
    int n0 = wave * 32;
    int m_base = blockIdx.x * 32;
    int koff = q * 8;

    f32x4 acc[2][2];
    const f32x4 z = {0.f, 0.f, 0.f, 0.f};
#pragma unroll
    for (int mt = 0; mt < 2; mt++)
#pragma unroll
        for (int nt = 0; nt < 2; nt++) acc[mt][nt] = z;

#pragma unroll
    for (int kt = 0; kt < 8; kt++) {
        int k = kt * 32 + koff;
        short8 a0 = ld8(h2b + (size_t)(m_base + c) * HID + k);
        short8 a1 = ld8(h2b + (size_t)(m_base + 16 + c) * HID + k);
#pragma unroll
        for (int nt = 0; nt < 2; nt++) {
            int n = n0 + nt * 16 + c;
            short8 b = ld8(Wob + (size_t)n * 256 + k);
            acc[0][nt] = __builtin_amdgcn_mfma_f32_16x16x32_bf16(a0, b, acc[0][nt], 0, 0, 0);
            acc[1][nt] = __builtin_amdgcn_mfma_f32_16x16x32_bf16(a1, b, acc[1][nt], 0, 0, 0);
        }
    }
    float bcol[2];
#pragma unroll
    for (int nt = 0; nt < 2; nt++) bcol[nt] = bof[n0 + nt * 16 + c];
    int isbf = flags[0];
#pragma unroll
    for (int mt = 0; mt < 2; mt++)
#pragma unroll
        for (int r = 0; r < 4; r++) {
            int row = m_base + mt * 16 + q * 4 + r;
            if (row < N_NODES) {
#pragma unroll
                for (int nt = 0; nt < 2; nt++) {
                    float v = acc[mt][nt][r] + bcol[nt];
                    int col = n0 + nt * 16 + c;
                    if (isbf) ((u16*)out)[(size_t)row * OUT_CH + col] = f2bf(v);
                    else      ((float*)out)[(size_t)row * OUT_CH + col] = v;
                }
            }
        }
}

extern "C" void kernel_launch(void* const* d_in, const int* in_sizes, int n_in,
                              void* d_out, int out_size, void* d_ws, size_t ws_size,
                              hipStream_t stream) {
    const void* x    = d_in[0];
    const int*  ei   = (const int*)d_in[1];
    const void* em   = d_in[2];
    const void* W1l  = d_in[3];
    const void* b1   = d_in[4];
    const void* W1r  = d_in[5];
    const void* Ws   = d_in[6];
    const void* bs   = d_in[7];
    const void* W2l  = d_in[8];
    const void* b2   = d_in[9];
    const void* W2r  = d_in[10];
    const void* Wo   = d_in[11];
    const void* bo   = d_in[12];

    char* p = (char*)d_ws;
    auto carve = [&](size_t bytes) { char* r = p; p += (bytes + 63) & ~(size_t)63; return r; };
    int*   flags  = (int*)carve(256);
    u16*   xb     = (u16*)carve((size_t)N_PAD * IN_CH * 2);
    u16*   h1b    = (u16*)carve((size_t)N_PAD * HID * 2);
    u16*   aggb   = (u16*)carve((size_t)N_PAD * HID * 2);   // layer1 view: [N_PAD][128]
    u16*   h2b    = (u16*)carve((size_t)N_PAD * HID * 2);
    u16*   Wc1    = (u16*)carve(256 * 256 * 2);
    u16*   Wsb    = (u16*)carve(256 * 128 * 2);
    u16*   Wc2    = (u16*)carve(256 * 512 * 2);
    u16*   Wob    = (u16*)carve(128 * 256 * 2);
    float* biasf  = (float*)carve(896 * 4);   // [b1|bs|b2|bo]
    int*   deg    = (int*)carve(50056 * 4);
    int*   row_ptr= (int*)carve(50056 * 4);
    int*   partial= (int*)carve(256 * 4);
    int*   pscan  = (int*)carve(256 * 4);
    int*   rank   = (int*)carve((size_t)N_EDGES * 4);
    int*   srcs   = (int*)carve((size_t)N_EDGES * 4);
    float* maskf  = (float*)carve((size_t)N_EDGES * 4);
    float* maskp  = (float*)carve((size_t)N_EDGES * 4);
    float* b1f = biasf, *bsf = biasf + 256, *b2f = biasf + 512, *bof = biasf + 768;
    (void)ws_size; (void)in_sizes; (void)n_in; (void)out_size;

    detect_kernel<<<1, 64, 0, stream>>>((const u16*)x, (const u8*)em, flags);

    // bf16 conversions / weight concats
    wcat_kernel<<<(N_NODES * IN_CH + 255) / 256, 256, 0, stream>>>(x, x, xb, 1, N_NODES * IN_CH, 0, flags);
    wcat_kernel<<<(256 * 256 + 255) / 256, 256, 0, stream>>>(W1l, W1r, Wc1, 256, 128, 128, flags);
    wcat_kernel<<<(256 * 128 + 255) / 256, 256, 0, stream>>>(Ws, Ws, Wsb, 1, 256 * 128, 0, flags);
    wcat_kernel<<<(256 * 512 + 255) / 256, 256, 0, stream>>>(W2l, W2r, Wc2, 256, 256, 256, flags);
    wcat_kernel<<<(128 * 256 + 255) / 256, 256, 0, stream>>>(Wo, Wo, Wob, 1, 128 * 256, 0, flags);
    biases_kernel<<<4, 256, 0, stream>>>(b1, bs, b2, bo, biasf, flags);
    mask_kernel<<<(N_EDGES + 255) / 256, 256, 0, stream>>>(em, maskf, N_EDGES, flags);

    // ---- CSR build (shared by both layers) ----
    hipMemsetAsync(deg, 0, 50056 * sizeof(int), stream);
    hist_kernel<<<(N_EDGES + 255) / 256, 256, 0, stream>>>(ei, deg, rank);
    const int NB = (N_NODES + 255) / 256;
    partial_kernel<<<NB, 256, 0, stream>>>(deg, partial);
    scanp_kernel<<<1, 256, 0, stream>>>(partial, pscan, NB);
    rowptr_kernel<<<NB, 256, 0, stream>>>(deg, pscan, row_ptr);
    scatter_csr_kernel<<<(N_EDGES + 255) / 256, 256, 0, stream>>>(ei, rank, row_ptr, maskf, srcs, maskp);

    const int GB = (N_NODES + 31) / 32;   // 1563 GEMM blocks

    // ---- layer 1 ----
    gather1_kernel<<<(N_NODES * 64) / 256, 256, 0, stream>>>(row_ptr, srcs, xb, aggb);
    sage1_kernel<<<GB, 256, 0, stream>>>(xb, aggb, Wc1, Wsb, b1f, bsf, h1b);

    // ---- layer 2 ----
    gather2_kernel<<<(N_NODES * 64) / 256, 256, 0, stream>>>(row_ptr, srcs, maskp, h1b, aggb);
    sage2_kernel<<<GB, 256, 0, stream>>>(h1b, aggb, Wc2, b2f, h2b);

    final_kernel<<<GB, 256, 0, stream>>>(h2b, Wob, bof, d_out, flags);
}

// Round 5
// 428.585 us; speedup vs baseline: 7.3168x; 1.1557x over previous
//
#include <hip/hip_runtime.h>
#include <hip/hip_bf16.h>

#define N_NODES 50000
#define N_PAD   50048
#define N_EDGES 600000
#define IN_CH 128
#define HID 256
#define OUT_CH 128

typedef unsigned short u16;
typedef unsigned char u8;
typedef unsigned int u32;

typedef __attribute__((ext_vector_type(8))) short short8;
typedef __attribute__((ext_vector_type(4))) float f32x4;

__device__ __forceinline__ float bf2f(u16 v) {
    unsigned u = ((unsigned)v) << 16;
    return __uint_as_float(u);
}
__device__ __forceinline__ u16 f2bf(float f) {
    unsigned u = __float_as_uint(f);
    u += 0x7FFF + ((u >> 16) & 1);   // round-to-nearest-even
    return (u16)(u >> 16);
}
__device__ __forceinline__ short8 ld8(const u16* p) {
    return *(const short8*)p;        // 16B vector load (aligned by construction)
}

// ---------------- format detection (one wave, lane-parallel) ----------------
// flags[0]: 1 if float tensors are bf16, 0 if f32
// flags[1]: mask format: 0=u8, 1=i32, 2=f32, 3=bf16
__global__ void detect_kernel(const u16* __restrict__ xu, const u8* __restrict__ mb,
                              int* __restrict__ flags) {
    int lane = threadIdx.x & 63;

    int inr = 0;
    {
        u32 w0 = ((const u32*)xu)[lane * 2 + 0];
        u32 w1 = ((const u32*)xu)[lane * 2 + 1];
        u16 h[4] = {(u16)w0, (u16)(w0 >> 16), (u16)w1, (u16)(w1 >> 16)};
#pragma unroll
        for (int j = 0; j < 4; j++) {
            int e = (h[j] >> 7) & 0xFF;
            if (e >= 100 && e <= 133) inr++;
        }
    }

    int c1 = 0, c23 = 0, h3f_1 = 0, h3f_3 = 0;
#pragma unroll
    for (int t = 0; t < 16; t++) {
        u32 w = ((const u32*)mb)[t * 64 + lane];
        u8 b1 = (u8)(w >> 8), b2 = (u8)(w >> 16), b3 = (u8)(w >> 24);
        if (b1) c1++;
        if (b1 == 0x3F) h3f_1 = 1;
        if (b2) c23++;
        if (b3) c23++;
        if (b3 == 0x3F) h3f_3 = 1;
    }

#pragma unroll
    for (int off = 32; off > 0; off >>= 1) {
        inr   += __shfl_xor(inr, off, 64);
        c1    += __shfl_xor(c1, off, 64);
        c23   += __shfl_xor(c23, off, 64);
        h3f_1 |= __shfl_xor(h3f_1, off, 64);
        h3f_3 |= __shfl_xor(h3f_3, off, 64);
    }

    if (lane == 0 && blockIdx.x == 0) {
        flags[0] = (inr >= 200) ? 1 : 0;
        int fmt;
        if (h3f_1) fmt = 3;              // bf16
        else if (h3f_3) fmt = 2;         // f32
        else if (c1 + c23 > 0) fmt = 0;  // u8 bool
        else fmt = 1;                    // int32
        flags[1] = fmt;
    }
}

// ---------------- conversions ----------------
__global__ void biases_kernel(const void* __restrict__ b1, const void* __restrict__ bs,
                              const void* __restrict__ b2, const void* __restrict__ bo,
                              float* __restrict__ dst, const int* __restrict__ flags) {
    int i = blockIdx.x * blockDim.x + threadIdx.x;
    if (i >= 896) return;
    const void* src; int idx;
    if (i < 256)      { src = b1; idx = i; }
    else if (i < 512) { src = bs; idx = i - 256; }
    else if (i < 768) { src = b2; idx = i - 512; }
    else              { src = bo; idx = i - 768; }
    float v;
    if (flags[0]) v = bf2f(((const u16*)src)[idx]);
    else          v = ((const float*)src)[idx];
    dst[i] = v;
}

// concat-convert to bf16: dst[n][k] = k<K1 ? A[n][k] : B[n][k-K1]  (K2 may be 0)
__global__ void wcat_kernel(const void* __restrict__ A, const void* __restrict__ B,
                            u16* __restrict__ dst, int N, int K1, int K2,
                            const int* __restrict__ flags) {
    int i = blockIdx.x * blockDim.x + threadIdx.x;
    int K = K1 + K2;
    if (i >= N * K) return;
    int n = i / K, k = i % K;
    const void* src; int idx;
    if (k < K1) { src = A; idx = n * K1 + k; }
    else        { src = B; idx = n * K2 + (k - K1); }
    u16 v;
    if (flags[0]) v = ((const u16*)src)[idx];
    else          v = f2bf(((const float*)src)[idx]);
    dst[i] = v;
}

// ---------------- CSR build (counting sort by dst) ----------------
__global__ void hist_kernel(const int* __restrict__ ei, int* __restrict__ deg,
                            int* __restrict__ rank) {
    int i = blockIdx.x * blockDim.x + threadIdx.x;
    if (i >= N_EDGES) return;
    int d = ei[N_EDGES + i];
    rank[i] = atomicAdd(&deg[d], 1);
}

__global__ void partial_kernel(const int* __restrict__ deg, int* __restrict__ partial) {
    __shared__ int sh[256];
    int t = threadIdx.x;
    int i = blockIdx.x * 256 + t;
    sh[t] = (i < N_NODES) ? deg[i] : 0;
    __syncthreads();
    for (int s = 128; s > 0; s >>= 1) {
        if (t < s) sh[t] += sh[t + s];
        __syncthreads();
    }
    if (t == 0) partial[blockIdx.x] = sh[0];
}

__global__ void scanp_kernel(const int* __restrict__ partial, int* __restrict__ pscan, int nb) {
    __shared__ int sh[256];
    int t = threadIdx.x;
    int v = (t < nb) ? partial[t] : 0;
    sh[t] = v;
    __syncthreads();
    for (int o = 1; o < 256; o <<= 1) {
        int u = (t >= o) ? sh[t - o] : 0;
        __syncthreads();
        sh[t] += u;
        __syncthreads();
    }
    if (t < nb) pscan[t] = sh[t] - v;   // exclusive
}

__global__ void rowptr_kernel(const int* __restrict__ deg, const int* __restrict__ pscan,
                              int* __restrict__ row_ptr) {
    __shared__ int sh[256];
    int t = threadIdx.x;
    int i = blockIdx.x * 256 + t;
    int v = (i < N_NODES) ? deg[i] : 0;
    sh[t] = v;
    __syncthreads();
    for (int o = 1; o < 256; o <<= 1) {
        int u = (t >= o) ? sh[t - o] : 0;
        __syncthreads();
        sh[t] += u;
        __syncthreads();
    }
    if (i <= N_NODES) row_ptr[i] = pscan[blockIdx.x] + sh[t] - v;
}

// mask decode folded in; mask packed into MSB of srcs (MSB set = dropped edge)
__global__ void scatter_csr_kernel(const int* __restrict__ ei, const int* __restrict__ rank,
                                   const int* __restrict__ row_ptr,
                                   const void* __restrict__ em,
                                   u32* __restrict__ srcs, const int* __restrict__ flags) {
    int i = blockIdx.x * blockDim.x + threadIdx.x;
    if (i >= N_EDGES) return;
    int d = ei[N_EDGES + i];
    int p = row_ptr[d] + rank[i];
    int fmt = flags[1];
    bool keep;
    if (fmt == 0)      keep = ((const u8*)em)[i] != 0;
    else if (fmt == 1) keep = ((const int*)em)[i] != 0;
    else if (fmt == 2) keep = ((const float*)em)[i] != 0.f;
    else               keep = ((const u16*)em)[i] != 0;
    srcs[p] = (u32)ei[i] | (keep ? 0u : 0x80000000u);
}

// ---------------- CSR gathers (one wave per node), write MEAN as bf16 ----------------
__global__ __launch_bounds__(256) void gather1_kernel(const int* __restrict__ row_ptr,
                                                      const u32* __restrict__ srcs,
                                                      const u16* __restrict__ xb,
                                                      u16* __restrict__ aggb) {
    int wid = (blockIdx.x * blockDim.x + threadIdx.x) >> 6;
    int lane = threadIdx.x & 63;
    if (wid >= N_NODES) return;
    int start = row_ptr[wid], end = row_ptr[wid + 1];
    float ax = 0.f, ay = 0.f, bx = 0.f, by = 0.f;
    int e = start;
    for (; e + 2 <= end; e += 2) {
        int s0 = (int)(srcs[e] & 0x7fffffffu);
        int s1 = (int)(srcs[e + 1] & 0x7fffffffu);
        u32 v0 = *(const u32*)(xb + (size_t)s0 * IN_CH + lane * 2);
        u32 v1 = *(const u32*)(xb + (size_t)s1 * IN_CH + lane * 2);
        ax += bf2f((u16)v0); ay += bf2f((u16)(v0 >> 16));
        bx += bf2f((u16)v1); by += bf2f((u16)(v1 >> 16));
    }
    if (e < end) {
        int s0 = (int)(srcs[e] & 0x7fffffffu);
        u32 v0 = *(const u32*)(xb + (size_t)s0 * IN_CH + lane * 2);
        ax += bf2f((u16)v0); ay += bf2f((u16)(v0 >> 16));
    }
    float inv = 1.f / fmaxf((float)(end - start), 1.f);
    u32 o = (u32)f2bf((ax + bx) * inv) | ((u32)f2bf((ay + by) * inv) << 16);
    *(u32*)(aggb + (size_t)wid * IN_CH + lane * 2) = o;
}

__global__ __launch_bounds__(256) void gather2_kernel(const int* __restrict__ row_ptr,
                                                      const u32* __restrict__ srcs,
                                                      const u16* __restrict__ h1b,
                                                      u16* __restrict__ aggb) {
    int wid = (blockIdx.x * blockDim.x + threadIdx.x) >> 6;
    int lane = threadIdx.x & 63;
    if (wid >= N_NODES) return;
    int start = row_ptr[wid], end = row_ptr[wid + 1];
    float a0 = 0.f, a1 = 0.f, a2 = 0.f, a3 = 0.f, c = 0.f;
    for (int e = start; e < end; e++) {
        u32 sv = srcs[e];
        if ((int)sv >= 0) {               // MSB clear = kept edge (mask==1)
            const u16* p = h1b + (size_t)sv * HID + lane * 4;
            u32 v0 = *(const u32*)p;
            u32 v1 = *(const u32*)(p + 2);
            a0 += bf2f((u16)v0);
            a1 += bf2f((u16)(v0 >> 16));
            a2 += bf2f((u16)v1);
            a3 += bf2f((u16)(v1 >> 16));
            c += 1.f;
        }
    }
    float inv = 1.f / fmaxf(c, 1.f);
    u32 o0 = (u32)f2bf(a0 * inv) | ((u32)f2bf(a1 * inv) << 16);
    u32 o1 = (u32)f2bf(a2 * inv) | ((u32)f2bf(a3 * inv) << 16);
    u16* p = aggb + (size_t)wid * HID + lane * 4;
    *(u32*)p = o0;
    *(u32*)(p + 2) = o1;
}

// ---------------- layer 1 MFMA GEMM (M=32, prefetch pipeline) ----------------
// A = [agg1 (128) | x (128)], K=256; acc1 = A @ Wc1^T (+b1, norm); accs = x @ Ws^T
// h1 = tanh(norm(acc1+b1) + accs + bs), stored bf16.
__global__ __launch_bounds__(256, 3) void sage1_kernel(const u16* __restrict__ xb,
                                                       const u16* __restrict__ aggb,
                                                       const u16* __restrict__ Wc1,
                                                       const u16* __restrict__ Wsb,
                                                       const float* __restrict__ b1f,
                                                       const float* __restrict__ bsf,
                                                       u16* __restrict__ h1b) {
    __shared__ float red[32][4];
    __shared__ float invn[32];
    int tid = threadIdx.x;
    int wave = tid >> 6, lane = tid & 63;
    int q = lane >> 4, c = lane & 15;
    int n0 = wave * 64;
    int m_base = blockIdx.x * 32;
    int koff = q * 8;

    f32x4 acc1[2][4], accs[2][4];
    const f32x4 z = {0.f, 0.f, 0.f, 0.f};
#pragma unroll
    for (int mt = 0; mt < 2; mt++)
#pragma unroll
        for (int nt = 0; nt < 4; nt++) { acc1[mt][nt] = z; accs[mt][nt] = z; }

    short8 a[2], b[4], bs_[4], an[2], bn[4], bsn[4];

    auto loadA = [&](int kt, short8* d) {
        int k = kt * 32 + koff;
        const u16* s; int kk;
        if (kt < 4) { s = aggb; kk = k; } else { s = xb; kk = k - 128; }
        d[0] = ld8(s + (size_t)(m_base + c) * IN_CH + kk);
        d[1] = ld8(s + (size_t)(m_base + 16 + c) * IN_CH + kk);
    };
    auto loadB = [&](int kt, short8* d) {
        int k = kt * 32 + koff;
#pragma unroll
        for (int nt = 0; nt < 4; nt++)
            d[nt] = ld8(Wc1 + (size_t)(n0 + nt * 16 + c) * 256 + k);
    };
    auto loadBs = [&](int kt, short8* d) {
        int k = (kt - 4) * 32 + koff;
#pragma unroll
        for (int nt = 0; nt < 4; nt++)
            d[nt] = ld8(Wsb + (size_t)(n0 + nt * 16 + c) * 128 + k);
    };

    loadA(0, a);
    loadB(0, b);
#pragma unroll
    for (int kt = 0; kt < 8; kt++) {
        if (kt < 7) {
            loadA(kt + 1, an);
            loadB(kt + 1, bn);
            if (kt + 1 >= 4) loadBs(kt + 1, bsn);
        }
#pragma unroll
        for (int mt = 0; mt < 2; mt++)
#pragma unroll
            for (int nt = 0; nt < 4; nt++)
                acc1[mt][nt] = __builtin_amdgcn_mfma_f32_16x16x32_bf16(a[mt], b[nt], acc1[mt][nt], 0, 0, 0);
        if (kt >= 4) {
#pragma unroll
            for (int mt = 0; mt < 2; mt++)
#pragma unroll
                for (int nt = 0; nt < 4; nt++)
                    accs[mt][nt] = __builtin_amdgcn_mfma_f32_16x16x32_bf16(a[mt], bs_[nt], accs[mt][nt], 0, 0, 0);
        }
        if (kt < 7) {
#pragma unroll
            for (int mt = 0; mt < 2; mt++) a[mt] = an[mt];
#pragma unroll
            for (int nt = 0; nt < 4; nt++) b[nt] = bn[nt];
            if (kt + 1 >= 4) {
#pragma unroll
                for (int nt = 0; nt < 4; nt++) bs_[nt] = bsn[nt];
            }
        }
    }

    float bcol[4], bscol[4];
#pragma unroll
    for (int nt = 0; nt < 4; nt++) {
        bcol[nt] = b1f[n0 + nt * 16 + c];
        bscol[nt] = bsf[n0 + nt * 16 + c];
    }
    float s[2][4];
#pragma unroll
    for (int mt = 0; mt < 2; mt++)
#pragma unroll
        for (int r = 0; r < 4; r++) {
            float t = 0.f;
#pragma unroll
            for (int nt = 0; nt < 4; nt++) {
                float v = acc1[mt][nt][r] + bcol[nt];
                acc1[mt][nt][r] = v;
                t += v * v;
            }
            s[mt][r] = t;
        }
#pragma unroll
    for (int off = 1; off < 16; off <<= 1) {
#pragma unroll
        for (int mt = 0; mt < 2; mt++)
#pragma unroll
            for (int r = 0; r < 4; r++)
                s[mt][r] += __shfl_xor(s[mt][r], off, 64);
    }
    if (c == 0) {
#pragma unroll
        for (int mt = 0; mt < 2; mt++)
#pragma unroll
            for (int r = 0; r < 4; r++)
                red[mt * 16 + q * 4 + r][wave] = s[mt][r];
    }
    __syncthreads();
    if (tid < 32) {
        float t = red[tid][0] + red[tid][1] + red[tid][2] + red[tid][3];
        invn[tid] = 1.f / fmaxf(sqrtf(t), 1e-12f);
    }
    __syncthreads();
#pragma unroll
    for (int mt = 0; mt < 2; mt++)
#pragma unroll
        for (int r = 0; r < 4; r++) {
            int rl = mt * 16 + q * 4 + r;
            int row = m_base + rl;
            if (row < N_NODES) {
                float iv = invn[rl];
#pragma unroll
                for (int nt = 0; nt < 4; nt++) {
                    float h = acc1[mt][nt][r] * iv + accs[mt][nt][r] + bscol[nt];
                    h1b[(size_t)row * HID + n0 + nt * 16 + c] = f2bf(tanhf(h));
                }
            }
        }
}

// ---------------- layer 2 MFMA GEMM (M=64, prefetch pipeline) ----------------
// A = [agg2 (256) | h1 (256)], K=512; h2 = tanh(norm(A@Wc2^T + b2)), stored bf16.
__global__ __launch_bounds__(256, 3) void sage2_kernel(const u16* __restrict__ h1b,
                                                       const u16* __restrict__ aggb,
                                                       const u16* __restrict__ Wc2,
                                                       const float* __restrict__ b2f,
                                                       u16* __restrict__ h2b) {
    __shared__ float red[64][4];
    __shared__ float invn[64];
    int tid = threadIdx.x;
    int wave = tid >> 6, lane = tid & 63;
    int q = lane >> 4, c = lane & 15;
    int n0 = wave * 64;
    int m_base = blockIdx.x * 64;
    int koff = q * 8;

    f32x4 acc[4][4];
    const f32x4 z = {0.f, 0.f, 0.f, 0.f};
#pragma unroll
    for (int mt = 0; mt < 4; mt++)
#pragma unroll
        for (int nt = 0; nt < 4; nt++) acc[mt][nt] = z;

    short8 a[4], b[4], an[4], bn[4];

    auto loadA = [&](int kt, short8* d) {
        int k = kt * 32 + koff;
        const u16* s; int kk;
        if (kt < 8) { s = aggb; kk = k; } else { s = h1b; kk = k - 256; }
#pragma unroll
        for (int mt = 0; mt < 4; mt++)
            d[mt] = ld8(s + (size_t)(m_base + mt * 16 + c) * HID + kk);
    };
    auto loadB = [&](int kt, short8* d) {
        int k = kt * 32 + koff;
#pragma unroll
        for (int nt = 0; nt < 4; nt++)
            d[nt] = ld8(Wc2 + (size_t)(n0 + nt * 16 + c) * 512 + k);
    };

    loadA(0, a);
    loadB(0, b);
#pragma unroll
    for (int kt = 0; kt < 16; kt++) {
        if (kt < 15) {
            loadA(kt + 1, an);
            loadB(kt + 1, bn);
        }
#pragma unroll
        for (int mt = 0; mt < 4; mt++)
#pragma unroll
            for (int nt = 0; nt < 4; nt++)
                acc[mt][nt] = __builtin_amdgcn_mfma_f32_16x16x32_bf16(a[mt], b[nt], acc[mt][nt], 0, 0, 0);
        if (kt < 15) {
#pragma unroll
            for (int mt = 0; mt < 4; mt++) a[mt] = an[mt];
#pragma unroll
            for (int nt = 0; nt < 4; nt++) b[nt] = bn[nt];
        }
    }

    float bcol[4];
#pragma unroll
    for (int nt = 0; nt < 4; nt++) bcol[nt] = b2f[n0 + nt * 16 + c];
    float s[4][4];
#pragma unroll
    for (int mt = 0; mt < 4; mt++)
#pragma unroll
        for (int r = 0; r < 4; r++) {
            float t = 0.f;
#pragma unroll
            for (int nt = 0; nt < 4; nt++) {
                float v = acc[mt][nt][r] + bcol[nt];
                acc[mt][nt][r] = v;
                t += v * v;
            }
            s[mt][r] = t;
        }
#pragma unroll
    for (int off = 1; off < 16; off <<= 1) {
#pragma unroll
        for (int mt = 0; mt < 4; mt++)
#pragma unroll
            for (int r = 0; r < 4; r++)
                s[mt][r] += __shfl_xor(s[mt][r], off, 64);
    }
    if (c == 0) {
#pragma unroll
        for (int mt = 0; mt < 4; mt++)
#pragma unroll
            for (int r = 0; r < 4; r++)
                red[mt * 16 + q * 4 + r][wave] = s[mt][r];
    }
    __syncthreads();
    if (tid < 64) {
        float t = red[tid][0] + red[tid][1] + red[tid][2] + red[tid][3];
        invn[tid] = 1.f / fmaxf(sqrtf(t), 1e-12f);
    }
    __syncthreads();
#pragma unroll
    for (int mt = 0; mt < 4; mt++)
#pragma unroll
        for (int r = 0; r < 4; r++) {
            int rl = mt * 16 + q * 4 + r;
            int row = m_base + rl;
            if (row < N_NODES) {
                float iv = invn[rl];
#pragma unroll
                for (int nt = 0; nt < 4; nt++)
                    h2b[(size_t)row * HID + n0 + nt * 16 + c] = f2bf(tanhf(acc[mt][nt][r] * iv));
            }
        }
}

// ---------------- final MFMA projection (M=128 per block, prefetch) ----------------
// out = h2 @ Wo^T + bo, N=128, K=256; wave owns 32 rows x all 128 cols
__global__ __launch_bounds__(256, 3) void final_kernel(const u16* __restrict__ h2b,
                                                       const u16* __restrict__ Wob,
                                                       const float* __restrict__ bof,
                                                       void* __restrict__ out,
                                                       const int* __restrict__ flags) {
    int tid = threadIdx.x;
    int wave = tid >> 6, lane = tid & 63;
    int q = lane >> 4, c = lane & 15;
    int m_base = blockIdx.x * 128 + wave * 32;
    int koff = q * 8;

    f32x4 acc[2][8];
    const f32x4 z = {0.f, 0.f, 0.f, 0.f};
#pragma unroll
    for (int mt = 0; mt < 2; mt++)
#pragma unroll
        for (int nt = 0; nt < 8; nt++) acc[mt][nt] = z;

    short8 a[2], b[8], an[2], bn[8];
    auto loadA = [&](int kt, short8* d) {
        int k = kt * 32 + koff;
        d[0] = ld8(h2b + (size_t)(m_base + c) * HID + k);
        d[1] = ld8(h2b + (size_t)(m_base + 16 + c) * HID + k);
    };
    auto loadB = [&](int kt, short8* d) {
        int k = kt * 32 + koff;
#pragma unroll
        for (int nt = 0; nt < 8; nt++)
            d[nt] = ld8(Wob + (size_t)(nt * 16 + c) * 256 + k);
    };

    loadA(0, a);
    loadB(0, b);
#pragma unroll
    for (int kt = 0; kt < 8; kt++) {
        if (kt < 7) {
            loadA(kt + 1, an);
            loadB(kt + 1, bn);
        }
#pragma unroll
        for (int mt = 0; mt < 2; mt++)
#pragma unroll
            for (int nt = 0; nt < 8; nt++)
                acc[mt][nt] = __builtin_amdgcn_mfma_f32_16x16x32_bf16(a[mt], b[nt], acc[mt][nt], 0, 0, 0);
        if (kt < 7) {
#pragma unroll
            for (int mt = 0; mt < 2; mt++) a[mt] = an[mt];
#pragma unroll
            for (int nt = 0; nt < 8; nt++) b[nt] = bn[nt];
        }
    }

    float bcol[8];
#pragma unroll
    for (int nt = 0; nt < 8; nt++) bcol[nt] = bof[nt * 16 + c];
    int isbf = flags[0];
#pragma unroll
    for (int mt = 0; mt < 2; mt++)
#pragma unroll
        for (int r = 0; r < 4; r++) {
            int row = m_base + mt * 16 + q * 4 + r;
            if (row < N_NODES) {
#pragma unroll
                for (int nt = 0; nt < 8; nt++) {
                    float v = acc[mt][nt][r] + bcol[nt];
                    int col = nt * 16 + c;
                    if (isbf) ((u16*)out)[(size_t)row * OUT_CH + col] = f2bf(v);
                    else      ((float*)out)[(size_t)row * OUT_CH + col] = v;
                }
            }
        }
}

extern "C" void kernel_launch(void* const* d_in, const int* in_sizes, int n_in,
                              void* d_out, int out_size, void* d_ws, size_t ws_size,
                              hipStream_t stream) {
    const void* x    = d_in[0];
    const int*  ei   = (const int*)d_in[1];
    const void* em   = d_in[2];
    const void* W1l  = d_in[3];
    const void* b1   = d_in[4];
    const void* W1r  = d_in[5];
    const void* Ws   = d_in[6];
    const void* bs   = d_in[7];
    const void* W2l  = d_in[8];
    const void* b2   = d_in[9];
    const void* W2r  = d_in[10];
    const void* Wo   = d_in[11];
    const void* bo   = d_in[12];

    char* p = (char*)d_ws;
    auto carve = [&](size_t bytes) { char* r = p; p += (bytes + 63) & ~(size_t)63; return r; };
    int*   flags  = (int*)carve(256);
    u16*   xb     = (u16*)carve((size_t)N_PAD * IN_CH * 2);
    u16*   h1b    = (u16*)carve((size_t)N_PAD * HID * 2);
    u16*   aggb   = (u16*)carve((size_t)N_PAD * HID * 2);   // layer1 view: [N_PAD][128]
    u16*   h2b    = (u16*)carve((size_t)N_PAD * HID * 2);
    u16*   Wc1    = (u16*)carve(256 * 256 * 2);
    u16*   Wsb    = (u16*)carve(256 * 128 * 2);
    u16*   Wc2    = (u16*)carve(256 * 512 * 2);
    u16*   Wob    = (u16*)carve(128 * 256 * 2);
    float* biasf  = (float*)carve(896 * 4);   // [b1|bs|b2|bo]
    int*   deg    = (int*)carve(50056 * 4);
    int*   row_ptr= (int*)carve(50056 * 4);
    int*   partial= (int*)carve(256 * 4);
    int*   pscan  = (int*)carve(256 * 4);
    int*   rank   = (int*)carve((size_t)N_EDGES * 4);
    u32*   srcs   = (u32*)carve((size_t)N_EDGES * 4);
    float* b1f = biasf, *bsf = biasf + 256, *b2f = biasf + 512, *bof = biasf + 768;
    (void)ws_size; (void)in_sizes; (void)n_in; (void)out_size;

    detect_kernel<<<1, 64, 0, stream>>>((const u16*)x, (const u8*)em, flags);

    // bf16 conversions / weight concats
    wcat_kernel<<<(N_NODES * IN_CH + 255) / 256, 256, 0, stream>>>(x, x, xb, 1, N_NODES * IN_CH, 0, flags);
    wcat_kernel<<<(256 * 256 + 255) / 256, 256, 0, stream>>>(W1l, W1r, Wc1, 256, 128, 128, flags);
    wcat_kernel<<<(256 * 128 + 255) / 256, 256, 0, stream>>>(Ws, Ws, Wsb, 1, 256 * 128, 0, flags);
    wcat_kernel<<<(256 * 512 + 255) / 256, 256, 0, stream>>>(W2l, W2r, Wc2, 256, 256, 256, flags);
    wcat_kernel<<<(128 * 256 + 255) / 256, 256, 0, stream>>>(Wo, Wo, Wob, 1, 128 * 256, 0, flags);
    biases_kernel<<<4, 256, 0, stream>>>(b1, bs, b2, bo, biasf, flags);

    // ---- CSR build (shared by both layers; mask packed into srcs MSB) ----
    hipMemsetAsync(deg, 0, 50056 * sizeof(int), stream);
    hist_kernel<<<(N_EDGES + 255) / 256, 256, 0, stream>>>(ei, deg, rank);
    const int NB = (N_NODES + 255) / 256;
    partial_kernel<<<NB, 256, 0, stream>>>(deg, partial);
    scanp_kernel<<<1, 256, 0, stream>>>(partial, pscan, NB);
    rowptr_kernel<<<NB, 256, 0, stream>>>(deg, pscan, row_ptr);
    scatter_csr_kernel<<<(N_EDGES + 255) / 256, 256, 0, stream>>>(ei, rank, row_ptr, em, srcs, flags);

    // ---- layer 1 ----
    gather1_kernel<<<(N_NODES * 64) / 256, 256, 0, stream>>>(row_ptr, srcs, xb, aggb);
    sage1_kernel<<<N_PAD / 32, 256, 0, stream>>>(xb, aggb, Wc1, Wsb, b1f, bsf, h1b);

    // ---- layer 2 ----
    gather2_kernel<<<(N_NODES * 64) / 256, 256, 0, stream>>>(row_ptr, srcs, h1b, aggb);
    sage2_kernel<<<N_PAD / 64, 256, 0, stream>>>(h1b, aggb, Wc2, b2f, h2b);

    final_kernel<<<N_PAD / 128, 256, 0, stream>>>(h2b, Wob, bof, d_out, flags);
}

// Round 6
// 351.967 us; speedup vs baseline: 8.9096x; 1.2177x over previous
//
#include <hip/hip_runtime.h>
#include <hip/hip_bf16.h>

#define N_NODES 50000
#define N_PAD   50048
#define N_EDGES 600000
#define IN_CH 128
#define HID 256
#define OUT_CH 128

typedef unsigned short u16;
typedef unsigned char u8;
typedef unsigned int u32;

typedef __attribute__((ext_vector_type(8))) short short8;
typedef __attribute__((ext_vector_type(4))) float f32x4;

typedef __attribute__((address_space(3))) u32 as3_u32;
typedef __attribute__((address_space(1))) const u32 as1_u32;

__device__ __forceinline__ float bf2f(u16 v) {
    unsigned u = ((unsigned)v) << 16;
    return __uint_as_float(u);
}
__device__ __forceinline__ u16 f2bf(float f) {
    unsigned u = __float_as_uint(f);
    u += 0x7FFF + ((u >> 16) & 1);   // round-to-nearest-even
    return (u16)(u >> 16);
}

// async global->LDS, 16B per lane; LDS dest = wave-uniform base + lane*16
__device__ __forceinline__ void async16(const void* g, void* l) {
    __builtin_amdgcn_global_load_lds((as1_u32*)g, (as3_u32*)l, 16, 0, 0);
}

// ---------------- format detection (one wave, lane-parallel) ----------------
// flags[0]: 1 if float tensors are bf16, 0 if f32
// flags[1]: mask format: 0=u8, 1=i32, 2=f32, 3=bf16
__global__ void detect_kernel(const u16* __restrict__ xu, const u8* __restrict__ mb,
                              int* __restrict__ flags) {
    int lane = threadIdx.x & 63;

    int inr = 0;
    {
        u32 w0 = ((const u32*)xu)[lane * 2 + 0];
        u32 w1 = ((const u32*)xu)[lane * 2 + 1];
        u16 h[4] = {(u16)w0, (u16)(w0 >> 16), (u16)w1, (u16)(w1 >> 16)};
#pragma unroll
        for (int j = 0; j < 4; j++) {
            int e = (h[j] >> 7) & 0xFF;
            if (e >= 100 && e <= 133) inr++;
        }
    }

    int c1 = 0, c23 = 0, h3f_1 = 0, h3f_3 = 0;
#pragma unroll
    for (int t = 0; t < 16; t++) {
        u32 w = ((const u32*)mb)[t * 64 + lane];
        u8 b1 = (u8)(w >> 8), b2 = (u8)(w >> 16), b3 = (u8)(w >> 24);
        if (b1) c1++;
        if (b1 == 0x3F) h3f_1 = 1;
        if (b2) c23++;
        if (b3) c23++;
        if (b3 == 0x3F) h3f_3 = 1;
    }

#pragma unroll
    for (int off = 32; off > 0; off >>= 1) {
        inr   += __shfl_xor(inr, off, 64);
        c1    += __shfl_xor(c1, off, 64);
        c23   += __shfl_xor(c23, off, 64);
        h3f_1 |= __shfl_xor(h3f_1, off, 64);
        h3f_3 |= __shfl_xor(h3f_3, off, 64);
    }

    if (lane == 0 && blockIdx.x == 0) {
        flags[0] = (inr >= 200) ? 1 : 0;
        int fmt;
        if (h3f_1) fmt = 3;              // bf16
        else if (h3f_3) fmt = 2;         // f32
        else if (c1 + c23 > 0) fmt = 0;  // u8 bool
        else fmt = 1;                    // int32
        flags[1] = fmt;
    }
}

// ---------------- conversions ----------------
__global__ void biases_kernel(const void* __restrict__ b1, const void* __restrict__ bs,
                              const void* __restrict__ b2, const void* __restrict__ bo,
                              float* __restrict__ dst, const int* __restrict__ flags) {
    int i = blockIdx.x * blockDim.x + threadIdx.x;
    if (i >= 896) return;
    const void* src; int idx;
    if (i < 256)      { src = b1; idx = i; }
    else if (i < 512) { src = bs; idx = i - 256; }
    else if (i < 768) { src = b2; idx = i - 512; }
    else              { src = bo; idx = i - 768; }
    float v;
    if (flags[0]) v = bf2f(((const u16*)src)[idx]);
    else          v = ((const float*)src)[idx];
    dst[i] = v;
}

// concat-convert to bf16: dst[n][k] = k<K1 ? A[n][k] : B[n][k-K1]  (K2 may be 0)
__global__ void wcat_kernel(const void* __restrict__ A, const void* __restrict__ B,
                            u16* __restrict__ dst, int N, int K1, int K2,
                            const int* __restrict__ flags) {
    int i = blockIdx.x * blockDim.x + threadIdx.x;
    int K = K1 + K2;
    if (i >= N * K) return;
    int n = i / K, k = i % K;
    const void* src; int idx;
    if (k < K1) { src = A; idx = n * K1 + k; }
    else        { src = B; idx = n * K2 + (k - K1); }
    u16 v;
    if (flags[0]) v = ((const u16*)src)[idx];
    else          v = f2bf(((const float*)src)[idx]);
    dst[i] = v;
}

// ---------------- CSR build (counting sort by dst) ----------------
__global__ void hist_kernel(const int* __restrict__ ei, int* __restrict__ deg,
                            int* __restrict__ rank) {
    int i = blockIdx.x * blockDim.x + threadIdx.x;
    if (i >= N_EDGES) return;
    int d = ei[N_EDGES + i];
    rank[i] = atomicAdd(&deg[d], 1);
}

__global__ void partial_kernel(const int* __restrict__ deg, int* __restrict__ partial) {
    __shared__ int sh[256];
    int t = threadIdx.x;
    int i = blockIdx.x * 256 + t;
    sh[t] = (i < N_NODES) ? deg[i] : 0;
    __syncthreads();
    for (int s = 128; s > 0; s >>= 1) {
        if (t < s) sh[t] += sh[t + s];
        __syncthreads();
    }
    if (t == 0) partial[blockIdx.x] = sh[0];
}

__global__ void scanp_kernel(const int* __restrict__ partial, int* __restrict__ pscan, int nb) {
    __shared__ int sh[256];
    int t = threadIdx.x;
    int v = (t < nb) ? partial[t] : 0;
    sh[t] = v;
    __syncthreads();
    for (int o = 1; o < 256; o <<= 1) {
        int u = (t >= o) ? sh[t - o] : 0;
        __syncthreads();
        sh[t] += u;
        __syncthreads();
    }
    if (t < nb) pscan[t] = sh[t] - v;   // exclusive
}

__global__ void rowptr_kernel(const int* __restrict__ deg, const int* __restrict__ pscan,
                              int* __restrict__ row_ptr) {
    __shared__ int sh[256];
    int t = threadIdx.x;
    int i = blockIdx.x * 256 + t;
    int v = (i < N_NODES) ? deg[i] : 0;
    sh[t] = v;
    __syncthreads();
    for (int o = 1; o < 256; o <<= 1) {
        int u = (t >= o) ? sh[t - o] : 0;
        __syncthreads();
        sh[t] += u;
        __syncthreads();
    }
    if (i <= N_NODES) row_ptr[i] = pscan[blockIdx.x] + sh[t] - v;
}

// mask decode folded in; mask packed into MSB of srcs (MSB set = dropped edge)
__global__ void scatter_csr_kernel(const int* __restrict__ ei, const int* __restrict__ rank,
                                   const int* __restrict__ row_ptr,
                                   const void* __restrict__ em,
                                   u32* __restrict__ srcs, const int* __restrict__ flags) {
    int i = blockIdx.x * blockDim.x + threadIdx.x;
    if (i >= N_EDGES) return;
    int d = ei[N_EDGES + i];
    int p = row_ptr[d] + rank[i];
    int fmt = flags[1];
    bool keep;
    if (fmt == 0)      keep = ((const u8*)em)[i] != 0;
    else if (fmt == 1) keep = ((const int*)em)[i] != 0;
    else if (fmt == 2) keep = ((const float*)em)[i] != 0.f;
    else               keep = ((const u16*)em)[i] != 0;
    srcs[p] = (u32)ei[i] | (keep ? 0u : 0x80000000u);
}

// ---------------- CSR gathers (one wave per node), write MEAN as bf16 ----------------
__global__ __launch_bounds__(256) void gather1_kernel(const int* __restrict__ row_ptr,
                                                      const u32* __restrict__ srcs,
                                                      const u16* __restrict__ xb,
                                                      u16* __restrict__ aggb) {
    int wid = (blockIdx.x * blockDim.x + threadIdx.x) >> 6;
    int lane = threadIdx.x & 63;
    if (wid >= N_NODES) return;
    int start = row_ptr[wid], end = row_ptr[wid + 1];
    float ax = 0.f, ay = 0.f, bx = 0.f, by = 0.f;
    int e = start;
    for (; e + 2 <= end; e += 2) {
        int s0 = (int)(srcs[e] & 0x7fffffffu);
        int s1 = (int)(srcs[e + 1] & 0x7fffffffu);
        u32 v0 = *(const u32*)(xb + (size_t)s0 * IN_CH + lane * 2);
        u32 v1 = *(const u32*)(xb + (size_t)s1 * IN_CH + lane * 2);
        ax += bf2f((u16)v0); ay += bf2f((u16)(v0 >> 16));
        bx += bf2f((u16)v1); by += bf2f((u16)(v1 >> 16));
    }
    if (e < end) {
        int s0 = (int)(srcs[e] & 0x7fffffffu);
        u32 v0 = *(const u32*)(xb + (size_t)s0 * IN_CH + lane * 2);
        ax += bf2f((u16)v0); ay += bf2f((u16)(v0 >> 16));
    }
    float inv = 1.f / fmaxf((float)(end - start), 1.f);
    u32 o = (u32)f2bf((ax + bx) * inv) | ((u32)f2bf((ay + by) * inv) << 16);
    *(u32*)(aggb + (size_t)wid * IN_CH + lane * 2) = o;
}

__global__ __launch_bounds__(256) void gather2_kernel(const int* __restrict__ row_ptr,
                                                      const u32* __restrict__ srcs,
                                                      const u16* __restrict__ h1b,
                                                      u16* __restrict__ aggb) {
    int wid = (blockIdx.x * blockDim.x + threadIdx.x) >> 6;
    int lane = threadIdx.x & 63;
    if (wid >= N_NODES) return;
    int start = row_ptr[wid], end = row_ptr[wid + 1];
    float a0 = 0.f, a1 = 0.f, a2 = 0.f, a3 = 0.f, c = 0.f;
    for (int e = start; e < end; e++) {
        u32 sv = srcs[e];
        if ((int)sv >= 0) {               // MSB clear = kept edge
            const u16* p = h1b + (size_t)sv * HID + lane * 4;
            u32 v0 = *(const u32*)p;
            u32 v1 = *(const u32*)(p + 2);
            a0 += bf2f((u16)v0);
            a1 += bf2f((u16)(v0 >> 16));
            a2 += bf2f((u16)v1);
            a3 += bf2f((u16)(v1 >> 16));
            c += 1.f;
        }
    }
    float inv = 1.f / fmaxf(c, 1.f);
    u32 o0 = (u32)f2bf(a0 * inv) | ((u32)f2bf(a1 * inv) << 16);
    u32 o1 = (u32)f2bf(a2 * inv) | ((u32)f2bf(a3 * inv) << 16);
    u16* p = aggb + (size_t)wid * HID + lane * 4;
    *(u32*)p = o0;
    *(u32*)(p + 2) = o1;
}

// ---------------- unified LDS-staged MFMA GEMM ----------------
// BM=64 rows/block, full N in block, BK=64, double-buffered LDS staged via
// global_load_lds(16B). XOR-8 chunk swizzle: slot s holds global chunk s^(row&7)
// -> conflict-free ds_read_b128 fragment reads.
// MODE 1: sage1. phase1 ks0-3: [agg(128)|x(128)] @ Wc1[256][256] -> acc
//                phase2 ks4-5: x @ Wsb[256][128] -> acc2
//                epi: v=acc+b1; norm over 256 cols; h1=tanh(v/nrm + acc2 + bs)
// MODE 2: sage2. ks0-7: [agg(256)|h1(256)] @ Wc2[256][512] -> acc
//                epi: v=acc+b2; h2=tanh(v/nrm)
// MODE 3: final. ks0-3: h2 @ Wob[128][256] -> acc; epi: out=acc+bo
template<int MODE>
__global__ __launch_bounds__(256, 2) void gemm_staged(
    const u16* __restrict__ A0, const u16* __restrict__ A1,
    const u16* __restrict__ W0, const u16* __restrict__ W1,
    const float* __restrict__ bias0, const float* __restrict__ bias1,
    u16* __restrict__ outb, void* __restrict__ outv, const int* __restrict__ flags) {

    constexpr int NT  = (MODE == 3) ? 2 : 4;       // n-tiles per wave
    constexpr int Nw  = NT * 16;                   // cols per wave
    constexpr int NKS = (MODE == 1) ? 6 : ((MODE == 2) ? 8 : 4);
    constexpr int BBYTES = NT * 64 * 128;          // B-tile bytes per buffer
    __shared__ __align__(16) u8 ldsmem[16384 + 2 * BBYTES];

    int tid = threadIdx.x;
    int w = tid >> 6, lane = tid & 63;
    int q = lane >> 4, c = lane & 15;
    int m_base = blockIdx.x * 64;
    int rj = lane >> 3, jj = lane & 7;
    int j16 = ((jj ^ rj) << 4);                    // swizzled global chunk offset

    f32x4 acc[4][NT], acc2[4][NT];
    const f32x4 z = {0.f, 0.f, 0.f, 0.f};
#pragma unroll
    for (int mt = 0; mt < 4; mt++)
#pragma unroll
        for (int nt = 0; nt < NT; nt++) { acc[mt][nt] = z; acc2[mt][nt] = z; }

    auto stage = [&](int ks, int b) {
        const u16* ap; int astr, kta;
        const u16* wp; int wstr, ktw;
        if (MODE == 1) {
            astr = 128;
            if (ks < 2)      { ap = A0; kta = ks; }
            else if (ks < 4) { ap = A1; kta = ks - 2; }
            else             { ap = A1; kta = ks - 4; }
            if (ks < 4) { wp = W0; wstr = 256; ktw = ks; }
            else        { wp = W1; wstr = 128; ktw = ks - 4; }
        } else if (MODE == 2) {
            astr = 256;
            if (ks < 4) { ap = A0; kta = ks; } else { ap = A1; kta = ks - 4; }
            wp = W0; wstr = 512; ktw = ks;
        } else {
            astr = 256; ap = A0; kta = ks;
            wp = W0; wstr = 256; ktw = ks;
        }
#pragma unroll
        for (int t = 0; t < 2; t++) {               // A: 16 rows/wave
            int r = w * 16 + t * 8;
            const u8* g = (const u8*)(ap + (size_t)(m_base + r + rj) * astr) + kta * 128 + j16;
            async16(g, ldsmem + b * 8192 + r * 128);
        }
#pragma unroll
        for (int t = 0; t < NT * 2; t++) {          // B: Nw rows/wave
            int n = w * Nw + t * 8;
            const u8* g = (const u8*)(wp + (size_t)(n + rj) * wstr) + ktw * 128 + j16;
            async16(g, ldsmem + 16384 + b * BBYTES + n * 128);
        }
    };

    auto compute = [&](int b, f32x4 (*tgt)[NT]) {
        const u8* ab = ldsmem + b * 8192;
        const u8* bb = ldsmem + 16384 + b * BBYTES;
#pragma unroll
        for (int kk = 0; kk < 2; kk++) {
            int sA = (((kk * 4 + q) ^ (c & 7)) << 4);
            short8 af[4], bfr[NT];
#pragma unroll
            for (int mt = 0; mt < 4; mt++)
                af[mt] = *(const short8*)(ab + (mt * 16 + c) * 128 + sA);
#pragma unroll
            for (int nt = 0; nt < NT; nt++)
                bfr[nt] = *(const short8*)(bb + (w * Nw + nt * 16 + c) * 128 + sA);
#pragma unroll
            for (int mt = 0; mt < 4; mt++)
#pragma unroll
                for (int nt = 0; nt < NT; nt++)
                    tgt[mt][nt] = __builtin_amdgcn_mfma_f32_16x16x32_bf16(af[mt], bfr[nt], tgt[mt][nt], 0, 0, 0);
        }
    };

    stage(0, 0);
    int b = 0;
#pragma unroll
    for (int ks = 0; ks < NKS; ks++) {
        __syncthreads();                  // drains staging of buffer b (vmcnt 0)
        if (ks + 1 < NKS) stage(ks + 1, b ^ 1);
        if (MODE == 1 && ks >= 4) compute(b, acc2);
        else                      compute(b, acc);
        b ^= 1;
    }
    __syncthreads();

    // ---------------- epilogue ----------------
    if (MODE == 3) {
        float bcol[NT];
#pragma unroll
        for (int nt = 0; nt < NT; nt++) bcol[nt] = bias0[w * Nw + nt * 16 + c];
        int isbf = flags[0];
#pragma unroll
        for (int mt = 0; mt < 4; mt++)
#pragma unroll
            for (int r = 0; r < 4; r++) {
                int row = m_base + mt * 16 + q * 4 + r;
                if (row < N_NODES) {
#pragma unroll
                    for (int nt = 0; nt < NT; nt++) {
                        float v = acc[mt][nt][r] + bcol[nt];
                        int col = w * Nw + nt * 16 + c;
                        if (isbf) ((u16*)outv)[(size_t)row * OUT_CH + col] = f2bf(v);
                        else      ((float*)outv)[(size_t)row * OUT_CH + col] = v;
                    }
                }
            }
    } else {
        float* redf = (float*)ldsmem;     // reuse staging LDS: red[64][4] + invn[64]
        float bcol[NT], b2col[NT];
#pragma unroll
        for (int nt = 0; nt < NT; nt++) {
            int col = w * Nw + nt * 16 + c;
            bcol[nt] = bias0[col];
            if (MODE == 1) b2col[nt] = bias1[col];
        }
        float s[4][4];
#pragma unroll
        for (int mt = 0; mt < 4; mt++)
#pragma unroll
            for (int r = 0; r < 4; r++) {
                float t = 0.f;
#pragma unroll
                for (int nt = 0; nt < NT; nt++) {
                    float v = acc[mt][nt][r] + bcol[nt];
                    acc[mt][nt][r] = v;
                    t += v * v;
                }
                s[mt][r] = t;
            }
#pragma unroll
        for (int off = 1; off < 16; off <<= 1) {
#pragma unroll
            for (int mt = 0; mt < 4; mt++)
#pragma unroll
                for (int r = 0; r < 4; r++)
                    s[mt][r] += __shfl_xor(s[mt][r], off, 64);
        }
        if (c == 0) {
#pragma unroll
            for (int mt = 0; mt < 4; mt++)
#pragma unroll
                for (int r = 0; r < 4; r++)
                    redf[(mt * 16 + q * 4 + r) * 4 + w] = s[mt][r];
        }
        __syncthreads();
        if (tid < 64) {
            float t = redf[tid * 4] + redf[tid * 4 + 1] + redf[tid * 4 + 2] + redf[tid * 4 + 3];
            redf[256 + tid] = 1.f / fmaxf(sqrtf(t), 1e-12f);
        }
        __syncthreads();
#pragma unroll
        for (int mt = 0; mt < 4; mt++)
#pragma unroll
            for (int r = 0; r < 4; r++) {
                int rl = mt * 16 + q * 4 + r;
                int row = m_base + rl;
                if (row < N_NODES) {
                    float iv = redf[256 + rl];
#pragma unroll
                    for (int nt = 0; nt < NT; nt++) {
                        int col = w * Nw + nt * 16 + c;
                        float h;
                        if (MODE == 1) h = acc[mt][nt][r] * iv + acc2[mt][nt][r] + b2col[nt];
                        else           h = acc[mt][nt][r] * iv;
                        outb[(size_t)row * HID + col] = f2bf(tanhf(h));
                    }
                }
            }
    }
}

extern "C" void kernel_launch(void* const* d_in, const int* in_sizes, int n_in,
                              void* d_out, int out_size, void* d_ws, size_t ws_size,
                              hipStream_t stream) {
    const void* x    = d_in[0];
    const int*  ei   = (const int*)d_in[1];
    const void* em   = d_in[2];
    const void* W1l  = d_in[3];
    const void* b1   = d_in[4];
    const void* W1r  = d_in[5];
    const void* Ws   = d_in[6];
    const void* bs   = d_in[7];
    const void* W2l  = d_in[8];
    const void* b2   = d_in[9];
    const void* W2r  = d_in[10];
    const void* Wo   = d_in[11];
    const void* bo   = d_in[12];

    char* p = (char*)d_ws;
    auto carve = [&](size_t bytes) { char* r = p; p += (bytes + 63) & ~(size_t)63; return r; };
    int*   flags  = (int*)carve(256);
    u16*   xb     = (u16*)carve((size_t)N_PAD * IN_CH * 2);
    u16*   h1b    = (u16*)carve((size_t)N_PAD * HID * 2);
    u16*   aggb   = (u16*)carve((size_t)N_PAD * HID * 2);   // layer1 view: [N_PAD][128]
    u16*   h2b    = (u16*)carve((size_t)N_PAD * HID * 2);
    u16*   Wc1    = (u16*)carve(256 * 256 * 2);
    u16*   Wsb    = (u16*)carve(256 * 128 * 2);
    u16*   Wc2    = (u16*)carve(256 * 512 * 2);
    u16*   Wob    = (u16*)carve(128 * 256 * 2);
    float* biasf  = (float*)carve(896 * 4);   // [b1|bs|b2|bo]
    int*   deg    = (int*)carve(50056 * 4);
    int*   row_ptr= (int*)carve(50056 * 4);
    int*   partial= (int*)carve(256 * 4);
    int*   pscan  = (int*)carve(256 * 4);
    int*   rank   = (int*)carve((size_t)N_EDGES * 4);
    u32*   srcs   = (u32*)carve((size_t)N_EDGES * 4);
    float* b1f = biasf, *bsf = biasf + 256, *b2f = biasf + 512, *bof = biasf + 768;
    (void)ws_size; (void)in_sizes; (void)n_in; (void)out_size;

    detect_kernel<<<1, 64, 0, stream>>>((const u16*)x, (const u8*)em, flags);

    // bf16 conversions / weight concats
    wcat_kernel<<<(N_NODES * IN_CH + 255) / 256, 256, 0, stream>>>(x, x, xb, 1, N_NODES * IN_CH, 0, flags);
    wcat_kernel<<<(256 * 256 + 255) / 256, 256, 0, stream>>>(W1l, W1r, Wc1, 256, 128, 128, flags);
    wcat_kernel<<<(256 * 128 + 255) / 256, 256, 0, stream>>>(Ws, Ws, Wsb, 1, 256 * 128, 0, flags);
    wcat_kernel<<<(256 * 512 + 255) / 256, 256, 0, stream>>>(W2l, W2r, Wc2, 256, 256, 256, flags);
    wcat_kernel<<<(128 * 256 + 255) / 256, 256, 0, stream>>>(Wo, Wo, Wob, 1, 128 * 256, 0, flags);
    biases_kernel<<<4, 256, 0, stream>>>(b1, bs, b2, bo, biasf, flags);

    // ---- CSR build (shared by both layers; mask packed into srcs MSB) ----
    hipMemsetAsync(deg, 0, 50056 * sizeof(int), stream);
    hist_kernel<<<(N_EDGES + 255) / 256, 256, 0, stream>>>(ei, deg, rank);
    const int NB = (N_NODES + 255) / 256;
    partial_kernel<<<NB, 256, 0, stream>>>(deg, partial);
    scanp_kernel<<<1, 256, 0, stream>>>(partial, pscan, NB);
    rowptr_kernel<<<NB, 256, 0, stream>>>(deg, pscan, row_ptr);
    scatter_csr_kernel<<<(N_EDGES + 255) / 256, 256, 0, stream>>>(ei, rank, row_ptr, em, srcs, flags);

    const int GB = N_PAD / 64;   // 782 blocks

    // ---- layer 1 ----
    gather1_kernel<<<(N_NODES * 64) / 256, 256, 0, stream>>>(row_ptr, srcs, xb, aggb);
    gemm_staged<1><<<GB, 256, 0, stream>>>(aggb, xb, Wc1, Wsb, b1f, bsf, h1b, nullptr, flags);

    // ---- layer 2 ----
    gather2_kernel<<<(N_NODES * 64) / 256, 256, 0, stream>>>(row_ptr, srcs, h1b, aggb);
    gemm_staged<2><<<GB, 256, 0, stream>>>(aggb, h1b, Wc2, nullptr, b2f, nullptr, h2b, nullptr, flags);

    // ---- final ----
    gemm_staged<3><<<GB, 256, 0, stream>>>(h2b, nullptr, Wob, nullptr, bof, nullptr, nullptr, d_out, flags);
}

// Round 7
// 339.153 us; speedup vs baseline: 9.2462x; 1.0378x over previous
//
#include <hip/hip_runtime.h>
#include <hip/hip_bf16.h>

#define N_NODES 50000
#define N_PAD   50048
#define N_EDGES 600000
#define IN_CH 128
#define HID 256
#define OUT_CH 128

typedef unsigned short u16;
typedef unsigned char u8;
typedef unsigned int u32;

typedef __attribute__((ext_vector_type(8))) short short8;
typedef __attribute__((ext_vector_type(4))) float f32x4;

typedef __attribute__((address_space(3))) u32 as3_u32;
typedef __attribute__((address_space(1))) const u32 as1_u32;

__device__ __forceinline__ float bf2f(u16 v) {
    unsigned u = ((unsigned)v) << 16;
    return __uint_as_float(u);
}
__device__ __forceinline__ u16 f2bf(float f) {
    unsigned u = __float_as_uint(f);
    u += 0x7FFF + ((u >> 16) & 1);   // round-to-nearest-even
    return (u16)(u >> 16);
}

// async global->LDS, 16B per lane; LDS dest = wave-uniform base + lane*16
__device__ __forceinline__ void async16(const void* g, void* l) {
    __builtin_amdgcn_global_load_lds((as1_u32*)g, (as3_u32*)l, 16, 0, 0);
}

// ---------------- format detection (one wave, lane-parallel) ----------------
// flags[0]: 1 if float tensors are bf16, 0 if f32
// flags[1]: mask format: 0=u8, 1=i32, 2=f32, 3=bf16
__global__ void detect_kernel(const u16* __restrict__ xu, const u8* __restrict__ mb,
                              int* __restrict__ flags) {
    int lane = threadIdx.x & 63;

    int inr = 0;
    {
        u32 w0 = ((const u32*)xu)[lane * 2 + 0];
        u32 w1 = ((const u32*)xu)[lane * 2 + 1];
        u16 h[4] = {(u16)w0, (u16)(w0 >> 16), (u16)w1, (u16)(w1 >> 16)};
#pragma unroll
        for (int j = 0; j < 4; j++) {
            int e = (h[j] >> 7) & 0xFF;
            if (e >= 100 && e <= 133) inr++;
        }
    }

    int c1 = 0, c23 = 0, h3f_1 = 0, h3f_3 = 0;
#pragma unroll
    for (int t = 0; t < 16; t++) {
        u32 w = ((const u32*)mb)[t * 64 + lane];
        u8 b1 = (u8)(w >> 8), b2 = (u8)(w >> 16), b3 = (u8)(w >> 24);
        if (b1) c1++;
        if (b1 == 0x3F) h3f_1 = 1;
        if (b2) c23++;
        if (b3) c23++;
        if (b3 == 0x3F) h3f_3 = 1;
    }

#pragma unroll
    for (int off = 32; off > 0; off >>= 1) {
        inr   += __shfl_xor(inr, off, 64);
        c1    += __shfl_xor(c1, off, 64);
        c23   += __shfl_xor(c23, off, 64);
        h3f_1 |= __shfl_xor(h3f_1, off, 64);
        h3f_3 |= __shfl_xor(h3f_3, off, 64);
    }

    if (lane == 0 && blockIdx.x == 0) {
        flags[0] = (inr >= 200) ? 1 : 0;
        int fmt;
        if (h3f_1) fmt = 3;              // bf16
        else if (h3f_3) fmt = 2;         // f32
        else if (c1 + c23 > 0) fmt = 0;  // u8 bool
        else fmt = 1;                    // int32
        flags[1] = fmt;
    }
}

// ---------------- conversions ----------------
__global__ void biases_kernel(const void* __restrict__ b1, const void* __restrict__ bs,
                              const void* __restrict__ b2, const void* __restrict__ bo,
                              float* __restrict__ dst, const int* __restrict__ flags) {
    int i = blockIdx.x * blockDim.x + threadIdx.x;
    if (i >= 896) return;
    const void* src; int idx;
    if (i < 256)      { src = b1; idx = i; }
    else if (i < 512) { src = bs; idx = i - 256; }
    else if (i < 768) { src = b2; idx = i - 512; }
    else              { src = bo; idx = i - 768; }
    float v;
    if (flags[0]) v = bf2f(((const u16*)src)[idx]);
    else          v = ((const float*)src)[idx];
    dst[i] = v;
}

// concat-convert to bf16: dst[n][k] = k<K1 ? A[n][k] : B[n][k-K1]  (K2 may be 0)
__global__ void wcat_kernel(const void* __restrict__ A, const void* __restrict__ B,
                            u16* __restrict__ dst, int N, int K1, int K2,
                            const int* __restrict__ flags) {
    int i = blockIdx.x * blockDim.x + threadIdx.x;
    int K = K1 + K2;
    if (i >= N * K) return;
    int n = i / K, k = i % K;
    const void* src; int idx;
    if (k < K1) { src = A; idx = n * K1 + k; }
    else        { src = B; idx = n * K2 + (k - K1); }
    u16 v;
    if (flags[0]) v = ((const u16*)src)[idx];
    else          v = f2bf(((const float*)src)[idx]);
    dst[i] = v;
}

// ---------------- CSR build (counting sort by dst; dual: full + masked) ----------------
__global__ void hist_kernel(const int* __restrict__ ei, const void* __restrict__ em,
                            int* __restrict__ deg, int* __restrict__ deg2,
                            int* __restrict__ rank, int* __restrict__ krank,
                            const int* __restrict__ flags) {
    int i = blockIdx.x * blockDim.x + threadIdx.x;
    if (i >= N_EDGES) return;
    int d = ei[N_EDGES + i];
    rank[i] = atomicAdd(&deg[d], 1);
    int fmt = flags[1];
    bool keep;
    if (fmt == 0)      keep = ((const u8*)em)[i] != 0;
    else if (fmt == 1) keep = ((const int*)em)[i] != 0;
    else if (fmt == 2) keep = ((const float*)em)[i] != 0.f;
    else               keep = ((const u16*)em)[i] != 0;
    krank[i] = keep ? atomicAdd(&deg2[d], 1) : -1;
}

// processes both deg arrays: blocks [0,nb) -> deg, [nb,2nb) -> deg2
__global__ void partial_kernel(const int* __restrict__ deg, const int* __restrict__ deg2,
                               int* __restrict__ partial, int nb) {
    __shared__ int sh[256];
    int t = threadIdx.x;
    int arr = (blockIdx.x >= nb) ? 1 : 0;
    int blk = blockIdx.x - arr * nb;
    const int* d = arr ? deg2 : deg;
    int i = blk * 256 + t;
    sh[t] = (i < N_NODES) ? d[i] : 0;
    __syncthreads();
    for (int s = 128; s > 0; s >>= 1) {
        if (t < s) sh[t] += sh[t + s];
        __syncthreads();
    }
    if (t == 0) partial[blockIdx.x] = sh[0];
}

// grid=2: block k scans partial[k*nb .. k*nb+nb)
__global__ void scanp_kernel(const int* __restrict__ partial, int* __restrict__ pscan, int nb) {
    __shared__ int sh[256];
    int t = threadIdx.x;
    int base = blockIdx.x * nb;
    int v = (t < nb) ? partial[base + t] : 0;
    sh[t] = v;
    __syncthreads();
    for (int o = 1; o < 256; o <<= 1) {
        int u = (t >= o) ? sh[t - o] : 0;
        __syncthreads();
        sh[t] += u;
        __syncthreads();
    }
    if (t < nb) pscan[base + t] = sh[t] - v;   // exclusive
}

__global__ void rowptr_kernel(const int* __restrict__ deg, const int* __restrict__ deg2,
                              const int* __restrict__ pscan,
                              int* __restrict__ row_ptr, int* __restrict__ row_ptr2, int nb) {
    __shared__ int sh[256];
    int t = threadIdx.x;
    int arr = (blockIdx.x >= nb) ? 1 : 0;
    int blk = blockIdx.x - arr * nb;
    const int* d = arr ? deg2 : deg;
    int* rp = arr ? row_ptr2 : row_ptr;
    int i = blk * 256 + t;
    int v = (i < N_NODES) ? d[i] : 0;
    sh[t] = v;
    __syncthreads();
    for (int o = 1; o < 256; o <<= 1) {
        int u = (t >= o) ? sh[t - o] : 0;
        __syncthreads();
        sh[t] += u;
        __syncthreads();
    }
    if (i <= N_NODES) rp[i] = pscan[arr * nb + blk] + sh[t] - v;
}

__global__ void scatter_csr_kernel(const int* __restrict__ ei, const int* __restrict__ rank,
                                   const int* __restrict__ krank,
                                   const int* __restrict__ row_ptr, const int* __restrict__ row_ptr2,
                                   int* __restrict__ srcs, int* __restrict__ srcs2) {
    int i = blockIdx.x * blockDim.x + threadIdx.x;
    if (i >= N_EDGES) return;
    int d = ei[N_EDGES + i];
    int s = ei[i];
    srcs[row_ptr[d] + rank[i]] = s;
    int r2 = krank[i];
    if (r2 >= 0) srcs2[row_ptr2[d] + r2] = s;
}

// ---------------- CSR gathers: scalar-addressed via lane-preload + readlane ----------------
__global__ __launch_bounds__(256) void gather1_kernel(const int* __restrict__ row_ptr,
                                                      const int* __restrict__ srcs,
                                                      const u16* __restrict__ xb,
                                                      u16* __restrict__ aggb) {
    int wid = (blockIdx.x * blockDim.x + threadIdx.x) >> 6;
    int lane = threadIdx.x & 63;
    if (wid >= N_NODES) return;
    int start = row_ptr[wid], end = row_ptr[wid + 1];
    int dg = end - start;
    int sv = (lane < dg) ? srcs[start + lane] : 0;   // one coalesced preload
    float ax = 0.f, ay = 0.f, bx = 0.f, by = 0.f;
    int n = dg < 64 ? dg : 64;
    int e = 0;
    for (; e + 2 <= n; e += 2) {
        int s0 = __builtin_amdgcn_readlane(sv, e);
        int s1 = __builtin_amdgcn_readlane(sv, e + 1);
        u32 v0 = *(const u32*)(xb + (size_t)s0 * IN_CH + lane * 2);
        u32 v1 = *(const u32*)(xb + (size_t)s1 * IN_CH + lane * 2);
        ax += bf2f((u16)v0); ay += bf2f((u16)(v0 >> 16));
        bx += bf2f((u16)v1); by += bf2f((u16)(v1 >> 16));
    }
    if (e < n) {
        int s0 = __builtin_amdgcn_readlane(sv, e);
        u32 v0 = *(const u32*)(xb + (size_t)s0 * IN_CH + lane * 2);
        ax += bf2f((u16)v0); ay += bf2f((u16)(v0 >> 16));
    }
    for (e = 64; e < dg; e++) {                      // rare tail (deg>64)
        int s0 = srcs[start + e];
        u32 v0 = *(const u32*)(xb + (size_t)s0 * IN_CH + lane * 2);
        ax += bf2f((u16)v0); ay += bf2f((u16)(v0 >> 16));
    }
    float inv = 1.f / fmaxf((float)dg, 1.f);
    u32 o = (u32)f2bf((ax + bx) * inv) | ((u32)f2bf((ay + by) * inv) << 16);
    *(u32*)(aggb + (size_t)wid * IN_CH + lane * 2) = o;
}

__global__ __launch_bounds__(256) void gather2_kernel(const int* __restrict__ row_ptr2,
                                                      const int* __restrict__ srcs2,
                                                      const u16* __restrict__ h1b,
                                                      u16* __restrict__ aggb) {
    int wid = (blockIdx.x * blockDim.x + threadIdx.x) >> 6;
    int lane = threadIdx.x & 63;
    if (wid >= N_NODES) return;
    int start = row_ptr2[wid], end = row_ptr2[wid + 1];
    int dg = end - start;
    int sv = (lane < dg) ? srcs2[start + lane] : 0;
    float a0 = 0.f, a1 = 0.f, a2 = 0.f, a3 = 0.f;
    float b0 = 0.f, b1 = 0.f, b2 = 0.f, b3 = 0.f;
    int n = dg < 64 ? dg : 64;
    int e = 0;
    for (; e + 2 <= n; e += 2) {
        int s0 = __builtin_amdgcn_readlane(sv, e);
        int s1 = __builtin_amdgcn_readlane(sv, e + 1);
        uint2 v = *(const uint2*)(h1b + (size_t)s0 * HID + lane * 4);
        uint2 w = *(const uint2*)(h1b + (size_t)s1 * HID + lane * 4);
        a0 += bf2f((u16)v.x); a1 += bf2f((u16)(v.x >> 16));
        a2 += bf2f((u16)v.y); a3 += bf2f((u16)(v.y >> 16));
        b0 += bf2f((u16)w.x); b1 += bf2f((u16)(w.x >> 16));
        b2 += bf2f((u16)w.y); b3 += bf2f((u16)(w.y >> 16));
    }
    if (e < n) {
        int s0 = __builtin_amdgcn_readlane(sv, e);
        uint2 v = *(const uint2*)(h1b + (size_t)s0 * HID + lane * 4);
        a0 += bf2f((u16)v.x); a1 += bf2f((u16)(v.x >> 16));
        a2 += bf2f((u16)v.y); a3 += bf2f((u16)(v.y >> 16));
    }
    for (e = 64; e < dg; e++) {                      // rare tail
        int s0 = srcs2[start + e];
        uint2 v = *(const uint2*)(h1b + (size_t)s0 * HID + lane * 4);
        a0 += bf2f((u16)v.x); a1 += bf2f((u16)(v.x >> 16));
        a2 += bf2f((u16)v.y); a3 += bf2f((u16)(v.y >> 16));
    }
    float inv = 1.f / fmaxf((float)dg, 1.f);
    u32 o0 = (u32)f2bf((a0 + b0) * inv) | ((u32)f2bf((a1 + b1) * inv) << 16);
    u32 o1 = (u32)f2bf((a2 + b2) * inv) | ((u32)f2bf((a3 + b3) * inv) << 16);
    u16* p = aggb + (size_t)wid * HID + lane * 4;
    *(u32*)p = o0;
    *(u32*)(p + 2) = o1;
}

// ---------------- unified LDS-staged MFMA GEMM ----------------
// BM=64 rows/block, full N in block, BK=64, double-buffered LDS staged via
// global_load_lds(16B). XOR-8 chunk swizzle: slot s holds global chunk s^(row&7)
// -> conflict-free ds_read_b128 fragment reads.
template<int MODE>
__global__ __launch_bounds__(256, 2) void gemm_staged(
    const u16* __restrict__ A0, const u16* __restrict__ A1,
    const u16* __restrict__ W0, const u16* __restrict__ W1,
    const float* __restrict__ bias0, const float* __restrict__ bias1,
    u16* __restrict__ outb, void* __restrict__ outv, const int* __restrict__ flags) {

    constexpr int NT  = (MODE == 3) ? 2 : 4;       // n-tiles per wave
    constexpr int Nw  = NT * 16;                   // cols per wave
    constexpr int NKS = (MODE == 1) ? 6 : ((MODE == 2) ? 8 : 4);
    constexpr int BBYTES = NT * 64 * 128;          // B-tile bytes per buffer
    __shared__ __align__(16) u8 ldsmem[16384 + 2 * BBYTES];

    int tid = threadIdx.x;
    int w = tid >> 6, lane = tid & 63;
    int q = lane >> 4, c = lane & 15;
    int m_base = blockIdx.x * 64;
    int rj = lane >> 3, jj = lane & 7;
    int j16 = ((jj ^ rj) << 4);                    // swizzled global chunk offset

    f32x4 acc[4][NT], acc2[4][NT];
    const f32x4 z = {0.f, 0.f, 0.f, 0.f};
#pragma unroll
    for (int mt = 0; mt < 4; mt++)
#pragma unroll
        for (int nt = 0; nt < NT; nt++) { acc[mt][nt] = z; acc2[mt][nt] = z; }

    auto stage = [&](int ks, int b) {
        const u16* ap; int astr, kta;
        const u16* wp; int wstr, ktw;
        if (MODE == 1) {
            astr = 128;
            if (ks < 2)      { ap = A0; kta = ks; }
            else if (ks < 4) { ap = A1; kta = ks - 2; }
            else             { ap = A1; kta = ks - 4; }
            if (ks < 4) { wp = W0; wstr = 256; ktw = ks; }
            else        { wp = W1; wstr = 128; ktw = ks - 4; }
        } else if (MODE == 2) {
            astr = 256;
            if (ks < 4) { ap = A0; kta = ks; } else { ap = A1; kta = ks - 4; }
            wp = W0; wstr = 512; ktw = ks;
        } else {
            astr = 256; ap = A0; kta = ks;
            wp = W0; wstr = 256; ktw = ks;
        }
#pragma unroll
        for (int t = 0; t < 2; t++) {               // A: 16 rows/wave
            int r = w * 16 + t * 8;
            const u8* g = (const u8*)(ap + (size_t)(m_base + r + rj) * astr) + kta * 128 + j16;
            async16(g, ldsmem + b * 8192 + r * 128);
        }
#pragma unroll
        for (int t = 0; t < NT * 2; t++) {          // B: Nw rows/wave
            int n = w * Nw + t * 8;
            const u8* g = (const u8*)(wp + (size_t)(n + rj) * wstr) + ktw * 128 + j16;
            async16(g, ldsmem + 16384 + b * BBYTES + n * 128);
        }
    };

    auto compute = [&](int b, f32x4 (*tgt)[NT]) {
        const u8* ab = ldsmem + b * 8192;
        const u8* bb = ldsmem + 16384 + b * BBYTES;
#pragma unroll
        for (int kk = 0; kk < 2; kk++) {
            int sA = (((kk * 4 + q) ^ (c & 7)) << 4);
            short8 af[4], bfr[NT];
#pragma unroll
            for (int mt = 0; mt < 4; mt++)
                af[mt] = *(const short8*)(ab + (mt * 16 + c) * 128 + sA);
#pragma unroll
            for (int nt = 0; nt < NT; nt++)
                bfr[nt] = *(const short8*)(bb + (w * Nw + nt * 16 + c) * 128 + sA);
#pragma unroll
            for (int mt = 0; mt < 4; mt++)
#pragma unroll
                for (int nt = 0; nt < NT; nt++)
                    tgt[mt][nt] = __builtin_amdgcn_mfma_f32_16x16x32_bf16(af[mt], bfr[nt], tgt[mt][nt], 0, 0, 0);
        }
    };

    stage(0, 0);
    int b = 0;
#pragma unroll
    for (int ks = 0; ks < NKS; ks++) {
        __syncthreads();                  // drains staging of buffer b (vmcnt 0)
        if (ks + 1 < NKS) stage(ks + 1, b ^ 1);
        if (MODE == 1 && ks >= 4) compute(b, acc2);
        else                      compute(b, acc);
        b ^= 1;
    }
    __syncthreads();

    // ---------------- epilogue ----------------
    if (MODE == 3) {
        float bcol[NT];
#pragma unroll
        for (int nt = 0; nt < NT; nt++) bcol[nt] = bias0[w * Nw + nt * 16 + c];
        int isbf = flags[0];
#pragma unroll
        for (int mt = 0; mt < 4; mt++)
#pragma unroll
            for (int r = 0; r < 4; r++) {
                int row = m_base + mt * 16 + q * 4 + r;
                if (row < N_NODES) {
#pragma unroll
                    for (int nt = 0; nt < NT; nt++) {
                        float v = acc[mt][nt][r] + bcol[nt];
                        int col = w * Nw + nt * 16 + c;
                        if (isbf) ((u16*)outv)[(size_t)row * OUT_CH + col] = f2bf(v);
                        else      ((float*)outv)[(size_t)row * OUT_CH + col] = v;
                    }
                }
            }
    } else {
        float* redf = (float*)ldsmem;     // reuse staging LDS: red[64][4] + invn[64]
        float bcol[NT], b2col[NT];
#pragma unroll
        for (int nt = 0; nt < NT; nt++) {
            int col = w * Nw + nt * 16 + c;
            bcol[nt] = bias0[col];
            if (MODE == 1) b2col[nt] = bias1[col];
        }
        float s[4][4];
#pragma unroll
        for (int mt = 0; mt < 4; mt++)
#pragma unroll
            for (int r = 0; r < 4; r++) {
                float t = 0.f;
#pragma unroll
                for (int nt = 0; nt < NT; nt++) {
                    float v = acc[mt][nt][r] + bcol[nt];
                    acc[mt][nt][r] = v;
                    t += v * v;
                }
                s[mt][r] = t;
            }
#pragma unroll
        for (int off = 1; off < 16; off <<= 1) {
#pragma unroll
            for (int mt = 0; mt < 4; mt++)
#pragma unroll
                for (int r = 0; r < 4; r++)
                    s[mt][r] += __shfl_xor(s[mt][r], off, 64);
        }
        if (c == 0) {
#pragma unroll
            for (int mt = 0; mt < 4; mt++)
#pragma unroll
                for (int r = 0; r < 4; r++)
                    redf[(mt * 16 + q * 4 + r) * 4 + w] = s[mt][r];
        }
        __syncthreads();
        if (tid < 64) {
            float t = redf[tid * 4] + redf[tid * 4 + 1] + redf[tid * 4 + 2] + redf[tid * 4 + 3];
            redf[256 + tid] = 1.f / fmaxf(sqrtf(t), 1e-12f);
        }
        __syncthreads();
#pragma unroll
        for (int mt = 0; mt < 4; mt++)
#pragma unroll
            for (int r = 0; r < 4; r++) {
                int rl = mt * 16 + q * 4 + r;
                int row = m_base + rl;
                if (row < N_NODES) {
                    float iv = redf[256 + rl];
#pragma unroll
                    for (int nt = 0; nt < NT; nt++) {
                        int col = w * Nw + nt * 16 + c;
                        float h;
                        if (MODE == 1) h = acc[mt][nt][r] * iv + acc2[mt][nt][r] + b2col[nt];
                        else           h = acc[mt][nt][r] * iv;
                        outb[(size_t)row * HID + col] = f2bf(tanhf(h));
                    }
                }
            }
    }
}

extern "C" void kernel_launch(void* const* d_in, const int* in_sizes, int n_in,
                              void* d_out, int out_size, void* d_ws, size_t ws_size,
                              hipStream_t stream) {
    const void* x    = d_in[0];
    const int*  ei   = (const int*)d_in[1];
    const void* em   = d_in[2];
    const void* W1l  = d_in[3];
    const void* b1   = d_in[4];
    const void* W1r  = d_in[5];
    const void* Ws   = d_in[6];
    const void* bs   = d_in[7];
    const void* W2l  = d_in[8];
    const void* b2   = d_in[9];
    const void* W2r  = d_in[10];
    const void* Wo   = d_in[11];
    const void* bo   = d_in[12];

    char* p = (char*)d_ws;
    auto carve = [&](size_t bytes) { char* r = p; p += (bytes + 63) & ~(size_t)63; return r; };
    int*   flags   = (int*)carve(256);
    u16*   xb      = (u16*)carve((size_t)N_PAD * IN_CH * 2);
    u16*   h1b     = (u16*)carve((size_t)N_PAD * HID * 2);
    u16*   aggb    = (u16*)carve((size_t)N_PAD * HID * 2);   // layer1 view: [N_PAD][128]
    u16*   h2b     = (u16*)carve((size_t)N_PAD * HID * 2);
    u16*   Wc1     = (u16*)carve(256 * 256 * 2);
    u16*   Wsb     = (u16*)carve(256 * 128 * 2);
    u16*   Wc2     = (u16*)carve(256 * 512 * 2);
    u16*   Wob     = (u16*)carve(128 * 256 * 2);
    float* biasf   = (float*)carve(896 * 4);   // [b1|bs|b2|bo]
    int*   deg     = (int*)carve(2 * 50176 * 4);   // deg | deg2
    int*   deg2    = deg + 50176;
    int*   row_ptr = (int*)carve(50056 * 4);
    int*   row_ptr2= (int*)carve(50056 * 4);
    int*   partial = (int*)carve(512 * 4);
    int*   pscan   = (int*)carve(512 * 4);
    int*   rank    = (int*)carve((size_t)N_EDGES * 4);
    int*   krank   = (int*)carve((size_t)N_EDGES * 4);
    int*   srcs    = (int*)carve((size_t)N_EDGES * 4);
    int*   srcs2   = (int*)carve((size_t)N_EDGES * 4);
    float* b1f = biasf, *bsf = biasf + 256, *b2f = biasf + 512, *bof = biasf + 768;
    (void)ws_size; (void)in_sizes; (void)n_in; (void)out_size;

    detect_kernel<<<1, 64, 0, stream>>>((const u16*)x, (const u8*)em, flags);

    // bf16 conversions / weight concats
    wcat_kernel<<<(N_NODES * IN_CH + 255) / 256, 256, 0, stream>>>(x, x, xb, 1, N_NODES * IN_CH, 0, flags);
    wcat_kernel<<<(256 * 256 + 255) / 256, 256, 0, stream>>>(W1l, W1r, Wc1, 256, 128, 128, flags);
    wcat_kernel<<<(256 * 128 + 255) / 256, 256, 0, stream>>>(Ws, Ws, Wsb, 1, 256 * 128, 0, flags);
    wcat_kernel<<<(256 * 512 + 255) / 256, 256, 0, stream>>>(W2l, W2r, Wc2, 256, 256, 256, flags);
    wcat_kernel<<<(128 * 256 + 255) / 256, 256, 0, stream>>>(Wo, Wo, Wob, 1, 128 * 256, 0, flags);
    biases_kernel<<<4, 256, 0, stream>>>(b1, bs, b2, bo, biasf, flags);

    // ---- dual CSR build (full graph + masked graph) ----
    hipMemsetAsync(deg, 0, 2 * 50176 * sizeof(int), stream);
    hist_kernel<<<(N_EDGES + 255) / 256, 256, 0, stream>>>(ei, em, deg, deg2, rank, krank, flags);
    const int NB = (N_NODES + 255) / 256;   // 196
    partial_kernel<<<2 * NB, 256, 0, stream>>>(deg, deg2, partial, NB);
    scanp_kernel<<<2, 256, 0, stream>>>(partial, pscan, NB);
    rowptr_kernel<<<2 * NB, 256, 0, stream>>>(deg, deg2, pscan, row_ptr, row_ptr2, NB);
    scatter_csr_kernel<<<(N_EDGES + 255) / 256, 256, 0, stream>>>(ei, rank, krank, row_ptr, row_ptr2, srcs, srcs2);

    const int GB = N_PAD / 64;   // 782 blocks

    // ---- layer 1 ----
    gather1_kernel<<<(N_NODES * 64) / 256, 256, 0, stream>>>(row_ptr, srcs, xb, aggb);
    gemm_staged<1><<<GB, 256, 0, stream>>>(aggb, xb, Wc1, Wsb, b1f, bsf, h1b, nullptr, flags);

    // ---- layer 2 ----
    gather2_kernel<<<(N_NODES * 64) / 256, 256, 0, stream>>>(row_ptr2, srcs2, h1b, aggb);
    gemm_staged<2><<<GB, 256, 0, stream>>>(aggb, h1b, Wc2, nullptr, b2f, nullptr, h2b, nullptr, flags);

    // ---- final ----
    gemm_staged<3><<<GB, 256, 0, stream>>>(h2b, nullptr, Wob, nullptr, bof, nullptr, nullptr, d_out, flags);
}

// Round 8
// 309.502 us; speedup vs baseline: 10.1320x; 1.0958x over previous
//
#include <hip/hip_runtime.h>
#include <hip/hip_bf16.h>

#define N_NODES 50000
#define N_PAD   50048
#define N_EDGES 600000
#define IN_CH 128
#define HID 256
#define OUT_CH 128

typedef unsigned short u16;
typedef unsigned char u8;
typedef unsigned int u32;

typedef __attribute__((ext_vector_type(8))) short short8;
typedef __attribute__((ext_vector_type(4))) float f32x4;

typedef __attribute__((address_space(3))) u32 as3_u32;
typedef __attribute__((address_space(1))) const u32 as1_u32;

__device__ __forceinline__ float bf2f(u16 v) {
    unsigned u = ((unsigned)v) << 16;
    return __uint_as_float(u);
}
__device__ __forceinline__ u16 f2bf(float f) {
    unsigned u = __float_as_uint(f);
    u += 0x7FFF + ((u >> 16) & 1);   // round-to-nearest-even
    return (u16)(u >> 16);
}

// async global->LDS, 16B per lane; LDS dest = wave-uniform base + lane*16
__device__ __forceinline__ void async16(const void* g, void* l) {
    __builtin_amdgcn_global_load_lds((as1_u32*)g, (as3_u32*)l, 16, 0, 0);
}

// ---------------- format detection (one wave, lane-parallel) ----------------
// flags[0]: 1 if float tensors are bf16, 0 if f32
// flags[1]: mask format: 0=u8, 1=i32, 2=f32, 3=bf16
__global__ void detect_kernel(const u16* __restrict__ xu, const u8* __restrict__ mb,
                              int* __restrict__ flags) {
    int lane = threadIdx.x & 63;

    int inr = 0;
    {
        u32 w0 = ((const u32*)xu)[lane * 2 + 0];
        u32 w1 = ((const u32*)xu)[lane * 2 + 1];
        u16 h[4] = {(u16)w0, (u16)(w0 >> 16), (u16)w1, (u16)(w1 >> 16)};
#pragma unroll
        for (int j = 0; j < 4; j++) {
            int e = (h[j] >> 7) & 0xFF;
            if (e >= 100 && e <= 133) inr++;
        }
    }

    int c1 = 0, c23 = 0, h3f_1 = 0, h3f_3 = 0;
#pragma unroll
    for (int t = 0; t < 16; t++) {
        u32 w = ((const u32*)mb)[t * 64 + lane];
        u8 b1 = (u8)(w >> 8), b2 = (u8)(w >> 16), b3 = (u8)(w >> 24);
        if (b1) c1++;
        if (b1 == 0x3F) h3f_1 = 1;
        if (b2) c23++;
        if (b3) c23++;
        if (b3 == 0x3F) h3f_3 = 1;
    }

#pragma unroll
    for (int off = 32; off > 0; off >>= 1) {
        inr   += __shfl_xor(inr, off, 64);
        c1    += __shfl_xor(c1, off, 64);
        c23   += __shfl_xor(c23, off, 64);
        h3f_1 |= __shfl_xor(h3f_1, off, 64);
        h3f_3 |= __shfl_xor(h3f_3, off, 64);
    }

    if (lane == 0 && blockIdx.x == 0) {
        flags[0] = (inr >= 200) ? 1 : 0;
        int fmt;
        if (h3f_1) fmt = 3;              // bf16
        else if (h3f_3) fmt = 2;         // f32
        else if (c1 + c23 > 0) fmt = 0;  // u8 bool
        else fmt = 1;                    // int32
        flags[1] = fmt;
    }
}

// ---------------- fused conversion: x + all weight concats + biases ----------------
#define NX (N_NODES * IN_CH)
__global__ void convert_all_kernel(const void* __restrict__ x,
                                   const void* __restrict__ W1l, const void* __restrict__ W1r,
                                   const void* __restrict__ Ws,
                                   const void* __restrict__ W2l, const void* __restrict__ W2r,
                                   const void* __restrict__ Wo,
                                   const void* __restrict__ b1, const void* __restrict__ bs,
                                   const void* __restrict__ b2, const void* __restrict__ bo,
                                   u16* __restrict__ xb, u16* __restrict__ Wc1,
                                   u16* __restrict__ Wsb, u16* __restrict__ Wc2,
                                   u16* __restrict__ Wob, float* __restrict__ biasf,
                                   const int* __restrict__ flags) {
    int i = blockIdx.x * blockDim.x + threadIdx.x;
    int isbf = flags[0];
    auto cv = [&](const void* s, int idx) -> u16 {
        return isbf ? ((const u16*)s)[idx] : f2bf(((const float*)s)[idx]);
    };
    if (i < NX) { xb[i] = cv(x, i); return; }
    i -= NX;
    if (i < 256 * 256) {                       // Wc1 = [W1l | W1r] along k
        int n = i >> 8, k = i & 255;
        const void* s = (k < 128) ? W1l : W1r;
        Wc1[i] = cv(s, n * 128 + (k & 127));
        return;
    }
    i -= 256 * 256;
    if (i < 256 * 128) { Wsb[i] = cv(Ws, i); return; }
    i -= 256 * 128;
    if (i < 256 * 512) {                       // Wc2 = [W2l | W2r] along k
        int n = i >> 9, k = i & 511;
        const void* s = (k < 256) ? W2l : W2r;
        Wc2[i] = cv(s, n * 256 + (k & 255));
        return;
    }
    i -= 256 * 512;
    if (i < 128 * 256) { Wob[i] = cv(Wo, i); return; }
    i -= 128 * 256;
    if (i < 896) {
        const void* s; int idx;
        if (i < 256)      { s = b1; idx = i; }
        else if (i < 512) { s = bs; idx = i - 256; }
        else if (i < 768) { s = b2; idx = i - 512; }
        else              { s = bo; idx = i - 768; }
        biasf[i] = isbf ? bf2f(((const u16*)s)[idx]) : ((const float*)s)[idx];
    }
}
#define CONV_TOTAL (NX + 256 * 256 + 256 * 128 + 256 * 512 + 128 * 256 + 896)

// ---------------- CSR build: packed dual histogram (deg lo16 | deg2 hi16) ----------------
__global__ void hist_kernel(const int* __restrict__ ei, const void* __restrict__ em,
                            u32* __restrict__ degp, u32* __restrict__ rankp,
                            const int* __restrict__ flags) {
    int i = blockIdx.x * blockDim.x + threadIdx.x;
    if (i >= N_EDGES) return;
    int d = ei[N_EDGES + i];
    int fmt = flags[1];
    bool keep;
    if (fmt == 0)      keep = ((const u8*)em)[i] != 0;
    else if (fmt == 1) keep = ((const int*)em)[i] != 0;
    else if (fmt == 2) keep = ((const float*)em)[i] != 0.f;
    else               keep = ((const u16*)em)[i] != 0;
    u32 inc = keep ? 0x10001u : 1u;
    u32 old = atomicAdd(&degp[d], inc);        // ONE atomic yields both ranks
    rankp[i] = (old & 0xffffu) | (keep ? (old & 0xffff0000u) : 0xffff0000u);
}

// packed per-chunk totals (chunk sums < 65536 per half -> no cross-carry)
__global__ void partial_kernel(const u32* __restrict__ degp, u32* __restrict__ partial) {
    __shared__ u32 sh[256];
    int t = threadIdx.x;
    int i = blockIdx.x * 256 + t;
    sh[t] = (i < N_NODES) ? degp[i] : 0;
    __syncthreads();
    for (int s = 128; s > 0; s >>= 1) {
        if (t < s) sh[t] += sh[t + s];
        __syncthreads();
    }
    if (t == 0) partial[blockIdx.x] = sh[0];
}

// one block: unpack chunk totals, exclusive-scan both halves -> pscan[0..nb) / pscan[nb..2nb)
__global__ void scanp_kernel(const u32* __restrict__ partial, int* __restrict__ pscan, int nb) {
    __shared__ int sh[256];
    int t = threadIdx.x;
    u32 pv = (t < nb) ? partial[t] : 0;
    int v1 = pv & 0xffff, v2 = pv >> 16;
    sh[t] = v1;
    __syncthreads();
    for (int o = 1; o < 256; o <<= 1) {
        int u = (t >= o) ? sh[t - o] : 0;
        __syncthreads();
        sh[t] += u;
        __syncthreads();
    }
    if (t < nb) pscan[t] = sh[t] - v1;
    __syncthreads();
    sh[t] = v2;
    __syncthreads();
    for (int o = 1; o < 256; o <<= 1) {
        int u = (t >= o) ? sh[t - o] : 0;
        __syncthreads();
        sh[t] += u;
        __syncthreads();
    }
    if (t < nb) pscan[nb + t] = sh[t] - v2;
}

// packed intra-chunk scan + global offsets -> both row_ptrs in one pass
__global__ void rowptr_kernel(const u32* __restrict__ degp, const int* __restrict__ pscan,
                              int* __restrict__ row_ptr, int* __restrict__ row_ptr2, int nb) {
    __shared__ u32 sh[256];
    int t = threadIdx.x;
    int i = blockIdx.x * 256 + t;
    u32 v = (i < N_NODES) ? degp[i] : 0;
    sh[t] = v;
    __syncthreads();
    for (int o = 1; o < 256; o <<= 1) {
        u32 u = (t >= o) ? sh[t - o] : 0;
        __syncthreads();
        sh[t] += u;
        __syncthreads();
    }
    u32 ex = sh[t] - v;                        // packed exclusive scan
    if (i <= N_NODES) {
        row_ptr[i]  = pscan[blockIdx.x] + (int)(ex & 0xffff);
        row_ptr2[i] = pscan[nb + blockIdx.x] + (int)(ex >> 16);
    }
}

__global__ void scatter_csr_kernel(const int* __restrict__ ei, const u32* __restrict__ rankp,
                                   const int* __restrict__ row_ptr, const int* __restrict__ row_ptr2,
                                   int* __restrict__ srcs, int* __restrict__ srcs2) {
    int i = blockIdx.x * blockDim.x + threadIdx.x;
    if (i >= N_EDGES) return;
    int d = ei[N_EDGES + i];
    int s = ei[i];
    u32 rp = rankp[i];
    srcs[row_ptr[d] + (int)(rp & 0xffffu)] = s;
    u32 kr = rp >> 16;
    if (kr != 0xffffu) srcs2[row_ptr2[d] + (int)kr] = s;
}

// ---------------- CSR gathers: scalar-addressed via lane-preload + readlane ----------------
__global__ __launch_bounds__(256) void gather1_kernel(const int* __restrict__ row_ptr,
                                                      const int* __restrict__ srcs,
                                                      const u16* __restrict__ xb,
                                                      u16* __restrict__ aggb) {
    int wid = (blockIdx.x * blockDim.x + threadIdx.x) >> 6;
    int lane = threadIdx.x & 63;
    if (wid >= N_NODES) return;
    int start = row_ptr[wid], end = row_ptr[wid + 1];
    int dg = end - start;
    int sv = (lane < dg) ? srcs[start + lane] : 0;   // one coalesced preload
    float a0 = 0.f, a1 = 0.f, b0 = 0.f, b1 = 0.f;
    float c0 = 0.f, c1 = 0.f, d0 = 0.f, d1 = 0.f;
    int n = dg < 64 ? dg : 64;
    int e = 0;
    for (; e + 4 <= n; e += 4) {
        int s0 = __builtin_amdgcn_readlane(sv, e);
        int s1 = __builtin_amdgcn_readlane(sv, e + 1);
        int s2 = __builtin_amdgcn_readlane(sv, e + 2);
        int s3 = __builtin_amdgcn_readlane(sv, e + 3);
        u32 v0 = *(const u32*)(xb + (size_t)s0 * IN_CH + lane * 2);
        u32 v1 = *(const u32*)(xb + (size_t)s1 * IN_CH + lane * 2);
        u32 v2 = *(const u32*)(xb + (size_t)s2 * IN_CH + lane * 2);
        u32 v3 = *(const u32*)(xb + (size_t)s3 * IN_CH + lane * 2);
        a0 += bf2f((u16)v0); a1 += bf2f((u16)(v0 >> 16));
        b0 += bf2f((u16)v1); b1 += bf2f((u16)(v1 >> 16));
        c0 += bf2f((u16)v2); c1 += bf2f((u16)(v2 >> 16));
        d0 += bf2f((u16)v3); d1 += bf2f((u16)(v3 >> 16));
    }
    for (; e < n; e++) {
        int s0 = __builtin_amdgcn_readlane(sv, e);
        u32 v0 = *(const u32*)(xb + (size_t)s0 * IN_CH + lane * 2);
        a0 += bf2f((u16)v0); a1 += bf2f((u16)(v0 >> 16));
    }
    for (e = 64; e < dg; e++) {                      // rare tail (deg>64)
        int s0 = srcs[start + e];
        u32 v0 = *(const u32*)(xb + (size_t)s0 * IN_CH + lane * 2);
        a0 += bf2f((u16)v0); a1 += bf2f((u16)(v0 >> 16));
    }
    float inv = 1.f / fmaxf((float)dg, 1.f);
    float rx = (a0 + b0) + (c0 + d0);
    float ry = (a1 + b1) + (c1 + d1);
    u32 o = (u32)f2bf(rx * inv) | ((u32)f2bf(ry * inv) << 16);
    *(u32*)(aggb + (size_t)wid * IN_CH + lane * 2) = o;
}

__global__ __launch_bounds__(256) void gather2_kernel(const int* __restrict__ row_ptr2,
                                                      const int* __restrict__ srcs2,
                                                      const u16* __restrict__ h1b,
                                                      u16* __restrict__ aggb) {
    int wid = (blockIdx.x * blockDim.x + threadIdx.x) >> 6;
    int lane = threadIdx.x & 63;
    if (wid >= N_NODES) return;
    int start = row_ptr2[wid], end = row_ptr2[wid + 1];
    int dg = end - start;
    int sv = (lane < dg) ? srcs2[start + lane] : 0;
    float a0 = 0.f, a1 = 0.f, a2 = 0.f, a3 = 0.f;
    float b0 = 0.f, b1 = 0.f, b2 = 0.f, b3 = 0.f;
    float c0 = 0.f, c1 = 0.f, c2 = 0.f, c3 = 0.f;
    float d0 = 0.f, d1 = 0.f, d2 = 0.f, d3 = 0.f;
    int n = dg < 64 ? dg : 64;
    int e = 0;
    for (; e + 4 <= n; e += 4) {
        int s0 = __builtin_amdgcn_readlane(sv, e);
        int s1 = __builtin_amdgcn_readlane(sv, e + 1);
        int s2 = __builtin_amdgcn_readlane(sv, e + 2);
        int s3 = __builtin_amdgcn_readlane(sv, e + 3);
        uint2 v = *(const uint2*)(h1b + (size_t)s0 * HID + lane * 4);
        uint2 w = *(const uint2*)(h1b + (size_t)s1 * HID + lane * 4);
        uint2 y = *(const uint2*)(h1b + (size_t)s2 * HID + lane * 4);
        uint2 zz = *(const uint2*)(h1b + (size_t)s3 * HID + lane * 4);
        a0 += bf2f((u16)v.x); a1 += bf2f((u16)(v.x >> 16));
        a2 += bf2f((u16)v.y); a3 += bf2f((u16)(v.y >> 16));
        b0 += bf2f((u16)w.x); b1 += bf2f((u16)(w.x >> 16));
        b2 += bf2f((u16)w.y); b3 += bf2f((u16)(w.y >> 16));
        c0 += bf2f((u16)y.x); c1 += bf2f((u16)(y.x >> 16));
        c2 += bf2f((u16)y.y); c3 += bf2f((u16)(y.y >> 16));
        d0 += bf2f((u16)zz.x); d1 += bf2f((u16)(zz.x >> 16));
        d2 += bf2f((u16)zz.y); d3 += bf2f((u16)(zz.y >> 16));
    }
    for (; e < n; e++) {
        int s0 = __builtin_amdgcn_readlane(sv, e);
        uint2 v = *(const uint2*)(h1b + (size_t)s0 * HID + lane * 4);
        a0 += bf2f((u16)v.x); a1 += bf2f((u16)(v.x >> 16));
        a2 += bf2f((u16)v.y); a3 += bf2f((u16)(v.y >> 16));
    }
    for (e = 64; e < dg; e++) {                      // rare tail
        int s0 = srcs2[start + e];
        uint2 v = *(const uint2*)(h1b + (size_t)s0 * HID + lane * 4);
        a0 += bf2f((u16)v.x); a1 += bf2f((u16)(v.x >> 16));
        a2 += bf2f((u16)v.y); a3 += bf2f((u16)(v.y >> 16));
    }
    float inv = 1.f / fmaxf((float)dg, 1.f);
    float r0 = (a0 + b0) + (c0 + d0);
    float r1 = (a1 + b1) + (c1 + d1);
    float r2 = (a2 + b2) + (c2 + d2);
    float r3 = (a3 + b3) + (c3 + d3);
    u32 o0 = (u32)f2bf(r0 * inv) | ((u32)f2bf(r1 * inv) << 16);
    u32 o1 = (u32)f2bf(r2 * inv) | ((u32)f2bf(r3 * inv) << 16);
    u16* p = aggb + (size_t)wid * HID + lane * 4;
    *(u32*)p = o0;
    *(u32*)(p + 2) = o1;
}

// ---------------- unified LDS-staged MFMA GEMM ----------------
// BM=64 rows/block, full N in block, BK=64, double-buffered LDS staged via
// global_load_lds(16B). XOR-8 chunk swizzle: slot s holds global chunk s^(row&7)
// -> conflict-free ds_read_b128 fragment reads.
template<int MODE>
__global__ __launch_bounds__(256, 2) void gemm_staged(
    const u16* __restrict__ A0, const u16* __restrict__ A1,
    const u16* __restrict__ W0, const u16* __restrict__ W1,
    const float* __restrict__ bias0, const float* __restrict__ bias1,
    u16* __restrict__ outb, void* __restrict__ outv, const int* __restrict__ flags) {

    constexpr int NT  = (MODE == 3) ? 2 : 4;       // n-tiles per wave
    constexpr int Nw  = NT * 16;                   // cols per wave
    constexpr int NKS = (MODE == 1) ? 6 : ((MODE == 2) ? 8 : 4);
    constexpr int BBYTES = NT * 64 * 128;          // B-tile bytes per buffer
    __shared__ __align__(16) u8 ldsmem[16384 + 2 * BBYTES];

    int tid = threadIdx.x;
    int w = tid >> 6, lane = tid & 63;
    int q = lane >> 4, c = lane & 15;
    int m_base = blockIdx.x * 64;
    int rj = lane >> 3, jj = lane & 7;
    int j16 = ((jj ^ rj) << 4);                    // swizzled global chunk offset

    f32x4 acc[4][NT], acc2[4][NT];
    const f32x4 z = {0.f, 0.f, 0.f, 0.f};
#pragma unroll
    for (int mt = 0; mt < 4; mt++)
#pragma unroll
        for (int nt = 0; nt < NT; nt++) { acc[mt][nt] = z; acc2[mt][nt] = z; }

    auto stage = [&](int ks, int b) {
        const u16* ap; int astr, kta;
        const u16* wp; int wstr, ktw;
        if (MODE == 1) {
            astr = 128;
            if (ks < 2)      { ap = A0; kta = ks; }
            else if (ks < 4) { ap = A1; kta = ks - 2; }
            else             { ap = A1; kta = ks - 4; }
            if (ks < 4) { wp = W0; wstr = 256; ktw = ks; }
            else        { wp = W1; wstr = 128; ktw = ks - 4; }
        } else if (MODE == 2) {
            astr = 256;
            if (ks < 4) { ap = A0; kta = ks; } else { ap = A1; kta = ks - 4; }
            wp = W0; wstr = 512; ktw = ks;
        } else {
            astr = 256; ap = A0; kta = ks;
            wp = W0; wstr = 256; ktw = ks;
        }
#pragma unroll
        for (int t = 0; t < 2; t++) {               // A: 16 rows/wave
            int r = w * 16 + t * 8;
            const u8* g = (const u8*)(ap + (size_t)(m_base + r + rj) * astr) + kta * 128 + j16;
            async16(g, ldsmem + b * 8192 + r * 128);
        }
#pragma unroll
        for (int t = 0; t < NT * 2; t++) {          // B: Nw rows/wave
            int n = w * Nw + t * 8;
            const u8* g = (const u8*)(wp + (size_t)(n + rj) * wstr) + ktw * 128 + j16;
            async16(g, ldsmem + 16384 + b * BBYTES + n * 128);
        }
    };

    auto compute = [&](int b, f32x4 (*tgt)[NT]) {
        const u8* ab = ldsmem + b * 8192;
        const u8* bb = ldsmem + 16384 + b * BBYTES;
#pragma unroll
        for (int kk = 0; kk < 2; kk++) {
            int sA = (((kk * 4 + q) ^ (c & 7)) << 4);
            short8 af[4], bfr[NT];
#pragma unroll
            for (int mt = 0; mt < 4; mt++)
                af[mt] = *(const short8*)(ab + (mt * 16 + c) * 128 + sA);
#pragma unroll
            for (int nt = 0; nt < NT; nt++)
                bfr[nt] = *(const short8*)(bb + (w * Nw + nt * 16 + c) * 128 + sA);
#pragma unroll
            for (int mt = 0; mt < 4; mt++)
#pragma unroll
                for (int nt = 0; nt < NT; nt++)
                    tgt[mt][nt] = __builtin_amdgcn_mfma_f32_16x16x32_bf16(af[mt], bfr[nt], tgt[mt][nt], 0, 0, 0);
        }
    };

    stage(0, 0);
    int b = 0;
#pragma unroll
    for (int ks = 0; ks < NKS; ks++) {
        __syncthreads();                  // drains staging of buffer b (vmcnt 0)
        if (ks + 1 < NKS) stage(ks + 1, b ^ 1);
        if (MODE == 1 && ks >= 4) compute(b, acc2);
        else                      compute(b, acc);
        b ^= 1;
    }
    __syncthreads();

    // ---------------- epilogue ----------------
    if (MODE == 3) {
        float bcol[NT];
#pragma unroll
        for (int nt = 0; nt < NT; nt++) bcol[nt] = bias0[w * Nw + nt * 16 + c];
        int isbf = flags[0];
#pragma unroll
        for (int mt = 0; mt < 4; mt++)
#pragma unroll
            for (int r = 0; r < 4; r++) {
                int row = m_base + mt * 16 + q * 4 + r;
                if (row < N_NODES) {
#pragma unroll
                    for (int nt = 0; nt < NT; nt++) {
                        float v = acc[mt][nt][r] + bcol[nt];
                        int col = w * Nw + nt * 16 + c;
                        if (isbf) ((u16*)outv)[(size_t)row * OUT_CH + col] = f2bf(v);
                        else      ((float*)outv)[(size_t)row * OUT_CH + col] = v;
                    }
                }
            }
    } else {
        float* redf = (float*)ldsmem;     // reuse staging LDS: red[64][4] + invn[64]
        float bcol[NT], b2col[NT];
#pragma unroll
        for (int nt = 0; nt < NT; nt++) {
            int col = w * Nw + nt * 16 + c;
            bcol[nt] = bias0[col];
            if (MODE == 1) b2col[nt] = bias1[col];
        }
        float s[4][4];
#pragma unroll
        for (int mt = 0; mt < 4; mt++)
#pragma unroll
            for (int r = 0; r < 4; r++) {
                float t = 0.f;
#pragma unroll
                for (int nt = 0; nt < NT; nt++) {
                    float v = acc[mt][nt][r] + bcol[nt];
                    acc[mt][nt][r] = v;
                    t += v * v;
                }
                s[mt][r] = t;
            }
#pragma unroll
        for (int off = 1; off < 16; off <<= 1) {
#pragma unroll
            for (int mt = 0; mt < 4; mt++)
#pragma unroll
                for (int r = 0; r < 4; r++)
                    s[mt][r] += __shfl_xor(s[mt][r], off, 64);
        }
        if (c == 0) {
#pragma unroll
            for (int mt = 0; mt < 4; mt++)
#pragma unroll
                for (int r = 0; r < 4; r++)
                    redf[(mt * 16 + q * 4 + r) * 4 + w] = s[mt][r];
        }
        __syncthreads();
        if (tid < 64) {
            float t = redf[tid * 4] + redf[tid * 4 + 1] + redf[tid * 4 + 2] + redf[tid * 4 + 3];
            redf[256 + tid] = 1.f / fmaxf(sqrtf(t), 1e-12f);
        }
        __syncthreads();
#pragma unroll
        for (int mt = 0; mt < 4; mt++)
#pragma unroll
            for (int r = 0; r < 4; r++) {
                int rl = mt * 16 + q * 4 + r;
                int row = m_base + rl;
                if (row < N_NODES) {
                    float iv = redf[256 + rl];
#pragma unroll
                    for (int nt = 0; nt < NT; nt++) {
                        int col = w * Nw + nt * 16 + c;
                        float h;
                        if (MODE == 1) h = acc[mt][nt][r] * iv + acc2[mt][nt][r] + b2col[nt];
                        else           h = acc[mt][nt][r] * iv;
                        outb[(size_t)row * HID + col] = f2bf(tanhf(h));
                    }
                }
            }
    }
}

extern "C" void kernel_launch(void* const* d_in, const int* in_sizes, int n_in,
                              void* d_out, int out_size, void* d_ws, size_t ws_size,
                              hipStream_t stream) {
    const void* x    = d_in[0];
    const int*  ei   = (const int*)d_in[1];
    const void* em   = d_in[2];
    const void* W1l  = d_in[3];
    const void* b1   = d_in[4];
    const void* W1r  = d_in[5];
    const void* Ws   = d_in[6];
    const void* bs   = d_in[7];
    const void* W2l  = d_in[8];
    const void* b2   = d_in[9];
    const void* W2r  = d_in[10];
    const void* Wo   = d_in[11];
    const void* bo   = d_in[12];

    char* p = (char*)d_ws;
    auto carve = [&](size_t bytes) { char* r = p; p += (bytes + 63) & ~(size_t)63; return r; };
    int*   flags   = (int*)carve(256);
    u16*   xb      = (u16*)carve((size_t)N_PAD * IN_CH * 2);
    u16*   h1b     = (u16*)carve((size_t)N_PAD * HID * 2);
    u16*   aggb    = (u16*)carve((size_t)N_PAD * HID * 2);   // layer1 view: [N_PAD][128]
    u16*   h2b     = (u16*)carve((size_t)N_PAD * HID * 2);
    u16*   Wc1     = (u16*)carve(256 * 256 * 2);
    u16*   Wsb     = (u16*)carve(256 * 128 * 2);
    u16*   Wc2     = (u16*)carve(256 * 512 * 2);
    u16*   Wob     = (u16*)carve(128 * 256 * 2);
    float* biasf   = (float*)carve(896 * 4);   // [b1|bs|b2|bo]
    u32*   degp    = (u32*)carve(50176 * 4);
    int*   row_ptr = (int*)carve(50056 * 4);
    int*   row_ptr2= (int*)carve(50056 * 4);
    u32*   partial = (u32*)carve(256 * 4);
    int*   pscan   = (int*)carve(512 * 4);
    u32*   rankp   = (u32*)carve((size_t)N_EDGES * 4);
    int*   srcs    = (int*)carve((size_t)N_EDGES * 4);
    int*   srcs2   = (int*)carve((size_t)N_EDGES * 4);
    float* b1f = biasf, *bsf = biasf + 256, *b2f = biasf + 512, *bof = biasf + 768;
    (void)ws_size; (void)in_sizes; (void)n_in; (void)out_size;

    detect_kernel<<<1, 64, 0, stream>>>((const u16*)x, (const u8*)em, flags);

    // fused conversions: x + weight concats + biases, one launch
    convert_all_kernel<<<(CONV_TOTAL + 255) / 256, 256, 0, stream>>>(
        x, W1l, W1r, Ws, W2l, W2r, Wo, b1, bs, b2, bo,
        xb, Wc1, Wsb, Wc2, Wob, biasf, flags);

    // ---- dual CSR build (packed histogram: one atomic per edge) ----
    hipMemsetAsync(degp, 0, 50176 * sizeof(u32), stream);
    hist_kernel<<<(N_EDGES + 255) / 256, 256, 0, stream>>>(ei, em, degp, rankp, flags);
    const int NB = (N_NODES + 255) / 256;   // 196
    partial_kernel<<<NB, 256, 0, stream>>>(degp, partial);
    scanp_kernel<<<1, 256, 0, stream>>>(partial, pscan, NB);
    rowptr_kernel<<<NB, 256, 0, stream>>>(degp, pscan, row_ptr, row_ptr2, NB);
    scatter_csr_kernel<<<(N_EDGES + 255) / 256, 256, 0, stream>>>(ei, rankp, row_ptr, row_ptr2, srcs, srcs2);

    const int GB = N_PAD / 64;   // 782 blocks

    // ---- layer 1 ----
    gather1_kernel<<<(N_NODES * 64) / 256, 256, 0, stream>>>(row_ptr, srcs, xb, aggb);
    gemm_staged<1><<<GB, 256, 0, stream>>>(aggb, xb, Wc1, Wsb, b1f, bsf, h1b, nullptr, flags);

    // ---- layer 2 ----
    gather2_kernel<<<(N_NODES * 64) / 256, 256, 0, stream>>>(row_ptr2, srcs2, h1b, aggb);
    gemm_staged<2><<<GB, 256, 0, stream>>>(aggb, h1b, Wc2, nullptr, b2f, nullptr, h2b, nullptr, flags);

    // ---- final ----
    gemm_staged<3><<<GB, 256, 0, stream>>>(h2b, nullptr, Wob, nullptr, bof, nullptr, nullptr, d_out, flags);
}